// Round 1
// baseline (1103.168 us; speedup 1.0000x reference)
//
#include <hip/hip_runtime.h>
#include <hip/hip_bf16.h>

#define BB 256
#define TT 128
#define SS 16
#define QQ 16
#define EE 128
#define KK 20
#define VOCAB 50020

// ---------------- workspace layout (floats) ----------------
static const size_t OFF_SENC = 0;                              // B*T*E
static const size_t OFF_QENC = OFF_SENC + (size_t)BB*TT*EE;    // B*E
static const size_t OFF_CKF  = OFF_QENC + (size_t)BB*EE;       // K*E
static const size_t OFF_XW   = OFF_CKF  + (size_t)KK*EE;       // B*T*E
static const size_t OFF_Z    = OFF_XW   + (size_t)BB*TT*EE;    // B*E

// ---------------- kernel 1: embedding bag-sum ----------------
// rows of `tok` (ntok ids each); out[row][e] = sum_s emb[tok[row,s]][e]*mask[s][e]
__global__ __launch_bounds__(256) void k_embed_sum(
    const int* __restrict__ tok, const float* __restrict__ emb,
    const float* __restrict__ mask, float* __restrict__ out,
    int nrow, int ntok)
{
  int tid = threadIdx.x;
  int row = blockIdx.x*8 + (tid>>5);
  if (row >= nrow) return;
  int e4 = (tid&31)*4;
  float4 acc = make_float4(0.f,0.f,0.f,0.f);
  for (int s=0; s<ntok; ++s) {
    int id = tok[row*ntok + s];
    float4 ev = *(const float4*)(emb + (size_t)id*EE + e4);
    float4 mv = *(const float4*)(mask + s*EE + e4);
    acc.x += ev.x*mv.x; acc.y += ev.y*mv.y; acc.z += ev.z*mv.z; acc.w += ev.w*mv.w;
  }
  *(float4*)(out + (size_t)row*EE + e4) = acc;
}

// ---------------- kernel 2: Ckf[k][f] = bias[f] + keys[k] . V[f] ----------------
__global__ __launch_bounds__(128) void k_ckf(
    const float* __restrict__ emb, const float* __restrict__ V,
    const float* __restrict__ bias, float* __restrict__ Ckf)
{
  int k = blockIdx.x;
  int f = threadIdx.x;
  const float* key = emb + (size_t)(VOCAB-KK+k)*EE;
  const float* vr  = V + (size_t)f*EE;
  float acc = bias[f];
  for (int e=0; e<EE; e+=4) {
    float4 kv = *(const float4*)(key + e);
    float4 vv = *(const float4*)(vr + e);
    acc += kv.x*vv.x + kv.y*vv.y + kv.z*vv.z + kv.w*vv.w;
  }
  Ckf[k*EE + f] = acc;
}

// ---------------- kernel 3: xw[r][f] = s_enc[r] . W[f]  (r = b*T+t) ----------------
__global__ __launch_bounds__(256) void k_xw(
    const float* __restrict__ senc, const float* __restrict__ W,
    float* __restrict__ xw)
{
  __shared__ float xs[64*EE];   // 32 KB
  int tid = threadIdx.x;
  int r0 = blockIdx.x*64;
  for (int i=0;i<8;++i){
    int idx = tid + i*256; int r = idx>>5; int c4 = (idx&31)*4;
    *(float4*)(xs + r*EE + c4) = *(const float4*)(senc + (size_t)(r0+r)*EE + c4);
  }
  __syncthreads();
  int f  = tid & 127;
  int rh = tid >> 7;            // 0/1 -> rows [rh*32, rh*32+32)
  float acc[32];
  #pragma unroll
  for (int i=0;i<32;++i) acc[i]=0.f;
  const float* wr = W + (size_t)f*EE;
  for (int e4=0; e4<EE; e4+=4) {
    float4 w4 = *(const float4*)(wr + e4);
    #pragma unroll
    for (int rr=0; rr<32; ++rr) {
      float4 x4 = *(const float4*)(xs + (rh*32+rr)*EE + e4);   // broadcast read
      acc[rr] += w4.x*x4.x + w4.y*x4.y + w4.z*x4.z + w4.w*x4.w;
    }
  }
  #pragma unroll
  for (int rr=0; rr<32; ++rr)
    xw[(size_t)(r0 + rh*32 + rr)*EE + f] = acc[rr];
}

// ---------------- kernel 4: the scan (one workgroup per batch b) ----------------
// LDS: U (128x132 padded), state (20x128), partials (4x20x128), x (128), small bufs
#define SCAN_LDS_FLOATS (128*132 + 20*128 + 4*20*128 + 128 + 40 + 20 + 40 + 20)

__global__ __launch_bounds__(512) void k_scan(
    const float* __restrict__ emb, const float* __restrict__ U,
    const float* __restrict__ senc, const float* __restrict__ xw,
    const float* __restrict__ Ckf, const float* __restrict__ prelu_a,
    const float* __restrict__ qenc, const float* __restrict__ H,
    float* __restrict__ zout)
{
  extern __shared__ float lds[];
  float* U_s     = lds;                    // 128*132
  float* state_s = U_s + 128*132;          // 20*128
  float* part_s  = state_s + 20*128;       // 4*20*128
  float* x_s     = part_s + 4*20*128;      // 128
  float* gp_s    = x_s + 128;              // 40
  float* g_s     = gp_s + 40;              // 20
  float* np_s    = g_s + 20;               // 40
  float* nm_s    = np_s + 40;              // 20

  int tid  = threadIdx.x;
  int b    = blockIdx.x;
  int f    = tid & 127;
  int ec   = tid >> 7;          // 0..3: e-chunk / k-group
  int half = (tid >> 6) & 1;    // which 64-lane half of the 128-thread group
  int lane = tid & 63;

  // stage U into LDS, padded to 132 floats/row (bank-conflict-free b128 reads)
  for (int i=0;i<8;++i){
    int idx = tid + i*512; int r = idx>>5; int c4 = (idx&31)*4;
    *(float4*)(U_s + r*132 + c4) = *(const float4*)(U + (size_t)r*EE + c4);
  }
  // state0 = keys (last K rows of embed table)
  for (int i=0;i<5;++i){
    int idx = tid + i*512;
    if (idx < KK*EE) {
      int k = idx>>7; int e = idx&127;
      state_s[k*EE + e] = emb[(size_t)(VOCAB-KK+k)*EE + e];
    }
  }
  // per-thread constants
  float keysreg[5];   // gate mapping: k = kk*4 + ec, at column e=f
  #pragma unroll
  for (int kk=0; kk<5; ++kk)
    keysreg[kk] = emb[(size_t)(VOCAB-KK + kk*4 + ec)*EE + f];
  float Creg[5];      // cand mapping: k = ec*5 + j, at column f
  #pragma unroll
  for (int j=0; j<5; ++j)
    Creg[j] = Ckf[(ec*5 + j)*EE + f];
  float pa = prelu_a[f];
  __syncthreads();

  const float* xrow  = senc + (size_t)b*TT*EE;
  const float* xwrow = xw   + (size_t)b*TT*EE;

  for (int t=0; t<TT; ++t) {
    // ---- A0: stage x_t ----
    if (tid < EE) x_s[tid] = xrow[t*EE + tid];
    float xwreg = xwrow[t*EE + f];
    __syncthreads();

    // ---- A: gate partials (dot(x, state[k]+keys[k]) over this wave's e-half) ----
    {
      float xv = x_s[f];
      #pragma unroll
      for (int kk=0; kk<5; ++kk) {
        float p = xv * (state_s[(kk*4+ec)*EE + f] + keysreg[kk]);
        #pragma unroll
        for (int off=32; off; off>>=1) p += __shfl_xor(p, off);
        if (lane == 0) gp_s[(kk*4+ec)*2 + half] = p;
      }
    }
    // ---- A: cand GEMM partial: acc[k] = sum_{e in chunk ec} state[k][e]*U[f][e] ----
    {
      float acc[20];
      #pragma unroll
      for (int k=0;k<20;++k) acc[k]=0.f;
      int e0 = ec*32;
      #pragma unroll
      for (int i=0;i<8;++i){
        float4 u4 = *(const float4*)(U_s + f*132 + e0 + i*4);
        #pragma unroll
        for (int k=0;k<20;++k){
          float4 s4 = *(const float4*)(state_s + k*EE + e0 + i*4);  // broadcast b128
          acc[k] += u4.x*s4.x + u4.y*s4.y + u4.z*s4.z + u4.w*s4.w;
        }
      }
      #pragma unroll
      for (int k=0;k<20;++k) part_s[(ec*20 + k)*EE + f] = acc[k];
    }
    __syncthreads();

    // ---- B: finalize gates ----
    if (tid < KK) {
      float v = gp_s[tid*2] + gp_s[tid*2+1];
      g_s[tid] = 1.0f/(1.0f + expf(-v));
    }
    __syncthreads();

    // ---- C: combine partials -> cand -> ns; norm partials ----
    float ns[5];
    #pragma unroll
    for (int j=0;j<5;++j){
      int k = ec*5 + j;
      float cv = part_s[(0*20+k)*EE + f] + part_s[(1*20+k)*EE + f]
               + part_s[(2*20+k)*EE + f] + part_s[(3*20+k)*EE + f];
      cv += Creg[j] + xwreg;
      cv = cv > 0.f ? cv : pa*cv;                    // prelu
      float n = state_s[k*EE + f] + g_s[k]*cv;
      ns[j] = n;
      float sq = n*n;
      #pragma unroll
      for (int off=32; off; off>>=1) sq += __shfl_xor(sq, off);
      if (lane == 0) np_s[k*2 + half] = sq;
    }
    __syncthreads();

    // ---- D: norms ----
    if (tid < KK) nm_s[tid] = sqrtf(np_s[tid*2] + np_s[tid*2+1]) + 1e-8f;
    __syncthreads();

    // ---- E: state update ----
    #pragma unroll
    for (int j=0;j<5;++j){
      int k = ec*5 + j;
      float n = ns[j];
      state_s[k*EE + f] = (n > 0.f ? n : 1.0f) / nm_s[k];
    }
    __syncthreads();
  }

  // ---------------- tail: attention + u + z ----------------
  float qv = qenc[(size_t)b*EE + f];
  #pragma unroll
  for (int kk=0; kk<5; ++kk){
    float p = qv * state_s[(kk*4+ec)*EE + f];
    #pragma unroll
    for (int off=32; off; off>>=1) p += __shfl_xor(p, off);
    if (lane == 0) gp_s[(kk*4+ec)*2 + half] = p;
  }
  __syncthreads();
  if (tid == 0) {
    float mx = -1e30f;
    for (int k=0;k<KK;++k){ float v = gp_s[k*2]+gp_s[k*2+1]; g_s[k]=v; mx = fmaxf(mx, v); }
    float s = 0.f;
    for (int k=0;k<KK;++k){ float e_ = expf(g_s[k]-mx); g_s[k]=e_; s += e_; }
    for (int k=0;k<KK;++k) g_s[k] = g_s[k]/s;
  }
  __syncthreads();
  if (tid < EE) {
    float u_ = 0.f;
    #pragma unroll
    for (int k=0;k<KK;++k) u_ += g_s[k]*state_s[k*EE + tid];
    x_s[tid] = u_;
  }
  __syncthreads();
  {
    float hp = 0.f;
    const float* hr = H + (size_t)f*EE + ec*32;
    #pragma unroll
    for (int i=0;i<8;++i){
      float4 h4 = *(const float4*)(hr + i*4);
      float4 u4 = *(const float4*)(x_s + ec*32 + i*4);
      hp += h4.x*u4.x + h4.y*u4.y + h4.z*u4.z + h4.w*u4.w;
    }
    part_s[ec*EE + f] = hp;
  }
  __syncthreads();
  if (tid < EE) {
    float zv = qv + part_s[0*EE+tid] + part_s[1*EE+tid] + part_s[2*EE+tid] + part_s[3*EE+tid];
    zv = zv > 0.f ? zv : pa*zv;                      // prelu (f==tid here)
    zout[(size_t)b*EE + tid] = zv;
  }
}

// ---------------- kernel 5: y = z @ R^T  (256 x 50020) ----------------
__global__ __launch_bounds__(256) void k_out(
    const float* __restrict__ z, const float* __restrict__ R,
    float* __restrict__ y)
{
  __shared__ float zs[64*EE];   // 32 KB
  int tid = threadIdx.x;
  int rb = blockIdx.y*64;
  for (int i=0;i<8;++i){
    int idx = tid + i*256; int r = idx>>5; int c4 = (idx&31)*4;
    *(float4*)(zs + r*EE + c4) = *(const float4*)(z + (size_t)(rb+r)*EE + c4);
  }
  __syncthreads();
  int c0 = blockIdx.x*128 + (tid&31)*4;
  int r0 = (tid>>5)*8;
  float acc[8][4];
  #pragma unroll
  for (int i=0;i<8;++i)
    #pragma unroll
    for (int j=0;j<4;++j) acc[i][j]=0.f;

  const float* rp[4];
  #pragma unroll
  for (int cc=0;cc<4;++cc){ int col = c0+cc; if (col >= VOCAB) col = 0; rp[cc] = R + (size_t)col*EE; }

  for (int e4=0; e4<EE; e4+=4) {
    float4 rv[4];
    #pragma unroll
    for (int cc=0;cc<4;++cc) rv[cc] = *(const float4*)(rp[cc] + e4);
    #pragma unroll
    for (int rr=0;rr<8;++rr){
      float4 x4 = *(const float4*)(zs + (r0+rr)*EE + e4);   // broadcast
      #pragma unroll
      for (int cc=0;cc<4;++cc)
        acc[rr][cc] += x4.x*rv[cc].x + x4.y*rv[cc].y + x4.z*rv[cc].z + x4.w*rv[cc].w;
    }
  }
  #pragma unroll
  for (int rr=0;rr<8;++rr){
    int row = rb + r0 + rr;
    if (c0 + 3 < VOCAB) {
      *(float4*)(y + (size_t)row*VOCAB + c0) =
          make_float4(acc[rr][0], acc[rr][1], acc[rr][2], acc[rr][3]);
    } else {
      for (int cc=0;cc<4;++cc){ int col = c0+cc; if (col < VOCAB) y[(size_t)row*VOCAB + col] = acc[rr][cc]; }
    }
  }
}

// ---------------- launch ----------------
extern "C" void kernel_launch(void* const* d_in, const int* in_sizes, int n_in,
                              void* d_out, int out_size, void* d_ws, size_t ws_size,
                              hipStream_t stream)
{
  const int*   story = (const int*)d_in[0];
  const int*   query = (const int*)d_in[1];
  const float* emb   = (const float*)d_in[2];
  const float* smask = (const float*)d_in[3];
  const float* qmask = (const float*)d_in[4];
  const float* pa    = (const float*)d_in[5];
  const float* U     = (const float*)d_in[6];
  const float* V     = (const float*)d_in[7];
  const float* W     = (const float*)d_in[8];
  const float* bias  = (const float*)d_in[9];
  const float* H     = (const float*)d_in[10];
  const float* R     = (const float*)d_in[11];
  float* y  = (float*)d_out;
  float* ws = (float*)d_ws;

  float* s_enc = ws + OFF_SENC;
  float* q_enc = ws + OFF_QENC;
  float* Ckf   = ws + OFF_CKF;
  float* xw    = ws + OFF_XW;
  float* z     = ws + OFF_Z;

  k_embed_sum<<<dim3(BB*TT/8), 256, 0, stream>>>(story, emb, smask, s_enc, BB*TT, SS);
  k_embed_sum<<<dim3(BB/8),    256, 0, stream>>>(query, emb, qmask, q_enc, BB, QQ);
  k_ckf<<<dim3(KK), 128, 0, stream>>>(emb, V, bias, Ckf);
  k_xw<<<dim3(BB*TT/64), 256, 0, stream>>>(s_enc, W, xw);

  const int scan_lds = SCAN_LDS_FLOATS * 4;   // 119,776 B
  hipFuncSetAttribute(reinterpret_cast<const void*>(k_scan),
                      hipFuncAttributeMaxDynamicSharedMemorySize, scan_lds);
  k_scan<<<dim3(BB), 512, scan_lds, stream>>>(emb, U, s_enc, xw, Ckf, pa, q_enc, H, z);

  k_out<<<dim3((VOCAB+127)/128, BB/64), 256, 0, stream>>>(z, R, y);
}

// Round 2
// 1034.179 us; speedup vs baseline: 1.0667x; 1.0667x over previous
//
#include <hip/hip_runtime.h>
#include <hip/hip_bf16.h>

#define BB 256
#define TT 128
#define SS 16
#define QQ 16
#define EE 128
#define KK 20
#define VOCAB 50020

// ---------------- workspace layout (floats) ----------------
static const size_t OFF_SENC = 0;                              // B*T*E
static const size_t OFF_QENC = OFF_SENC + (size_t)BB*TT*EE;    // B*E
static const size_t OFF_CKF  = OFF_QENC + (size_t)BB*EE;       // K*E
static const size_t OFF_XW   = OFF_CKF  + (size_t)KK*EE;       // B*T*E
static const size_t OFF_Z    = OFF_XW   + (size_t)BB*TT*EE;    // B*E

// ---------------- kernel 1: embedding bag-sum ----------------
__global__ __launch_bounds__(256) void k_embed_sum(
    const int* __restrict__ tok, const float* __restrict__ emb,
    const float* __restrict__ mask, float* __restrict__ out,
    int nrow, int ntok)
{
  int tid = threadIdx.x;
  int row = blockIdx.x*8 + (tid>>5);
  if (row >= nrow) return;
  int e4 = (tid&31)*4;
  float4 acc = make_float4(0.f,0.f,0.f,0.f);
  for (int s=0; s<ntok; ++s) {
    int id = tok[row*ntok + s];
    float4 ev = *(const float4*)(emb + (size_t)id*EE + e4);
    float4 mv = *(const float4*)(mask + s*EE + e4);
    acc.x += ev.x*mv.x; acc.y += ev.y*mv.y; acc.z += ev.z*mv.z; acc.w += ev.w*mv.w;
  }
  *(float4*)(out + (size_t)row*EE + e4) = acc;
}

// ---------------- kernel 2: Ckf[k][f] = bias[f] + keys[k] . V[f] ----------------
__global__ __launch_bounds__(128) void k_ckf(
    const float* __restrict__ emb, const float* __restrict__ V,
    const float* __restrict__ bias, float* __restrict__ Ckf)
{
  int k = blockIdx.x;
  int f = threadIdx.x;
  const float* key = emb + (size_t)(VOCAB-KK+k)*EE;
  const float* vr  = V + (size_t)f*EE;
  float acc = bias[f];
  for (int e=0; e<EE; e+=4) {
    float4 kv = *(const float4*)(key + e);
    float4 vv = *(const float4*)(vr + e);
    acc += kv.x*vv.x + kv.y*vv.y + kv.z*vv.z + kv.w*vv.w;
  }
  Ckf[k*EE + f] = acc;
}

// ---------------- kernel 3: xw[r][f] = s_enc[r] . W[f] ----------------
__global__ __launch_bounds__(256) void k_xw(
    const float* __restrict__ senc, const float* __restrict__ W,
    float* __restrict__ xw)
{
  __shared__ float xs[64*EE];
  int tid = threadIdx.x;
  int r0 = blockIdx.x*64;
  for (int i=0;i<8;++i){
    int idx = tid + i*256; int r = idx>>5; int c4 = (idx&31)*4;
    *(float4*)(xs + r*EE + c4) = *(const float4*)(senc + (size_t)(r0+r)*EE + c4);
  }
  __syncthreads();
  int f  = tid & 127;
  int rh = tid >> 7;
  float acc[32];
  #pragma unroll
  for (int i=0;i<32;++i) acc[i]=0.f;
  const float* wr = W + (size_t)f*EE;
  for (int e4=0; e4<EE; e4+=4) {
    float4 w4 = *(const float4*)(wr + e4);
    #pragma unroll
    for (int rr=0; rr<32; ++rr) {
      float4 x4 = *(const float4*)(xs + (rh*32+rr)*EE + e4);
      acc[rr] += w4.x*x4.x + w4.y*x4.y + w4.z*x4.z + w4.w*x4.w;
    }
  }
  #pragma unroll
  for (int rr=0; rr<32; ++rr)
    xw[(size_t)(r0 + rh*32 + rr)*EE + f] = acc[rr];
}

// ---------------- kernel 4: scan, wave-specialized layout ----------------
// 512 threads = 8 waves. wave w: kg=w>>1 owns k in [kg*5, kg*5+5); eh=w&1 owns
// e-half [eh*64, eh*64+64). lane owns output cols fA=lane, fB=lane+64.
// U col fA held in registers (constant across steps); U col fB read per-lane
// from LDS in [e4][f] float4 layout (conflict-free). State broadcasts b128.
// 2 barriers per step.
// LDS floats: state 2560 | part 2*2560 | Uq 32*128*4 | gp 40 | g 20 | np 40 | nm 20 | x 128
#define SCAN_LDS_FLOATS (2560 + 5120 + 16384 + 40 + 20 + 40 + 20 + 128)

__global__ __launch_bounds__(512, 2) void k_scan(
    const float* __restrict__ emb, const float* __restrict__ U,
    const float* __restrict__ senc, const float* __restrict__ xw,
    const float* __restrict__ Ckf, const float* __restrict__ prelu_a,
    const float* __restrict__ qenc, const float* __restrict__ H,
    float* __restrict__ zout)
{
  extern __shared__ float lds[];
  float* state_s = lds;                    // 2560
  float* part_s  = state_s + 2560;         // 5120 (part[eh][k][f])
  float* Uq_s    = part_s + 5120;          // 16384 (Uq[e4][f] as float4)
  float* gp_s    = Uq_s + 16384;           // 40 (gp[eh][k])
  float* g_s     = gp_s + 40;              // 20
  float* np_s    = g_s + 20;               // 40
  float* nm_s    = np_s + 40;              // 20
  float* x_s     = nm_s + 20;              // 128

  int tid  = threadIdx.x;
  int b    = blockIdx.x;
  int lane = tid & 63;
  int w    = tid >> 6;
  int kg   = w >> 1;
  int eh   = w & 1;
  int k0   = kg*5;
  int e0   = eh*64;
  int fA   = lane;
  int fB   = lane + 64;

  // stage Uq: Uq[e4*128 + f] = U[f][e4*4 .. e4*4+3]
  for (int i=0;i<8;++i){
    int idx = i*512 + tid; int ee4 = idx>>7; int f = idx&127;
    *(float4*)&Uq_s[(size_t)idx*4] = *(const float4*)(U + (size_t)f*EE + ee4*4);
  }
  // U col fA, e in [e0,e0+64): registers, constant across the whole scan
  float4 ur[16];
  #pragma unroll
  for (int i=0;i<16;++i)
    ur[i] = *(const float4*)(U + (size_t)fA*EE + e0 + i*4);
  // state0 = keys
  for (int idx=tid; idx<KK*EE; idx+=512)
    state_s[idx] = emb[(size_t)(VOCAB-KK + (idx>>7))*EE + (idx&127)];
  // per-thread constants
  float keysreg[5], CregA[5], CregB[5];
  #pragma unroll
  for (int j=0;j<5;++j){
    keysreg[j] = emb[(size_t)(VOCAB-KK + k0+j)*EE + e0 + lane];
    CregA[j]   = Ckf[(k0+j)*EE + fA];
    CregB[j]   = Ckf[(k0+j)*EE + fB];
  }
  float paA = prelu_a[fA], paB = prelu_a[fB];
  __syncthreads();

  const float* xrow  = senc + (size_t)b*TT*EE;
  const float* xwrow = xw   + (size_t)b*TT*EE;

  float xv  = xrow[e0 + lane];
  float xwA = xwrow[fA], xwB = xwrow[fB];

  for (int t=0; t<TT; ++t) {
    // ---- gate partial over this wave's e-half (in-wave shuffle reduce) ----
    #pragma unroll
    for (int j=0;j<5;++j){
      float s = state_s[(k0+j)*EE + e0 + lane];
      float p = xv * (s + keysreg[j]);
      #pragma unroll
      for (int off=32; off; off>>=1) p += __shfl_xor(p, off);
      if (lane == 0) gp_s[eh*KK + k0+j] = p;
    }
    // ---- cache old state at own output cols (before any overwrite) ----
    float soA[5], soB[5];
    #pragma unroll
    for (int j=0;j<5;++j){
      soA[j] = state_s[(k0+j)*EE + fA];
      soB[j] = state_s[(k0+j)*EE + fB];
    }
    // ---- cand partial: acc[j][col] over e in [e0, e0+64) ----
    float accA[5], accB[5];
    #pragma unroll
    for (int j=0;j<5;++j){ accA[j]=0.f; accB[j]=0.f; }
    #pragma unroll
    for (int i=0;i<16;++i){
      float4 ua = ur[i];
      float4 ub = *(const float4*)&Uq_s[(size_t)(((e0>>2)+i)*EE + fB)*4];
      #pragma unroll
      for (int j=0;j<5;++j){
        float4 s4 = *(const float4*)(state_s + (k0+j)*EE + e0 + i*4);  // broadcast
        accA[j] += ua.x*s4.x + ua.y*s4.y + ua.z*s4.z + ua.w*s4.w;
        accB[j] += ub.x*s4.x + ub.y*s4.y + ub.z*s4.z + ub.w*s4.w;
      }
    }
    #pragma unroll
    for (int j=0;j<5;++j){
      part_s[eh*2560 + (k0+j)*EE + fA] = accA[j];
      part_s[eh*2560 + (k0+j)*EE + fB] = accB[j];
    }
    __syncthreads();                       // barrier 1

    // prefetch next step's x / xw (hidden under phase C + barrier 2)
    float nxv = 0.f, nxwA = 0.f, nxwB = 0.f;
    if (t+1 < TT) {
      nxv  = xrow[(t+1)*EE + e0 + lane];
      nxwA = xwrow[(t+1)*EE + fA];
      nxwB = xwrow[(t+1)*EE + fB];
    }

    // ---- gates (uniform broadcast reads, computed redundantly per wave) ----
    float g[5];
    #pragma unroll
    for (int j=0;j<5;++j){
      float v = gp_s[k0+j] + gp_s[KK + k0+j];
      g[j] = 1.0f/(1.0f + expf(-v));
    }
    // ---- combine partials -> cand -> ns -> norm (in-wave) -> state ----
    #pragma unroll
    for (int j=0;j<5;++j){
      float cvA = accA[j] + part_s[(eh^1)*2560 + (k0+j)*EE + fA] + CregA[j] + xwA;
      float cvB = accB[j] + part_s[(eh^1)*2560 + (k0+j)*EE + fB] + CregB[j] + xwB;
      cvA = cvA > 0.f ? cvA : paA*cvA;
      cvB = cvB > 0.f ? cvB : paB*cvB;
      float nA = soA[j] + g[j]*cvA;
      float nB = soB[j] + g[j]*cvB;
      float sq = nA*nA + nB*nB;
      #pragma unroll
      for (int off=32; off; off>>=1) sq += __shfl_xor(sq, off);
      float nm = sqrtf(sq) + 1e-8f;
      if (eh == 0) {
        state_s[(k0+j)*EE + fA] = (nA > 0.f ? nA : 1.0f) / nm;
        state_s[(k0+j)*EE + fB] = (nB > 0.f ? nB : 1.0f) / nm;
      }
    }
    __syncthreads();                       // barrier 2
    xv = nxv; xwA = nxwA; xwB = nxwB;
  }

  // ---------------- tail: attention + u + z (same as validated R1) ----------------
  int f    = tid & 127;
  int ec   = tid >> 7;
  int half = (tid >> 6) & 1;
  int lane_t = tid & 63;
  float pat = prelu_a[f];

  float qv = qenc[(size_t)b*EE + f];
  #pragma unroll
  for (int kk=0; kk<5; ++kk){
    float p = qv * state_s[(kk*4+ec)*EE + f];
    #pragma unroll
    for (int off=32; off; off>>=1) p += __shfl_xor(p, off);
    if (lane_t == 0) gp_s[(kk*4+ec)*2 + half] = p;
  }
  __syncthreads();
  if (tid == 0) {
    float mx = -1e30f;
    for (int k=0;k<KK;++k){ float v = gp_s[k*2]+gp_s[k*2+1]; g_s[k]=v; mx = fmaxf(mx, v); }
    float s = 0.f;
    for (int k=0;k<KK;++k){ float e_ = expf(g_s[k]-mx); g_s[k]=e_; s += e_; }
    for (int k=0;k<KK;++k) g_s[k] = g_s[k]/s;
  }
  __syncthreads();
  if (tid < EE) {
    float u_ = 0.f;
    #pragma unroll
    for (int k=0;k<KK;++k) u_ += g_s[k]*state_s[k*EE + tid];
    x_s[tid] = u_;
  }
  __syncthreads();
  {
    float hp = 0.f;
    const float* hr = H + (size_t)f*EE + ec*32;
    #pragma unroll
    for (int i=0;i<8;++i){
      float4 h4 = *(const float4*)(hr + i*4);
      float4 u4 = *(const float4*)(x_s + ec*32 + i*4);
      hp += h4.x*u4.x + h4.y*u4.y + h4.z*u4.z + h4.w*u4.w;
    }
    part_s[ec*EE + f] = hp;
  }
  __syncthreads();
  if (tid < EE) {
    float zv = qv + part_s[0*EE+tid] + part_s[1*EE+tid] + part_s[2*EE+tid] + part_s[3*EE+tid];
    zv = zv > 0.f ? zv : pat*zv;
    zout[(size_t)b*EE + tid] = zv;
  }
}

// ---------------- kernel 5: y = z @ R^T ----------------
__global__ __launch_bounds__(256) void k_out(
    const float* __restrict__ z, const float* __restrict__ R,
    float* __restrict__ y)
{
  __shared__ float zs[64*EE];
  int tid = threadIdx.x;
  int rb = blockIdx.y*64;
  for (int i=0;i<8;++i){
    int idx = tid + i*256; int r = idx>>5; int c4 = (idx&31)*4;
    *(float4*)(zs + r*EE + c4) = *(const float4*)(z + (size_t)(rb+r)*EE + c4);
  }
  __syncthreads();
  int c0 = blockIdx.x*128 + (tid&31)*4;
  int r0 = (tid>>5)*8;
  float acc[8][4];
  #pragma unroll
  for (int i=0;i<8;++i)
    #pragma unroll
    for (int j=0;j<4;++j) acc[i][j]=0.f;

  const float* rp[4];
  #pragma unroll
  for (int cc=0;cc<4;++cc){ int col = c0+cc; if (col >= VOCAB) col = 0; rp[cc] = R + (size_t)col*EE; }

  for (int e4=0; e4<EE; e4+=4) {
    float4 rv[4];
    #pragma unroll
    for (int cc=0;cc<4;++cc) rv[cc] = *(const float4*)(rp[cc] + e4);
    #pragma unroll
    for (int rr=0;rr<8;++rr){
      float4 x4 = *(const float4*)(zs + (r0+rr)*EE + e4);
      #pragma unroll
      for (int cc=0;cc<4;++cc)
        acc[rr][cc] += x4.x*rv[cc].x + x4.y*rv[cc].y + x4.z*rv[cc].z + x4.w*rv[cc].w;
    }
  }
  #pragma unroll
  for (int rr=0;rr<8;++rr){
    int row = rb + r0 + rr;
    if (c0 + 3 < VOCAB) {
      *(float4*)(y + (size_t)row*VOCAB + c0) =
          make_float4(acc[rr][0], acc[rr][1], acc[rr][2], acc[rr][3]);
    } else {
      for (int cc=0;cc<4;++cc){ int col = c0+cc; if (col < VOCAB) y[(size_t)row*VOCAB + col] = acc[rr][cc]; }
    }
  }
}

// ---------------- launch ----------------
extern "C" void kernel_launch(void* const* d_in, const int* in_sizes, int n_in,
                              void* d_out, int out_size, void* d_ws, size_t ws_size,
                              hipStream_t stream)
{
  const int*   story = (const int*)d_in[0];
  const int*   query = (const int*)d_in[1];
  const float* emb   = (const float*)d_in[2];
  const float* smask = (const float*)d_in[3];
  const float* qmask = (const float*)d_in[4];
  const float* pa    = (const float*)d_in[5];
  const float* U     = (const float*)d_in[6];
  const float* V     = (const float*)d_in[7];
  const float* W     = (const float*)d_in[8];
  const float* bias  = (const float*)d_in[9];
  const float* H     = (const float*)d_in[10];
  const float* R     = (const float*)d_in[11];
  float* y  = (float*)d_out;
  float* ws = (float*)d_ws;

  float* s_enc = ws + OFF_SENC;
  float* q_enc = ws + OFF_QENC;
  float* Ckf   = ws + OFF_CKF;
  float* xw    = ws + OFF_XW;
  float* z     = ws + OFF_Z;

  k_embed_sum<<<dim3(BB*TT/8), 256, 0, stream>>>(story, emb, smask, s_enc, BB*TT, SS);
  k_embed_sum<<<dim3(BB/8),    256, 0, stream>>>(query, emb, qmask, q_enc, BB, QQ);
  k_ckf<<<dim3(KK), 128, 0, stream>>>(emb, V, bias, Ckf);
  k_xw<<<dim3(BB*TT/64), 256, 0, stream>>>(s_enc, W, xw);

  const int scan_lds = SCAN_LDS_FLOATS * 4;   // 97,248 B
  hipFuncSetAttribute(reinterpret_cast<const void*>(k_scan),
                      hipFuncAttributeMaxDynamicSharedMemorySize, scan_lds);
  k_scan<<<dim3(BB), 512, scan_lds, stream>>>(emb, U, s_enc, xw, Ckf, pa, q_enc, H, z);

  k_out<<<dim3((VOCAB+127)/128, BB/64), 256, 0, stream>>>(z, R, y);
}

// Round 3
// 824.867 us; speedup vs baseline: 1.3374x; 1.2538x over previous
//
#include <hip/hip_runtime.h>
#include <hip/hip_bf16.h>

#define BB 256
#define TT 128
#define SS 16
#define QQ 16
#define EE 128
#define KK 20
#define VOCAB 50020

typedef __attribute__((ext_vector_type(8))) short s8v;   // 8 bf16 (4 VGPR)
typedef __attribute__((ext_vector_type(4))) float f4v;   // MFMA acc
#define MFMA(a,b,c) __builtin_amdgcn_mfma_f32_16x16x32_bf16(a,b,c,0,0,0)

static __device__ __forceinline__ unsigned short f2bf(float x){
  unsigned u = __float_as_uint(x);
  unsigned r = (u + 0x7fffu + ((u>>16)&1u)) >> 16;
  return (unsigned short)r;
}
static __device__ __forceinline__ float bf2f(unsigned short h){
  return __uint_as_float(((unsigned)h)<<16);
}
// split 8 f32 into bf16 hi/lo fragments
static __device__ __forceinline__ void split8(const float* v, s8v& h, s8v& l){
  #pragma unroll
  for (int j=0;j<8;++j){
    unsigned short hb = f2bf(v[j]);
    float hf = bf2f(hb);
    unsigned short lb = f2bf(v[j]-hf);
    h[j] = (short)hb; l[j] = (short)lb;
  }
}

// ---------------- workspace layout (floats) ----------------
static const size_t OFF_SENC = 0;                              // B*T*E
static const size_t OFF_QENC = OFF_SENC + (size_t)BB*TT*EE;    // B*E
static const size_t OFF_CKF  = OFF_QENC + (size_t)BB*EE;       // K*E
static const size_t OFF_XW   = OFF_CKF  + (size_t)KK*EE;       // B*T*E
static const size_t OFF_Z    = OFF_XW   + (size_t)BB*TT*EE;    // B*E
static const size_t OFF_XK   = OFF_Z    + (size_t)BB*EE;       // B*T*K

// ---------------- kernel 1: embedding bag-sum ----------------
__global__ __launch_bounds__(256) void k_embed_sum(
    const int* __restrict__ tok, const float* __restrict__ emb,
    const float* __restrict__ mask, float* __restrict__ out,
    int nrow, int ntok)
{
  int tid = threadIdx.x;
  int row = blockIdx.x*8 + (tid>>5);
  if (row >= nrow) return;
  int e4 = (tid&31)*4;
  float4 acc = make_float4(0.f,0.f,0.f,0.f);
  for (int s=0; s<ntok; ++s) {
    int id = tok[row*ntok + s];
    float4 ev = *(const float4*)(emb + (size_t)id*EE + e4);
    float4 mv = *(const float4*)(mask + s*EE + e4);
    acc.x += ev.x*mv.x; acc.y += ev.y*mv.y; acc.z += ev.z*mv.z; acc.w += ev.w*mv.w;
  }
  *(float4*)(out + (size_t)row*EE + e4) = acc;
}

// ---------------- kernel 2: Ckf[k][f] = bias[f] + keys[k] . V[f] ----------------
__global__ __launch_bounds__(128) void k_ckf(
    const float* __restrict__ emb, const float* __restrict__ V,
    const float* __restrict__ bias, float* __restrict__ Ckf)
{
  int k = blockIdx.x;
  int f = threadIdx.x;
  const float* key = emb + (size_t)(VOCAB-KK+k)*EE;
  const float* vr  = V + (size_t)f*EE;
  float acc = bias[f];
  for (int e=0; e<EE; e+=4) {
    float4 kv = *(const float4*)(key + e);
    float4 vv = *(const float4*)(vr + e);
    acc += kv.x*vv.x + kv.y*vv.y + kv.z*vv.z + kv.w*vv.w;
  }
  Ckf[k*EE + f] = acc;
}

// ---------------- kernel 3: xw = senc@W^T  and  xk = senc@keys^T ----------------
__global__ __launch_bounds__(256) void k_xw(
    const float* __restrict__ senc, const float* __restrict__ W,
    const float* __restrict__ emb, float* __restrict__ xw,
    float* __restrict__ xk)
{
  __shared__ float xs[64*EE];        // 32 KB
  __shared__ float keys_s[KK*EE];    // 10 KB
  int tid = threadIdx.x;
  int r0 = blockIdx.x*64;
  for (int i=0;i<8;++i){
    int idx = tid + i*256; int r = idx>>5; int c4 = (idx&31)*4;
    *(float4*)(xs + r*EE + c4) = *(const float4*)(senc + (size_t)(r0+r)*EE + c4);
  }
  for (int idx=tid; idx<KK*EE; idx+=256)
    keys_s[idx] = emb[(size_t)(VOCAB-KK + (idx>>7))*EE + (idx&127)];
  __syncthreads();
  int f  = tid & 127;
  int rh = tid >> 7;
  float acc[32];
  #pragma unroll
  for (int i=0;i<32;++i) acc[i]=0.f;
  const float* wr = W + (size_t)f*EE;
  for (int e4=0; e4<EE; e4+=4) {
    float4 w4 = *(const float4*)(wr + e4);
    #pragma unroll
    for (int rr=0; rr<32; ++rr) {
      float4 x4 = *(const float4*)(xs + (rh*32+rr)*EE + e4);
      acc[rr] += w4.x*x4.x + w4.y*x4.y + w4.z*x4.z + w4.w*x4.w;
    }
  }
  #pragma unroll
  for (int rr=0; rr<32; ++rr)
    xw[(size_t)(r0 + rh*32 + rr)*EE + f] = acc[rr];
  // xk: 64 rows x 20 keys = 1280 dots of 128
  for (int i=0;i<5;++i){
    int task = tid + i*256;
    int r = task/KK, k = task - r*KK;
    float a = 0.f;
    for (int e=0; e<EE; e+=4){
      float4 x4 = *(const float4*)(xs + r*EE + e);
      float4 k4 = *(const float4*)(keys_s + k*EE + e);
      a += x4.x*k4.x + x4.y*k4.y + x4.z*k4.z + x4.w*k4.w;
    }
    xk[(size_t)(r0+r)*KK + k] = a;
  }
}

// ---------------- kernel 4: MFMA scan ----------------
// 512 thr = 8 waves: wave w -> m = w>>2 (M-tile: k rows 16m..16m+15),
// cg = w&3 (32-col slice). Lane l: q=l>>4, c=l&15.
// State in LDS as bf16 hi/lo ushort [32][136] (rows 20-31 zero pad).
// A-frag (state) row = 16m + c, e = kk*32 + q*8 + j  -> 1 ds_read_b128.
// B-frag (U cols) preloaded in regs. Gate = extra B-col (x) on cg==0 waves.
struct ScanLds {
  unsigned short shi[32][136];
  unsigned short slo[32][136];
  float xs[EE];
  float gs[32];
  float nms[32];
  float npart[8][32];
  float sf[KK*EE];    // tail: f32 state
  float gp[64];       // tail scratch
  float tpart[4*EE];  // tail scratch
};

__global__ __launch_bounds__(512) void k_scan(
    const float* __restrict__ emb, const float* __restrict__ U,
    const float* __restrict__ senc, const float* __restrict__ xw,
    const float* __restrict__ xk, const float* __restrict__ Ckf,
    const float* __restrict__ prelu_a, const float* __restrict__ qenc,
    const float* __restrict__ H, float* __restrict__ zout)
{
  __shared__ ScanLds L;
  int tid = threadIdx.x;
  int b   = blockIdx.x;
  int l   = tid & 63;
  int w   = tid >> 6;
  int cg  = w & 3;
  int m   = w >> 2;
  int q   = l >> 4;
  int c   = l & 15;
  bool isGate = (cg == 0);

  int rowA = 16*m + c;                 // A-frag row this lane loads
  int rowC[4];                          // C-frag rows this lane owns
  #pragma unroll
  for (int r=0;r<4;++r) rowC[r] = 16*m + 4*q + r;
  int col[2];
  #pragma unroll
  for (int nt=0;nt<2;++nt) col[nt] = cg*32 + nt*16 + c;

  // ---- init state arrays (zero pad rows 20-31 and pad cols) ----
  for (int idx=tid; idx<32*136; idx+=512){ ((unsigned short*)L.shi)[idx]=0; ((unsigned short*)L.slo)[idx]=0; }
  __syncthreads();
  for (int idx=tid; idx<KK*EE; idx+=512){
    int row=idx>>7, e=idx&127;
    float v = emb[(size_t)(VOCAB-KK+row)*EE + e];
    unsigned short hb = f2bf(v);
    float lo = v - bf2f(hb);
    L.shi[row][e] = hb;
    L.slo[row][e] = f2bf(lo);
  }
  // ---- B-frags: U columns, split hi/lo, constant across scan ----
  s8v bhi[2][4], blo[2][4];
  #pragma unroll
  for (int nt=0;nt<2;++nt)
    #pragma unroll
    for (int kk=0;kk<4;++kk){
      float tmp[8];
      const float* up = U + (size_t)col[nt]*EE + kk*32 + q*8;
      *(float4*)&tmp[0] = *(const float4*)up;
      *(float4*)&tmp[4] = *(const float4*)(up+4);
      split8(tmp, bhi[nt][kk], blo[nt][kk]);
    }
  // ---- per-lane constants ----
  float Creg[2][4], pa[2];
  #pragma unroll
  for (int nt=0;nt<2;++nt){
    pa[nt] = prelu_a[col[nt]];
    #pragma unroll
    for (int r=0;r<4;++r)
      Creg[nt][r] = (rowC[r] < KK) ? Ckf[rowC[r]*EE + col[nt]] : 0.f;
  }

  const float* xrow  = senc + (size_t)b*TT*EE;
  const float* xwrow = xw   + (size_t)b*TT*EE;
  const float* xkrow = xk   + (size_t)b*TT*KK;

  // t=0 staging
  if (tid < EE) L.xs[tid] = xrow[tid];
  float xwc[2];
  #pragma unroll
  for (int nt=0;nt<2;++nt) xwc[nt] = xwrow[col[nt]];
  float xkc[4] = {0.f,0.f,0.f,0.f};
  if (isGate && c==0){
    #pragma unroll
    for (int r=0;r<4;++r) if (rowC[r] < KK) xkc[r] = xkrow[rowC[r]];
  }
  __syncthreads();

  for (int t=0; t<TT; ++t) {
    // ======== P1: reads of old state + MFMAs + gate write ========
    // prefetch t+1 globals
    float nxv = 0.f, xwn[2] = {0.f,0.f}, xkn[4] = {0.f,0.f,0.f,0.f};
    if (t+1 < TT){
      if (tid < EE) nxv = xrow[(size_t)(t+1)*EE + tid];
      #pragma unroll
      for (int nt=0;nt<2;++nt) xwn[nt] = xwrow[(size_t)(t+1)*EE + col[nt]];
      if (isGate && c==0){
        #pragma unroll
        for (int r=0;r<4;++r) if (rowC[r] < KK) xkn[r] = xkrow[(size_t)(t+1)*KK + rowC[r]];
      }
    }
    // A-frags (old state)
    s8v ahi[4], alo[4];
    #pragma unroll
    for (int kk=0;kk<4;++kk){
      ahi[kk] = *(const s8v*)&L.shi[rowA][kk*32 + q*8];
      alo[kk] = *(const s8v*)&L.slo[rowA][kk*32 + q*8];
    }
    // old state at own C positions
    float so[2][4];
    #pragma unroll
    for (int nt=0;nt<2;++nt)
      #pragma unroll
      for (int r=0;r<4;++r)
        so[nt][r] = bf2f(L.shi[rowC[r]][col[nt]]) + bf2f(L.slo[rowC[r]][col[nt]]);
    // cand MFMAs (3-term split)
    f4v acc0 = {0.f,0.f,0.f,0.f}, acc1 = {0.f,0.f,0.f,0.f};
    #pragma unroll
    for (int kk=0;kk<4;++kk){
      acc0 = MFMA(ahi[kk], bhi[0][kk], acc0);
      acc0 = MFMA(ahi[kk], blo[0][kk], acc0);
      acc0 = MFMA(alo[kk], bhi[0][kk], acc0);
      acc1 = MFMA(ahi[kk], bhi[1][kk], acc1);
      acc1 = MFMA(ahi[kk], blo[1][kk], acc1);
      acc1 = MFMA(alo[kk], bhi[1][kk], acc1);
    }
    // gate MFMA on cg==0 waves: B col0 = x
    if (isGate){
      s8v xh[4], xl[4];
      #pragma unroll
      for (int kk=0;kk<4;++kk){
        #pragma unroll
        for (int j=0;j<8;++j){ xh[kk][j]=0; xl[kk][j]=0; }
      }
      if (c==0){
        #pragma unroll
        for (int kk=0;kk<4;++kk){
          float tmp[8];
          *(float4*)&tmp[0] = *(const float4*)&L.xs[kk*32 + q*8];
          *(float4*)&tmp[4] = *(const float4*)&L.xs[kk*32 + q*8 + 4];
          split8(tmp, xh[kk], xl[kk]);
        }
      }
      f4v gacc = {0.f,0.f,0.f,0.f};
      #pragma unroll
      for (int kk=0;kk<4;++kk){
        gacc = MFMA(ahi[kk], xh[kk], gacc);
        gacc = MFMA(ahi[kk], xl[kk], gacc);
        gacc = MFMA(alo[kk], xh[kk], gacc);
      }
      if (c==0){
        #pragma unroll
        for (int r=0;r<4;++r){
          if (rowC[r] < KK){
            float v = gacc[r] + xkc[r];
            L.gs[rowC[r]] = 1.0f/(1.0f + expf(-v));
          }
        }
      }
    }
    __syncthreads();   // A: gs ready, xs consumed

    // ======== P2: stage next x, combine, norm partials ========
    if (tid < EE) L.xs[tid] = nxv;
    float grow[4];
    #pragma unroll
    for (int r=0;r<4;++r) grow[r] = (rowC[r] < KK) ? L.gs[rowC[r]] : 0.f;
    float ns[2][4];
    #pragma unroll
    for (int r=0;r<4;++r){
      float s2 = 0.f;
      #pragma unroll
      for (int nt=0;nt<2;++nt){
        float cv = (nt==0 ? acc0[r] : acc1[r]) + Creg[nt][r] + xwc[nt];
        cv = cv > 0.f ? cv : pa[nt]*cv;
        float n = so[nt][r] + grow[r]*cv;
        ns[nt][r] = n;
        s2 += n*n;
      }
      s2 += __shfl_xor(s2, 1);
      s2 += __shfl_xor(s2, 2);
      s2 += __shfl_xor(s2, 4);
      s2 += __shfl_xor(s2, 8);
      if (c==0) L.npart[w][rowC[r]] = s2;
    }
    __syncthreads();   // B: npart ready

    // ======== P3: inverse norms ========
    if (tid < KK){
      float s;
      if (tid < 16) s = L.npart[0][tid] + L.npart[1][tid] + L.npart[2][tid] + L.npart[3][tid];
      else          s = L.npart[4][tid] + L.npart[5][tid] + L.npart[6][tid] + L.npart[7][tid];
      L.nms[tid] = 1.0f/(sqrtf(s) + 1e-8f);
    }
    __syncthreads();   // C: nms ready

    // ======== P4: state update ========
    #pragma unroll
    for (int r=0;r<4;++r){
      if (rowC[r] < KK){
        float inv = L.nms[rowC[r]];
        #pragma unroll
        for (int nt=0;nt<2;++nt){
          float n = ns[nt][r];
          float v = (n > 0.f ? n : 1.0f) * inv;
          unsigned short hb = f2bf(v);
          float lo = v - bf2f(hb);
          L.shi[rowC[r]][col[nt]] = hb;
          L.slo[rowC[r]][col[nt]] = f2bf(lo);
        }
      }
    }
    #pragma unroll
    for (int nt=0;nt<2;++nt) xwc[nt] = xwn[nt];
    #pragma unroll
    for (int r=0;r<4;++r) xkc[r] = xkn[r];
    __syncthreads();   // D: state writes visible
  }

  // ---------------- tail: rebuild f32 state, then attention + u + z ----------------
  for (int idx=tid; idx<KK*EE; idx+=512){
    int row=idx>>7, e=idx&127;
    L.sf[idx] = bf2f(L.shi[row][e]) + bf2f(L.slo[row][e]);
  }
  __syncthreads();

  int f    = tid & 127;
  int ec   = tid >> 7;
  int half = (tid >> 6) & 1;
  int lane_t = tid & 63;
  float pat = prelu_a[f];

  float qv = qenc[(size_t)b*EE + f];
  #pragma unroll
  for (int kk=0; kk<5; ++kk){
    float p = qv * L.sf[(kk*4+ec)*EE + f];
    #pragma unroll
    for (int off=32; off; off>>=1) p += __shfl_xor(p, off);
    if (lane_t == 0) L.gp[(kk*4+ec)*2 + half] = p;
  }
  __syncthreads();
  if (tid == 0) {
    float mx = -1e30f;
    float gg[KK];
    for (int k=0;k<KK;++k){ float v = L.gp[k*2]+L.gp[k*2+1]; gg[k]=v; mx = fmaxf(mx, v); }
    float s = 0.f;
    for (int k=0;k<KK;++k){ float e_ = expf(gg[k]-mx); gg[k]=e_; s += e_; }
    for (int k=0;k<KK;++k) L.gs[k] = gg[k]/s;
  }
  __syncthreads();
  if (tid < EE) {
    float u_ = 0.f;
    #pragma unroll
    for (int k=0;k<KK;++k) u_ += L.gs[k]*L.sf[k*EE + tid];
    L.xs[tid] = u_;
  }
  __syncthreads();
  {
    float hp = 0.f;
    const float* hr = H + (size_t)f*EE + ec*32;
    #pragma unroll
    for (int i=0;i<8;++i){
      float4 h4 = *(const float4*)(hr + i*4);
      float4 u4 = *(const float4*)(&L.xs[ec*32 + i*4]);
      hp += h4.x*u4.x + h4.y*u4.y + h4.z*u4.z + h4.w*u4.w;
    }
    L.tpart[ec*EE + f] = hp;
  }
  __syncthreads();
  if (tid < EE) {
    float zv = qv + L.tpart[0*EE+tid] + L.tpart[1*EE+tid] + L.tpart[2*EE+tid] + L.tpart[3*EE+tid];
    zv = zv > 0.f ? zv : pat*zv;
    zout[(size_t)b*EE + tid] = zv;
  }
}

// ---------------- kernel 5: y = z @ R^T ----------------
__global__ __launch_bounds__(256) void k_out(
    const float* __restrict__ z, const float* __restrict__ R,
    float* __restrict__ y)
{
  __shared__ float zs[64*EE];
  int tid = threadIdx.x;
  int rb = blockIdx.y*64;
  for (int i=0;i<8;++i){
    int idx = tid + i*256; int r = idx>>5; int c4 = (idx&31)*4;
    *(float4*)(zs + r*EE + c4) = *(const float4*)(z + (size_t)(rb+r)*EE + c4);
  }
  __syncthreads();
  int c0 = blockIdx.x*128 + (tid&31)*4;
  int r0 = (tid>>5)*8;
  float acc[8][4];
  #pragma unroll
  for (int i=0;i<8;++i)
    #pragma unroll
    for (int j=0;j<4;++j) acc[i][j]=0.f;

  const float* rp[4];
  #pragma unroll
  for (int cc=0;cc<4;++cc){ int colq = c0+cc; if (colq >= VOCAB) colq = 0; rp[cc] = R + (size_t)colq*EE; }

  for (int e4=0; e4<EE; e4+=4) {
    float4 rv[4];
    #pragma unroll
    for (int cc=0;cc<4;++cc) rv[cc] = *(const float4*)(rp[cc] + e4);
    #pragma unroll
    for (int rr=0;rr<8;++rr){
      float4 x4 = *(const float4*)(zs + (r0+rr)*EE + e4);
      #pragma unroll
      for (int cc=0;cc<4;++cc)
        acc[rr][cc] += x4.x*rv[cc].x + x4.y*rv[cc].y + x4.z*rv[cc].z + x4.w*rv[cc].w;
    }
  }
  #pragma unroll
  for (int rr=0;rr<8;++rr){
    int row = rb + r0 + rr;
    if (c0 + 3 < VOCAB) {
      *(float4*)(y + (size_t)row*VOCAB + c0) =
          make_float4(acc[rr][0], acc[rr][1], acc[rr][2], acc[rr][3]);
    } else {
      for (int cc=0;cc<4;++cc){ int colq = c0+cc; if (colq < VOCAB) y[(size_t)row*VOCAB + colq] = acc[rr][cc]; }
    }
  }
}

// ---------------- launch ----------------
extern "C" void kernel_launch(void* const* d_in, const int* in_sizes, int n_in,
                              void* d_out, int out_size, void* d_ws, size_t ws_size,
                              hipStream_t stream)
{
  const int*   story = (const int*)d_in[0];
  const int*   query = (const int*)d_in[1];
  const float* emb   = (const float*)d_in[2];
  const float* smask = (const float*)d_in[3];
  const float* qmask = (const float*)d_in[4];
  const float* pa    = (const float*)d_in[5];
  const float* U     = (const float*)d_in[6];
  const float* V     = (const float*)d_in[7];
  const float* W     = (const float*)d_in[8];
  const float* bias  = (const float*)d_in[9];
  const float* H     = (const float*)d_in[10];
  const float* R     = (const float*)d_in[11];
  float* y  = (float*)d_out;
  float* ws = (float*)d_ws;

  float* s_enc = ws + OFF_SENC;
  float* q_enc = ws + OFF_QENC;
  float* Ckf   = ws + OFF_CKF;
  float* xw    = ws + OFF_XW;
  float* z     = ws + OFF_Z;
  float* xk    = ws + OFF_XK;

  k_embed_sum<<<dim3(BB*TT/8), 256, 0, stream>>>(story, emb, smask, s_enc, BB*TT, SS);
  k_embed_sum<<<dim3(BB/8),    256, 0, stream>>>(query, emb, qmask, q_enc, BB, QQ);
  k_ckf<<<dim3(KK), 128, 0, stream>>>(emb, V, bias, Ckf);
  k_xw<<<dim3(BB*TT/64), 256, 0, stream>>>(s_enc, W, emb, xw, xk);

  k_scan<<<dim3(BB), 512, 0, stream>>>(emb, U, s_enc, xw, xk, Ckf, pa, q_enc, H, z);

  k_out<<<dim3((VOCAB+127)/128, BB/64), 256, 0, stream>>>(z, R, y);
}

// Round 5
// 816.118 us; speedup vs baseline: 1.3517x; 1.0107x over previous
//
#include <hip/hip_runtime.h>
#include <hip/hip_bf16.h>

#define BB 256
#define TT 128
#define SS 16
#define QQ 16
#define EE 128
#define KK 20
#define VOCAB 50020

typedef __attribute__((ext_vector_type(8))) short s8v;   // 8 bf16 (4 VGPR)
typedef __attribute__((ext_vector_type(4))) float f4v;   // MFMA acc
#define MFMA(a,b,c) __builtin_amdgcn_mfma_f32_16x16x32_bf16(a,b,c,0,0,0)

static __device__ __forceinline__ unsigned short f2bf(float x){
  unsigned u = __float_as_uint(x);
  unsigned r = (u + 0x7fffu + ((u>>16)&1u)) >> 16;
  return (unsigned short)r;
}
static __device__ __forceinline__ float bf2f(unsigned short h){
  return __uint_as_float(((unsigned)h)<<16);
}
// 3-term split: v = hi + mid + lo + O(2^-24 |v|)
static __device__ __forceinline__ void split3(float v, unsigned short& hb,
                                              unsigned short& mb, unsigned short& lb){
  hb = f2bf(v);
  float r1 = v - bf2f(hb);
  mb = f2bf(r1);
  float r2 = r1 - bf2f(mb);
  lb = f2bf(r2);
}
static __device__ __forceinline__ void split3_8(const float* v, s8v& h, s8v& m_, s8v& l){
  #pragma unroll
  for (int j=0;j<8;++j){
    unsigned short hb, mb, lb;
    split3(v[j], hb, mb, lb);
    h[j]=(short)hb; m_[j]=(short)mb; l[j]=(short)lb;
  }
}

// fragment-major state index: (row, e) -> ushort index
// m=row>>4, c=row&15, kk=e>>5, q=(e>>3)&3, j=e&7
static __device__ __forceinline__ int frag_idx(int row, int e){
  int m=row>>4, c=row&15, kk=e>>5, q=(e>>3)&3, j=e&7;
  return ((((m*4+kk)*4+q)*16)+c)*8 + j;
}

// ---------------- workspace layout (floats) ----------------
static const size_t OFF_SENC = 0;                              // B*T*E
static const size_t OFF_QENC = OFF_SENC + (size_t)BB*TT*EE;    // B*E
static const size_t OFF_CKF  = OFF_QENC + (size_t)BB*EE;       // K*E
static const size_t OFF_XW   = OFF_CKF  + (size_t)KK*EE;       // B*T*E
static const size_t OFF_Z    = OFF_XW   + (size_t)BB*TT*EE;    // B*E
static const size_t OFF_XK   = OFF_Z    + (size_t)BB*EE;       // B*T*K

// ---------------- kernel 1: embedding bag-sum ----------------
__global__ __launch_bounds__(256) void k_embed_sum(
    const int* __restrict__ tok, const float* __restrict__ emb,
    const float* __restrict__ mask, float* __restrict__ out,
    int nrow, int ntok)
{
  int tid = threadIdx.x;
  int row = blockIdx.x*8 + (tid>>5);
  if (row >= nrow) return;
  int e4 = (tid&31)*4;
  float4 acc = make_float4(0.f,0.f,0.f,0.f);
  for (int s=0; s<ntok; ++s) {
    int id = tok[row*ntok + s];
    float4 ev = *(const float4*)(emb + (size_t)id*EE + e4);
    float4 mv = *(const float4*)(mask + s*EE + e4);
    acc.x += ev.x*mv.x; acc.y += ev.y*mv.y; acc.z += ev.z*mv.z; acc.w += ev.w*mv.w;
  }
  *(float4*)(out + (size_t)row*EE + e4) = acc;
}

// ---------------- kernel 2: Ckf[k][f] = bias[f] + keys[k] . V[f] ----------------
__global__ __launch_bounds__(128) void k_ckf(
    const float* __restrict__ emb, const float* __restrict__ V,
    const float* __restrict__ bias, float* __restrict__ Ckf)
{
  int k = blockIdx.x;
  int f = threadIdx.x;
  const float* key = emb + (size_t)(VOCAB-KK+k)*EE;
  const float* vr  = V + (size_t)f*EE;
  float acc = bias[f];
  for (int e=0; e<EE; e+=4) {
    float4 kv = *(const float4*)(key + e);
    float4 vv = *(const float4*)(vr + e);
    acc += kv.x*vv.x + kv.y*vv.y + kv.z*vv.z + kv.w*vv.w;
  }
  Ckf[k*EE + f] = acc;
}

// ---------------- kernel 3: xw = senc@W^T  and  xk = senc@keys^T ----------------
__global__ __launch_bounds__(256) void k_xw(
    const float* __restrict__ senc, const float* __restrict__ W,
    const float* __restrict__ emb, float* __restrict__ xw,
    float* __restrict__ xk)
{
  __shared__ float xs[64*EE];
  __shared__ float keys_s[KK*EE];
  int tid = threadIdx.x;
  int r0 = blockIdx.x*64;
  for (int i=0;i<8;++i){
    int idx = tid + i*256; int r = idx>>5; int c4 = (idx&31)*4;
    *(float4*)(xs + r*EE + c4) = *(const float4*)(senc + (size_t)(r0+r)*EE + c4);
  }
  for (int idx=tid; idx<KK*EE; idx+=256)
    keys_s[idx] = emb[(size_t)(VOCAB-KK + (idx>>7))*EE + (idx&127)];
  __syncthreads();
  int f  = tid & 127;
  int rh = tid >> 7;
  float acc[32];
  #pragma unroll
  for (int i=0;i<32;++i) acc[i]=0.f;
  const float* wr = W + (size_t)f*EE;
  for (int e4=0; e4<EE; e4+=4) {
    float4 w4 = *(const float4*)(wr + e4);
    #pragma unroll
    for (int rr=0; rr<32; ++rr) {
      float4 x4 = *(const float4*)(xs + (rh*32+rr)*EE + e4);
      acc[rr] += w4.x*x4.x + w4.y*x4.y + w4.z*x4.z + w4.w*x4.w;
    }
  }
  #pragma unroll
  for (int rr=0; rr<32; ++rr)
    xw[(size_t)(r0 + rh*32 + rr)*EE + f] = acc[rr];
  for (int i=0;i<5;++i){
    int task = tid + i*256;
    int r = task/KK, k = task - r*KK;
    float a = 0.f;
    for (int e=0; e<EE; e+=4){
      float4 x4 = *(const float4*)(xs + r*EE + e);
      float4 k4 = *(const float4*)(keys_s + k*EE + e);
      a += x4.x*k4.x + x4.y*k4.y + x4.z*k4.z + x4.w*k4.w;
    }
    xk[(size_t)(r0+r)*KK + k] = a;
  }
}

// ---------------- kernel 4: MFMA scan, fragment-major LDS, 3-term split ----------------
struct ScanLds {
  unsigned short shi[2*4*4*16*8];   // 8 KB frag-major state hi
  unsigned short smd[2*4*4*16*8];   // 8 KB mid
  unsigned short slo[2*4*4*16*8];   // 8 KB lo
  float xs[EE];                     // x_t f32 (tail reuse)
  unsigned short xhi[EE];
  unsigned short xmd[EE];
  unsigned short xlo[EE];
  float gs[32];
  float npart[8][32];
  float sf[KK*EE];                  // tail f32 state
  float gp[64];
  float tpart[4*EE];
};

__global__ __launch_bounds__(512) void k_scan(
    const float* __restrict__ emb, const float* __restrict__ U,
    const float* __restrict__ senc, const float* __restrict__ xw,
    const float* __restrict__ xk, const float* __restrict__ Ckf,
    const float* __restrict__ prelu_a, const float* __restrict__ qenc,
    const float* __restrict__ H, float* __restrict__ zout)
{
  __shared__ ScanLds L;
  int tid = threadIdx.x;
  int b   = blockIdx.x;
  int l   = tid & 63;
  int w   = tid >> 6;
  int cg  = w & 3;
  int m   = w >> 2;
  int q   = l >> 4;
  int c   = l & 15;
  bool isGate = (cg == 0);

  int rowC[4];
  #pragma unroll
  for (int r=0;r<4;++r) rowC[r] = 16*m + 4*q + r;
  int col[2];
  #pragma unroll
  for (int nt=0;nt<2;++nt) col[nt] = cg*32 + nt*16 + c;

  // A-frag read offsets (ushort idx), lane-linear: conflict-free b128
  int aoff[4];
  #pragma unroll
  for (int kk=0;kk<4;++kk) aoff[kk] = (((m*4+kk)*4+q)*16 + c)*8;
  // state-write offsets: (row=16m+4q+r, e=cg*32+nt*16+c)
  int woff[2];
  #pragma unroll
  for (int nt=0;nt<2;++nt)
    woff[nt] = ((m*16 + cg*4 + nt*2 + (c>>3))*16 + 4*q)*8 + (c&7);

  // ---- init state (keys, 3-term split; pad rows 20-31 zero) ----
  if (tid < 32) L.gs[tid] = 0.f;
  for (int idx=tid; idx<32*EE; idx+=512){
    int row=idx>>7, e=idx&127;
    unsigned short hb=0, mb=0, lb=0;
    if (row < KK){
      float v = emb[(size_t)(VOCAB-KK+row)*EE + e];
      split3(v, hb, mb, lb);
    }
    int au = frag_idx(row, e);
    L.shi[au] = hb;
    L.smd[au] = mb;
    L.slo[au] = lb;
  }
  // ---- B-frags: U columns 3-term, constant across scan ----
  s8v bhi[2][4], bmd[2][4], blo[2][4];
  #pragma unroll
  for (int nt=0;nt<2;++nt)
    #pragma unroll
    for (int kk=0;kk<4;++kk){
      float tmp[8];
      const float* up = U + (size_t)col[nt]*EE + kk*32 + q*8;
      *(float4*)&tmp[0] = *(const float4*)up;
      *(float4*)&tmp[4] = *(const float4*)(up+4);
      split3_8(tmp, bhi[nt][kk], bmd[nt][kk], blo[nt][kk]);
    }
  // ---- per-lane constants ----
  float Creg[2][4], pa[2];
  #pragma unroll
  for (int nt=0;nt<2;++nt){
    pa[nt] = prelu_a[col[nt]];
    #pragma unroll
    for (int r=0;r<4;++r)
      Creg[nt][r] = (rowC[r] < KK) ? Ckf[rowC[r]*EE + col[nt]] : 0.f;
  }
  // ---- old-state-at-own-C carried in registers (exact f32) ----
  float so[2][4];
  #pragma unroll
  for (int nt=0;nt<2;++nt)
    #pragma unroll
    for (int r=0;r<4;++r)
      so[nt][r] = (rowC[r] < KK) ? emb[(size_t)(VOCAB-KK+rowC[r])*EE + col[nt]] : 0.f;

  const float* xrow  = senc + (size_t)b*TT*EE;
  const float* xwrow = xw   + (size_t)b*TT*EE;
  const float* xkrow = xk   + (size_t)b*TT*KK;

  // t=0 staging
  if (tid < EE){
    float v = xrow[tid];
    L.xs[tid] = v;
    unsigned short hb, mb, lb;
    split3(v, hb, mb, lb);
    L.xhi[tid] = hb; L.xmd[tid] = mb; L.xlo[tid] = lb;
  }
  float xwc[2];
  #pragma unroll
  for (int nt=0;nt<2;++nt) xwc[nt] = xwrow[col[nt]];
  float xkc[4] = {0.f,0.f,0.f,0.f};
  if (isGate){
    #pragma unroll
    for (int r=0;r<4;++r) if (rowC[r] < KK) xkc[r] = xkrow[rowC[r]];
  }
  __syncthreads();

  for (int t=0; t<TT; ++t) {
    // ======== P1: A-frags + MFMAs; gate; prefetch t+1 ========
    float nxv = 0.f, xwn[2] = {0.f,0.f}, xkn[4] = {0.f,0.f,0.f,0.f};
    if (t+1 < TT){
      if (tid < EE) nxv = xrow[(size_t)(t+1)*EE + tid];
      #pragma unroll
      for (int nt=0;nt<2;++nt) xwn[nt] = xwrow[(size_t)(t+1)*EE + col[nt]];
      if (isGate){
        #pragma unroll
        for (int r=0;r<4;++r) if (rowC[r] < KK) xkn[r] = xkrow[(size_t)(t+1)*KK + rowC[r]];
      }
    }
    s8v ahi[4], amd[4], alo[4];
    #pragma unroll
    for (int kk=0;kk<4;++kk){
      ahi[kk] = *(const s8v*)&L.shi[aoff[kk]];
      amd[kk] = *(const s8v*)&L.smd[aoff[kk]];
      alo[kk] = *(const s8v*)&L.slo[aoff[kk]];
    }
    // 6-term split product (terms down to 2^-16; drop <=2^-24)
    f4v acc0 = {0.f,0.f,0.f,0.f}, acc1 = {0.f,0.f,0.f,0.f};
    #pragma unroll
    for (int kk=0;kk<4;++kk){
      acc0 = MFMA(alo[kk], bhi[0][kk], acc0);
      acc1 = MFMA(alo[kk], bhi[1][kk], acc1);
      acc0 = MFMA(amd[kk], bmd[0][kk], acc0);
      acc1 = MFMA(amd[kk], bmd[1][kk], acc1);
      acc0 = MFMA(ahi[kk], blo[0][kk], acc0);
      acc1 = MFMA(ahi[kk], blo[1][kk], acc1);
      acc0 = MFMA(amd[kk], bhi[0][kk], acc0);
      acc1 = MFMA(amd[kk], bhi[1][kk], acc1);
      acc0 = MFMA(ahi[kk], bmd[0][kk], acc0);
      acc1 = MFMA(ahi[kk], bmd[1][kk], acc1);
      acc0 = MFMA(ahi[kk], bhi[0][kk], acc0);
      acc1 = MFMA(ahi[kk], bhi[1][kk], acc1);
    }
    if (isGate){
      f4v gacc = {0.f,0.f,0.f,0.f};
      #pragma unroll
      for (int kk=0;kk<4;++kk){
        s8v xh = *(const s8v*)&L.xhi[kk*32 + q*8];
        s8v xm = *(const s8v*)&L.xmd[kk*32 + q*8];
        s8v xl = *(const s8v*)&L.xlo[kk*32 + q*8];
        gacc = MFMA(alo[kk], xh, gacc);
        gacc = MFMA(amd[kk], xm, gacc);
        gacc = MFMA(ahi[kk], xl, gacc);
        gacc = MFMA(amd[kk], xh, gacc);
        gacc = MFMA(ahi[kk], xm, gacc);
        gacc = MFMA(ahi[kk], xh, gacc);
      }
      if (c==0){
        #pragma unroll
        for (int r=0;r<4;++r){
          if (rowC[r] < KK){
            float v = gacc[r] + xkc[r];
            L.gs[rowC[r]] = 1.0f/(1.0f + expf(-v));
          }
        }
      }
    }
    __syncthreads();   // bar A: gs ready

    // ======== P2: combine -> ns -> norm partials ========
    f4v g4 = *(const f4v*)&L.gs[16*m + 4*q];
    float ns[2][4];
    #pragma unroll
    for (int r=0;r<4;++r){
      float s2 = 0.f;
      #pragma unroll
      for (int nt=0;nt<2;++nt){
        float cv = (nt==0 ? acc0[r] : acc1[r]) + Creg[nt][r] + xwc[nt];
        cv = cv > 0.f ? cv : pa[nt]*cv;
        float n = so[nt][r] + g4[r]*cv;
        ns[nt][r] = n;
        s2 += n*n;
      }
      s2 += __shfl_xor(s2, 1);
      s2 += __shfl_xor(s2, 2);
      s2 += __shfl_xor(s2, 4);
      s2 += __shfl_xor(s2, 8);
      if (c==0) L.npart[w][rowC[r]] = s2;
    }
    __syncthreads();   // bar B: npart ready

    // ======== P3: norms + state update + stage x_{t+1} ========
    {
      f4v p0 = *(const f4v*)&L.npart[m*4+0][16*m + 4*q];
      f4v p1 = *(const f4v*)&L.npart[m*4+1][16*m + 4*q];
      f4v p2 = *(const f4v*)&L.npart[m*4+2][16*m + 4*q];
      f4v p3 = *(const f4v*)&L.npart[m*4+3][16*m + 4*q];
      f4v s4 = p0+p1+p2+p3;
      #pragma unroll
      for (int r=0;r<4;++r){
        if (rowC[r] < KK){
          float inv = 1.0f/(sqrtf(s4[r]) + 1e-8f);
          #pragma unroll
          for (int nt=0;nt<2;++nt){
            float n = ns[nt][r];
            float v = (n > 0.f ? n : 1.0f) * inv;
            so[nt][r] = v;
            unsigned short hb, mb, lb;
            split3(v, hb, mb, lb);
            L.shi[woff[nt] + r*8] = hb;
            L.smd[woff[nt] + r*8] = mb;
            L.slo[woff[nt] + r*8] = lb;
          }
        }
      }
    }
    if (t+1 < TT && tid < EE){
      L.xs[tid] = nxv;
      unsigned short hb, mb, lb;
      split3(nxv, hb, mb, lb);
      L.xhi[tid] = hb; L.xmd[tid] = mb; L.xlo[tid] = lb;
    }
    #pragma unroll
    for (int nt=0;nt<2;++nt) xwc[nt] = xwn[nt];
    #pragma unroll
    for (int r=0;r<4;++r) xkc[r] = xkn[r];
    __syncthreads();   // bar C: state visible
  }

  // ---------------- tail: rebuild f32 state, attention + u + z ----------------
  for (int idx=tid; idx<KK*EE; idx+=512){
    int row=idx>>7, e=idx&127;
    int au = frag_idx(row, e);
    L.sf[idx] = bf2f(L.shi[au]) + bf2f(L.smd[au]) + bf2f(L.slo[au]);
  }
  __syncthreads();

  int f    = tid & 127;
  int ec   = tid >> 7;
  int half = (tid >> 6) & 1;
  int lane_t = tid & 63;
  float pat = prelu_a[f];

  float qv = qenc[(size_t)b*EE + f];
  #pragma unroll
  for (int kk=0; kk<5; ++kk){
    float p = qv * L.sf[(kk*4+ec)*EE + f];
    #pragma unroll
    for (int off=32; off; off>>=1) p += __shfl_xor(p, off);
    if (lane_t == 0) L.gp[(kk*4+ec)*2 + half] = p;
  }
  __syncthreads();
  if (tid == 0) {
    float mx = -1e30f;
    float gg[KK];
    for (int k=0;k<KK;++k){ float v = L.gp[k*2]+L.gp[k*2+1]; gg[k]=v; mx = fmaxf(mx, v); }
    float s = 0.f;
    for (int k=0;k<KK;++k){ float e_ = expf(gg[k]-mx); gg[k]=e_; s += e_; }
    for (int k=0;k<KK;++k) L.gs[k] = gg[k]/s;
  }
  __syncthreads();
  if (tid < EE) {
    float u_ = 0.f;
    #pragma unroll
    for (int k=0;k<KK;++k) u_ += L.gs[k]*L.sf[k*EE + tid];
    L.xs[tid] = u_;
  }
  __syncthreads();
  {
    float hp = 0.f;
    const float* hr = H + (size_t)f*EE + ec*32;
    #pragma unroll
    for (int i=0;i<8;++i){
      float4 h4 = *(const float4*)(hr + i*4);
      float4 u4 = *(const float4*)(&L.xs[ec*32 + i*4]);
      hp += h4.x*u4.x + h4.y*u4.y + h4.z*u4.z + h4.w*u4.w;
    }
    L.tpart[ec*EE + f] = hp;
  }
  __syncthreads();
  if (tid < EE) {
    float zv = qv + L.tpart[0*EE+tid] + L.tpart[1*EE+tid] + L.tpart[2*EE+tid] + L.tpart[3*EE+tid];
    zv = zv > 0.f ? zv : pat*zv;
    zout[(size_t)b*EE + tid] = zv;
  }
}

// ---------------- kernel 5: y = z @ R^T ----------------
__global__ __launch_bounds__(256) void k_out(
    const float* __restrict__ z, const float* __restrict__ R,
    float* __restrict__ y)
{
  __shared__ float zs[64*EE];
  int tid = threadIdx.x;
  int rb = blockIdx.y*64;
  for (int i=0;i<8;++i){
    int idx = tid + i*256; int r = idx>>5; int c4 = (idx&31)*4;
    *(float4*)(zs + r*EE + c4) = *(const float4*)(z + (size_t)(rb+r)*EE + c4);
  }
  __syncthreads();
  int c0 = blockIdx.x*128 + (tid&31)*4;
  int r0 = (tid>>5)*8;
  float acc[8][4];
  #pragma unroll
  for (int i=0;i<8;++i)
    #pragma unroll
    for (int j=0;j<4;++j) acc[i][j]=0.f;

  const float* rp[4];
  #pragma unroll
  for (int cc=0;cc<4;++cc){ int colq = c0+cc; if (colq >= VOCAB) colq = 0; rp[cc] = R + (size_t)colq*EE; }

  for (int e4=0; e4<EE; e4+=4) {
    float4 rv[4];
    #pragma unroll
    for (int cc=0;cc<4;++cc) rv[cc] = *(const float4*)(rp[cc] + e4);
    #pragma unroll
    for (int rr=0;rr<8;++rr){
      float4 x4 = *(const float4*)(zs + (r0+rr)*EE + e4);
      #pragma unroll
      for (int cc=0;cc<4;++cc)
        acc[rr][cc] += x4.x*rv[cc].x + x4.y*rv[cc].y + x4.z*rv[cc].z + x4.w*rv[cc].w;
    }
  }
  #pragma unroll
  for (int rr=0;rr<8;++rr){
    int row = rb + r0 + rr;
    if (c0 + 3 < VOCAB) {
      *(float4*)(y + (size_t)row*VOCAB + c0) =
          make_float4(acc[rr][0], acc[rr][1], acc[rr][2], acc[rr][3]);
    } else {
      for (int cc=0;cc<4;++cc){ int colq = c0+cc; if (colq < VOCAB) y[(size_t)row*VOCAB + colq] = acc[rr][cc]; }
    }
  }
}

// ---------------- launch ----------------
extern "C" void kernel_launch(void* const* d_in, const int* in_sizes, int n_in,
                              void* d_out, int out_size, void* d_ws, size_t ws_size,
                              hipStream_t stream)
{
  const int*   story = (const int*)d_in[0];
  const int*   query = (const int*)d_in[1];
  const float* emb   = (const float*)d_in[2];
  const float* smask = (const float*)d_in[3];
  const float* qmask = (const float*)d_in[4];
  const float* pa    = (const float*)d_in[5];
  const float* U     = (const float*)d_in[6];
  const float* V     = (const float*)d_in[7];
  const float* W     = (const float*)d_in[8];
  const float* bias  = (const float*)d_in[9];
  const float* H     = (const float*)d_in[10];
  const float* R     = (const float*)d_in[11];
  float* y  = (float*)d_out;
  float* ws = (float*)d_ws;

  float* s_enc = ws + OFF_SENC;
  float* q_enc = ws + OFF_QENC;
  float* Ckf   = ws + OFF_CKF;
  float* xw    = ws + OFF_XW;
  float* z     = ws + OFF_Z;
  float* xk    = ws + OFF_XK;

  k_embed_sum<<<dim3(BB*TT/8), 256, 0, stream>>>(story, emb, smask, s_enc, BB*TT, SS);
  k_embed_sum<<<dim3(BB/8),    256, 0, stream>>>(query, emb, qmask, q_enc, BB, QQ);
  k_ckf<<<dim3(KK), 128, 0, stream>>>(emb, V, bias, Ckf);
  k_xw<<<dim3(BB*TT/64), 256, 0, stream>>>(s_enc, W, emb, xw, xk);

  k_scan<<<dim3(BB), 512, 0, stream>>>(emb, U, s_enc, xw, xk, Ckf, pa, q_enc, H, z);

  k_out<<<dim3((VOCAB+127)/128, BB/64), 256, 0, stream>>>(z, R, y);
}

// Round 6
// 658.772 us; speedup vs baseline: 1.6746x; 1.2388x over previous
//
#include <hip/hip_runtime.h>
#include <hip/hip_bf16.h>
#include <stdint.h>

#define BB 256
#define TT 128
#define SS 16
#define QQ 16
#define EE 128
#define KK 20
#define VOCAB 50020
#define KB_ROWS 10   // k-rows per scan block (2 blocks per batch)

typedef __attribute__((ext_vector_type(8))) short s8v;            // 8 bf16
typedef __attribute__((ext_vector_type(4))) unsigned short u4h;   // 4 bf16 (b64)
typedef __attribute__((ext_vector_type(4))) float f4v;            // MFMA acc
#define MFMA(a,b,c) __builtin_amdgcn_mfma_f32_16x16x32_bf16(a,b,c,0,0,0)

static __device__ __forceinline__ unsigned short f2bf(float x){
  unsigned u = __float_as_uint(x);
  unsigned r = (u + 0x7fffu + ((u>>16)&1u)) >> 16;
  return (unsigned short)r;
}
static __device__ __forceinline__ float bf2f(unsigned short h){
  return __uint_as_float(((unsigned)h)<<16);
}
// 3-term split: v = hi + mid + lo + O(2^-24 |v|)
static __device__ __forceinline__ void split3(float v, unsigned short& hb,
                                              unsigned short& mb, unsigned short& lb){
  hb = f2bf(v);
  float r1 = v - bf2f(hb);
  mb = f2bf(r1);
  float r2 = r1 - bf2f(mb);
  lb = f2bf(r2);
}
static __device__ __forceinline__ void split3_8(const float* v, s8v& h, s8v& m_, s8v& l){
  #pragma unroll
  for (int j=0;j<8;++j){
    unsigned short hb, mb, lb;
    split3(v[j], hb, mb, lb);
    h[j]=(short)hb; m_[j]=(short)mb; l[j]=(short)lb;
  }
}
static __device__ __forceinline__ s8v cat8(u4h a, u4h b){
  union { u4h p[2]; s8v v; } u; u.p[0]=a; u.p[1]=b; return u.v;
}
// hardware transpose read: quarter-wave reads 128B region, lane gets column (l&15)
template<int IMM>
static __device__ __forceinline__ u4h tr_read(unsigned va){
  u4h d;
  asm volatile("ds_read_b64_tr_b16 %0, %1 offset:%c2" : "=v"(d) : "v"(va), "i"(IMM));
  return d;
}
// A-frag (state) for plane P, k-slice K4: j=0..3 then j=4..7
#define LDA(P,K4) cat8(tr_read<(P)*4096+(K4)*1024>(va), tr_read<(P)*4096+(K4)*1024+128>(va))

// ---------------- workspace layout (floats) ----------------
static const size_t OFF_SENC = 0;                              // B*T*E
static const size_t OFF_QENC = OFF_SENC + (size_t)BB*TT*EE;    // B*E
static const size_t OFF_CKF  = OFF_QENC + (size_t)BB*EE;       // K*E
static const size_t OFF_XW   = OFF_CKF  + (size_t)KK*EE;       // B*T*E
static const size_t OFF_Z    = OFF_XW   + (size_t)BB*TT*EE;    // B*E
static const size_t OFF_XK   = OFF_Z    + (size_t)BB*EE;       // B*T*K
static const size_t OFF_ST   = OFF_XK   + (size_t)BB*TT*KK;    // B*K*E

// ---------------- kernel 1: embedding bag-sum ----------------
__global__ __launch_bounds__(256) void k_embed_sum(
    const int* __restrict__ tok, const float* __restrict__ emb,
    const float* __restrict__ mask, float* __restrict__ out,
    int nrow, int ntok)
{
  int tid = threadIdx.x;
  int row = blockIdx.x*8 + (tid>>5);
  if (row >= nrow) return;
  int e4 = (tid&31)*4;
  float4 acc = make_float4(0.f,0.f,0.f,0.f);
  for (int s=0; s<ntok; ++s) {
    int id = tok[row*ntok + s];
    float4 ev = *(const float4*)(emb + (size_t)id*EE + e4);
    float4 mv = *(const float4*)(mask + s*EE + e4);
    acc.x += ev.x*mv.x; acc.y += ev.y*mv.y; acc.z += ev.z*mv.z; acc.w += ev.w*mv.w;
  }
  *(float4*)(out + (size_t)row*EE + e4) = acc;
}

// ---------------- kernel 2: Ckf[k][f] = bias[f] + keys[k] . V[f] ----------------
__global__ __launch_bounds__(128) void k_ckf(
    const float* __restrict__ emb, const float* __restrict__ V,
    const float* __restrict__ bias, float* __restrict__ Ckf)
{
  int k = blockIdx.x;
  int f = threadIdx.x;
  const float* key = emb + (size_t)(VOCAB-KK+k)*EE;
  const float* vr  = V + (size_t)f*EE;
  float acc = bias[f];
  for (int e=0; e<EE; e+=4) {
    float4 kv = *(const float4*)(key + e);
    float4 vv = *(const float4*)(vr + e);
    acc += kv.x*vv.x + kv.y*vv.y + kv.z*vv.z + kv.w*vv.w;
  }
  Ckf[k*EE + f] = acc;
}

// ---------------- kernel 3: xw = senc@W^T  and  xk = senc@keys^T ----------------
__global__ __launch_bounds__(256) void k_xw(
    const float* __restrict__ senc, const float* __restrict__ W,
    const float* __restrict__ emb, float* __restrict__ xw,
    float* __restrict__ xk)
{
  __shared__ float xs[64*EE];
  __shared__ float keys_s[KK*EE];
  int tid = threadIdx.x;
  int r0 = blockIdx.x*64;
  for (int i=0;i<8;++i){
    int idx = tid + i*256; int r = idx>>5; int c4 = (idx&31)*4;
    *(float4*)(xs + r*EE + c4) = *(const float4*)(senc + (size_t)(r0+r)*EE + c4);
  }
  for (int idx=tid; idx<KK*EE; idx+=256)
    keys_s[idx] = emb[(size_t)(VOCAB-KK + (idx>>7))*EE + (idx&127)];
  __syncthreads();
  int f  = tid & 127;
  int rh = tid >> 7;
  float acc[32];
  #pragma unroll
  for (int i=0;i<32;++i) acc[i]=0.f;
  const float* wr = W + (size_t)f*EE;
  for (int e4=0; e4<EE; e4+=4) {
    float4 w4 = *(const float4*)(wr + e4);
    #pragma unroll
    for (int rr=0; rr<32; ++rr) {
      float4 x4 = *(const float4*)(xs + (rh*32+rr)*EE + e4);
      acc[rr] += w4.x*x4.x + w4.y*x4.y + w4.z*x4.z + w4.w*x4.w;
    }
  }
  #pragma unroll
  for (int rr=0; rr<32; ++rr)
    xw[(size_t)(r0 + rh*32 + rr)*EE + f] = acc[rr];
  for (int i=0;i<5;++i){
    int task = tid + i*256;
    int r = task/KK, k = task - r*KK;
    float a = 0.f;
    for (int e=0; e<EE; e+=4){
      float4 x4 = *(const float4*)(xs + r*EE + e);
      float4 k4 = *(const float4*)(keys_s + k*EE + e);
      a += x4.x*k4.x + x4.y*k4.y + x4.z*k4.z + x4.w*k4.w;
    }
    xk[(size_t)(r0+r)*KK + k] = a;
  }
}

// ---------------- kernel 4: MFMA scan, tr-read state, K-split blocks ----------------
// grid = 2*BB blocks of 256 thr (4 waves). Block (b, kb) owns k rows
// kb*10..kb*10+9 (padded to 16-row M-tile). Wave cg owns 32 output cols.
// State in LDS as 3 bf16 planes st[plane][e][row16]:
//   writes: ds_write_b64 (rows 4q..4q+3 at col e) - conflict-free
//   reads:  ds_read_b64_tr_b16 - quarter-wave q reads e-rows kk*32+q*8+j, col c
// Gate: MFMA with B = x in ALL columns -> every lane holds raw gate for its rows.
// 2 barriers per step.
struct ScanLds {
  unsigned short st[3][EE][16];   // 12288 B (planes hi,mid,lo)
  unsigned short xp[3][EE];       // 768 B
  float npart[4][16];             // 256 B
};

__global__ __launch_bounds__(256) void k_scan(
    const float* __restrict__ emb, const float* __restrict__ U,
    const float* __restrict__ senc, const float* __restrict__ xw,
    const float* __restrict__ xk, const float* __restrict__ Ckf,
    const float* __restrict__ prelu_a, float* __restrict__ zst)
{
  __shared__ ScanLds L;
  int tid = threadIdx.x;
  int bid = blockIdx.x;
  int b   = bid >> 1, kb = bid & 1;
  int l   = tid & 63, cg = tid >> 6;
  int q   = l >> 4,  c  = l & 15;
  int col[2] = { cg*32 + c, cg*32 + 16 + c };

  // ---- zero state planes (pad rows stay 0 forever) ----
  for (int idx = tid; idx < 3*EE*16; idx += 256) ((unsigned short*)L.st)[idx] = 0;
  __syncthreads();
  // ---- init real rows: keys ----
  for (int idx = tid; idx < KB_ROWS*EE; idx += 256){
    int row = idx >> 7, e = idx & 127;
    float v = emb[(size_t)(VOCAB - KK + kb*KB_ROWS + row)*EE + e];
    unsigned short hb, mb, lb; split3(v, hb, mb, lb);
    L.st[0][e][row] = hb; L.st[1][e][row] = mb; L.st[2][e][row] = lb;
  }
  // ---- B-frags: U columns, 3-plane, constant across scan ----
  s8v bh[2][4], bm[2][4], bl[2][4];
  #pragma unroll
  for (int nt=0;nt<2;++nt)
    #pragma unroll
    for (int kk=0;kk<4;++kk){
      float tmp[8];
      const float* up = U + (size_t)col[nt]*EE + kk*32 + q*8;
      *(float4*)&tmp[0] = *(const float4*)up;
      *(float4*)&tmp[4] = *(const float4*)(up+4);
      split3_8(tmp, bh[nt][kk], bm[nt][kk], bl[nt][kk]);
    }
  // ---- per-lane constants + register-carried state at own C positions ----
  float Creg[2][4], pa2[2], so[2][4];
  #pragma unroll
  for (int nt=0;nt<2;++nt){
    pa2[nt] = prelu_a[col[nt]];
    #pragma unroll
    for (int r=0;r<4;++r){
      int lr = 4*q + r;
      bool real = lr < KB_ROWS;
      Creg[nt][r] = real ? Ckf[(kb*KB_ROWS+lr)*EE + col[nt]] : 0.f;
      so[nt][r]   = real ? emb[(size_t)(VOCAB-KK+kb*KB_ROWS+lr)*EE + col[nt]] : 0.f;
    }
  }

  const float* xrow  = senc + (size_t)b*TT*EE;
  const float* xwrow = xw   + (size_t)b*TT*EE;
  const float* xkrow = xk   + (size_t)b*TT*KK;

  // t=0 staging
  if (tid < EE){
    float v = xrow[tid];
    unsigned short hb,mb,lb; split3(v,hb,mb,lb);
    L.xp[0][tid]=hb; L.xp[1][tid]=mb; L.xp[2][tid]=lb;
  }
  float xwc[2] = { xwrow[col[0]], xwrow[col[1]] };
  float xkc[4];
  #pragma unroll
  for (int r=0;r<4;++r)
    xkc[r] = (4*q+r < KB_ROWS) ? xkrow[kb*KB_ROWS + 4*q + r] : 0.f;

  unsigned va = (unsigned)(uintptr_t)&L.st[0][0][0] + q*256 + c*8;
  __syncthreads();

  for (int t=0; t<TT; ++t){
    // ---- prefetch t+1 globals ----
    float nxv = 0.f, xwn[2] = {0.f,0.f}, xkn[4] = {0.f,0.f,0.f,0.f};
    if (t+1 < TT){
      if (tid < EE) nxv = xrow[(size_t)(t+1)*EE + tid];
      xwn[0] = xwrow[(size_t)(t+1)*EE + col[0]];
      xwn[1] = xwrow[(size_t)(t+1)*EE + col[1]];
      #pragma unroll
      for (int r=0;r<4;++r)
        if (4*q+r < KB_ROWS) xkn[r] = xkrow[(size_t)(t+1)*KK + kb*KB_ROWS + 4*q + r];
    }
    // ---- A-frags via hardware transpose reads ----
    s8v A0[4] = { LDA(0,0), LDA(0,1), LDA(0,2), LDA(0,3) };  // hi
    s8v A1[4] = { LDA(1,0), LDA(1,1), LDA(1,2), LDA(1,3) };  // mid
    s8v A2[4] = { LDA(2,0), LDA(2,1), LDA(2,2), LDA(2,3) };  // lo
    asm volatile("s_waitcnt lgkmcnt(0)" ::: "memory");
    __builtin_amdgcn_sched_barrier(0);

    f4v z4 = {0.f,0.f,0.f,0.f};
    f4v acc[2][2] = {{z4,z4},{z4,z4}};
    f4v gac[2] = {z4,z4};
    #pragma unroll
    for (int kk=0; kk<4; ++kk){
      int h = kk>>1;
      s8v xh = *(const s8v*)&L.xp[0][kk*32 + q*8];
      s8v xm = *(const s8v*)&L.xp[1][kk*32 + q*8];
      s8v xl = *(const s8v*)&L.xp[2][kk*32 + q*8];
      #pragma unroll
      for (int nt=0;nt<2;++nt){
        acc[nt][h] = MFMA(A2[kk], bh[nt][kk], acc[nt][h]);
        acc[nt][h] = MFMA(A1[kk], bm[nt][kk], acc[nt][h]);
        acc[nt][h] = MFMA(A0[kk], bl[nt][kk], acc[nt][h]);
        acc[nt][h] = MFMA(A1[kk], bh[nt][kk], acc[nt][h]);
        acc[nt][h] = MFMA(A0[kk], bm[nt][kk], acc[nt][h]);
        acc[nt][h] = MFMA(A0[kk], bh[nt][kk], acc[nt][h]);
      }
      gac[h] = MFMA(A2[kk], xh, gac[h]);
      gac[h] = MFMA(A1[kk], xm, gac[h]);
      gac[h] = MFMA(A0[kk], xl, gac[h]);
      gac[h] = MFMA(A1[kk], xh, gac[h]);
      gac[h] = MFMA(A0[kk], xm, gac[h]);
      gac[h] = MFMA(A0[kk], xh, gac[h]);
    }
    f4v acc0 = acc[0][0] + acc[0][1];
    f4v acc1 = acc[1][0] + acc[1][1];
    f4v gacc = gac[0] + gac[1];

    // ---- gate + ns + norm partials (no LDS for gate: every lane has it) ----
    float g4[4], ns[2][4], s2[4];
    #pragma unroll
    for (int r=0;r<4;++r){
      float graw = gacc[r] + xkc[r];
      g4[r] = 1.0f/(1.0f + expf(-graw));
      float s2r = 0.f;
      #pragma unroll
      for (int nt=0;nt<2;++nt){
        float cv = (nt ? acc1[r] : acc0[r]) + Creg[nt][r] + xwc[nt];
        cv = cv > 0.f ? cv : pa2[nt]*cv;
        float n = so[nt][r] + g4[r]*cv;
        ns[nt][r] = n;
        s2r += n*n;
      }
      s2r += __shfl_xor(s2r, 1);
      s2r += __shfl_xor(s2r, 2);
      s2r += __shfl_xor(s2r, 4);
      s2r += __shfl_xor(s2r, 8);
      s2[r] = s2r;
    }
    if (c == 0){
      f4v np; np[0]=s2[0]; np[1]=s2[1]; np[2]=s2[2]; np[3]=s2[3];
      *(f4v*)&L.npart[cg][4*q] = np;
    }
    __syncthreads();                              // barrier 1: npart ready

    // ---- norms + state update (b64 writes) + stage x_{t+1} ----
    f4v p0 = *(const f4v*)&L.npart[0][4*q];
    f4v p1 = *(const f4v*)&L.npart[1][4*q];
    f4v p2 = *(const f4v*)&L.npart[2][4*q];
    f4v p3 = *(const f4v*)&L.npart[3][4*q];
    f4v ss = p0 + p1 + p2 + p3;
    unsigned short pk[3][2][4];
    #pragma unroll
    for (int r=0;r<4;++r){
      bool real = (4*q + r) < KB_ROWS;
      float inv = 1.0f/(sqrtf(ss[r]) + 1e-8f);
      #pragma unroll
      for (int nt=0;nt<2;++nt){
        float n = ns[nt][r];
        float v = real ? ((n > 0.f ? n : 1.0f) * inv) : 0.f;
        so[nt][r] = v;
        unsigned short hb,mb,lb; split3(v,hb,mb,lb);
        pk[0][nt][r]=hb; pk[1][nt][r]=mb; pk[2][nt][r]=lb;
      }
    }
    #pragma unroll
    for (int p=0;p<3;++p)
      #pragma unroll
      for (int nt=0;nt<2;++nt){
        u4h wv = { pk[p][nt][0], pk[p][nt][1], pk[p][nt][2], pk[p][nt][3] };
        *(u4h*)&L.st[p][col[nt]][4*q] = wv;
      }
    if (t+1 < TT && tid < EE){
      unsigned short hb,mb,lb; split3(nxv,hb,mb,lb);
      L.xp[0][tid]=hb; L.xp[1][tid]=mb; L.xp[2][tid]=lb;
    }
    xwc[0]=xwn[0]; xwc[1]=xwn[1];
    #pragma unroll
    for (int r=0;r<4;++r) xkc[r]=xkn[r];
    __syncthreads();                              // barrier 2: state visible
  }

  // ---- final state writeback (exact f32 from registers) ----
  #pragma unroll
  for (int nt=0;nt<2;++nt)
    #pragma unroll
    for (int r=0;r<4;++r){
      int lr = 4*q + r;
      if (lr < KB_ROWS)
        zst[((size_t)b*KK + kb*KB_ROWS + lr)*EE + col[nt]] = so[nt][r];
    }
}

// ---------------- kernel 4b: tail (attention + u + z), needs all 20 k ----------------
__global__ __launch_bounds__(128) void k_tail(
    const float* __restrict__ zst, const float* __restrict__ qenc,
    const float* __restrict__ prelu_a, const float* __restrict__ H,
    float* __restrict__ zout)
{
  __shared__ float st[KK*EE];
  __shared__ float us[EE];
  __shared__ float red[2][KK];
  __shared__ float gs[KK];
  int b = blockIdx.x, tid = threadIdx.x;
  for (int i = tid; i < KK*EE; i += 128) st[i] = zst[(size_t)b*KK*EE + i];
  float qv = qenc[(size_t)b*EE + tid];
  __syncthreads();
  int wv = tid >> 6, ln = tid & 63;
  for (int k=0;k<KK;++k){
    float p = qv * st[k*EE + tid];
    #pragma unroll
    for (int off=32; off; off>>=1) p += __shfl_xor(p, off);
    if (ln == 0) red[wv][k] = p;
  }
  __syncthreads();
  if (tid == 0){
    float mx = -1e30f, gg[KK];
    for (int k=0;k<KK;++k){ float v = red[0][k]+red[1][k]; gg[k]=v; mx = fmaxf(mx, v); }
    float s = 0.f;
    for (int k=0;k<KK;++k){ float e_ = expf(gg[k]-mx); gg[k]=e_; s += e_; }
    for (int k=0;k<KK;++k) gs[k] = gg[k]/s;
  }
  __syncthreads();
  float u_ = 0.f;
  #pragma unroll
  for (int k=0;k<KK;++k) u_ += gs[k]*st[k*EE + tid];
  us[tid] = u_;
  __syncthreads();
  float hp = 0.f;
  const float* hr = H + (size_t)tid*EE;
  for (int e=0; e<EE; e+=4){
    float4 h4 = *(const float4*)(hr + e);
    float4 u4 = *(const float4*)(us + e);
    hp += h4.x*u4.x + h4.y*u4.y + h4.z*u4.z + h4.w*u4.w;
  }
  float zv = qv + hp;
  float pat = prelu_a[tid];
  zv = zv > 0.f ? zv : pat*zv;
  zout[(size_t)b*EE + tid] = zv;
}

// ---------------- kernel 5: y = z @ R^T ----------------
__global__ __launch_bounds__(256) void k_out(
    const float* __restrict__ z, const float* __restrict__ R,
    float* __restrict__ y)
{
  __shared__ float zs[64*EE];
  int tid = threadIdx.x;
  int rb = blockIdx.y*64;
  for (int i=0;i<8;++i){
    int idx = tid + i*256; int r = idx>>5; int c4 = (idx&31)*4;
    *(float4*)(zs + r*EE + c4) = *(const float4*)(z + (size_t)(rb+r)*EE + c4);
  }
  __syncthreads();
  int c0 = blockIdx.x*128 + (tid&31)*4;
  int r0 = (tid>>5)*8;
  float acc[8][4];
  #pragma unroll
  for (int i=0;i<8;++i)
    #pragma unroll
    for (int j=0;j<4;++j) acc[i][j]=0.f;

  const float* rp[4];
  #pragma unroll
  for (int cc=0;cc<4;++cc){ int colq = c0+cc; if (colq >= VOCAB) colq = 0; rp[cc] = R + (size_t)colq*EE; }

  for (int e4=0; e4<EE; e4+=4) {
    float4 rv[4];
    #pragma unroll
    for (int cc=0;cc<4;++cc) rv[cc] = *(const float4*)(rp[cc] + e4);
    #pragma unroll
    for (int rr=0;rr<8;++rr){
      float4 x4 = *(const float4*)(zs + (r0+rr)*EE + e4);
      #pragma unroll
      for (int cc=0;cc<4;++cc)
        acc[rr][cc] += x4.x*rv[cc].x + x4.y*rv[cc].y + x4.z*rv[cc].z + x4.w*rv[cc].w;
    }
  }
  #pragma unroll
  for (int rr=0;rr<8;++rr){
    int row = rb + r0 + rr;
    if (c0 + 3 < VOCAB) {
      *(float4*)(y + (size_t)row*VOCAB + c0) =
          make_float4(acc[rr][0], acc[rr][1], acc[rr][2], acc[rr][3]);
    } else {
      for (int cc=0;cc<4;++cc){ int colq = c0+cc; if (colq < VOCAB) y[(size_t)row*VOCAB + colq] = acc[rr][cc]; }
    }
  }
}

// ---------------- launch ----------------
extern "C" void kernel_launch(void* const* d_in, const int* in_sizes, int n_in,
                              void* d_out, int out_size, void* d_ws, size_t ws_size,
                              hipStream_t stream)
{
  const int*   story = (const int*)d_in[0];
  const int*   query = (const int*)d_in[1];
  const float* emb   = (const float*)d_in[2];
  const float* smask = (const float*)d_in[3];
  const float* qmask = (const float*)d_in[4];
  const float* pa    = (const float*)d_in[5];
  const float* U     = (const float*)d_in[6];
  const float* V     = (const float*)d_in[7];
  const float* W     = (const float*)d_in[8];
  const float* bias  = (const float*)d_in[9];
  const float* H     = (const float*)d_in[10];
  const float* R     = (const float*)d_in[11];
  float* y  = (float*)d_out;
  float* ws = (float*)d_ws;

  float* s_enc = ws + OFF_SENC;
  float* q_enc = ws + OFF_QENC;
  float* Ckf   = ws + OFF_CKF;
  float* xw    = ws + OFF_XW;
  float* z     = ws + OFF_Z;
  float* xk    = ws + OFF_XK;
  float* zst   = ws + OFF_ST;

  k_embed_sum<<<dim3(BB*TT/8), 256, 0, stream>>>(story, emb, smask, s_enc, BB*TT, SS);
  k_embed_sum<<<dim3(BB/8),    256, 0, stream>>>(query, emb, qmask, q_enc, BB, QQ);
  k_ckf<<<dim3(KK), 128, 0, stream>>>(emb, V, bias, Ckf);
  k_xw<<<dim3(BB*TT/64), 256, 0, stream>>>(s_enc, W, emb, xw, xk);

  k_scan<<<dim3(BB*2), 256, 0, stream>>>(emb, U, s_enc, xw, xk, Ckf, pa, zst);
  k_tail<<<dim3(BB), 128, 0, stream>>>(zst, q_enc, pa, H, z);

  k_out<<<dim3((VOCAB+127)/128, BB/64), 256, 0, stream>>>(z, R, y);
}

// Round 7
// 567.635 us; speedup vs baseline: 1.9434x; 1.1606x over previous
//
#include <hip/hip_runtime.h>
#include <hip/hip_bf16.h>
#include <stdint.h>

#define BB 256
#define TT 128
#define SS 16
#define QQ 16
#define EE 128
#define KK 20
#define VOCAB 50020
#define KB_ROWS 10   // k-rows per scan block (2 blocks per batch)

typedef __attribute__((ext_vector_type(8))) short s8v;            // 8 bf16
typedef __attribute__((ext_vector_type(4))) unsigned short u4h;   // 4 bf16 (b64)
typedef __attribute__((ext_vector_type(4))) float f4v;            // MFMA acc
#define MFMA(a,b,c) __builtin_amdgcn_mfma_f32_16x16x32_bf16(a,b,c,0,0,0)

static __device__ __forceinline__ unsigned short f2bf(float x){
  unsigned u = __float_as_uint(x);
  unsigned r = (u + 0x7fffu + ((u>>16)&1u)) >> 16;
  return (unsigned short)r;
}
static __device__ __forceinline__ float bf2f(unsigned short h){
  return __uint_as_float(((unsigned)h)<<16);
}
// 3-term split: v = hi + mid + lo + O(2^-24 |v|)
static __device__ __forceinline__ void split3(float v, unsigned short& hb,
                                              unsigned short& mb, unsigned short& lb){
  hb = f2bf(v);
  float r1 = v - bf2f(hb);
  mb = f2bf(r1);
  float r2 = r1 - bf2f(mb);
  lb = f2bf(r2);
}
static __device__ __forceinline__ void split3_8(const float* v, s8v& h, s8v& m_, s8v& l){
  #pragma unroll
  for (int j=0;j<8;++j){
    unsigned short hb, mb, lb;
    split3(v[j], hb, mb, lb);
    h[j]=(short)hb; m_[j]=(short)mb; l[j]=(short)lb;
  }
}
static __device__ __forceinline__ s8v cat8(u4h a, u4h b){
  union { u4h p[2]; s8v v; } u; u.p[0]=a; u.p[1]=b; return u.v;
}
// packed f32->bf16 pair: low16 = bf16(a), high16 = bf16(b)
static __device__ __forceinline__ unsigned cvt_pk(float a, float b){
  unsigned r;
  asm("v_cvt_pk_bf16_f32 %0, %1, %2" : "=v"(r) : "v"(a), "v"(b));
  return r;
}
static __device__ __forceinline__ float ubf(unsigned u){ return __uint_as_float(u); }

// hardware transpose read: quarter-wave reads 128B region, lane gets column (l&15)
template<int IMM>
static __device__ __forceinline__ u4h tr_read(unsigned va){
  u4h d;
  asm volatile("ds_read_b64_tr_b16 %0, %1 offset:%c2" : "=v"(d) : "v"(va), "i"(IMM));
  return d;
}
// A-frag (state) for plane P, k-slice K4: j=0..3 then j=4..7
#define LDA(P,K4) cat8(tr_read<(P)*4096+(K4)*1024>(va), tr_read<(P)*4096+(K4)*1024+128>(va))

// ---------------- workspace layout (floats) ----------------
static const size_t OFF_SENC = 0;                              // B*T*E
static const size_t OFF_QENC = OFF_SENC + (size_t)BB*TT*EE;    // B*E
static const size_t OFF_CKF  = OFF_QENC + (size_t)BB*EE;       // K*E
static const size_t OFF_XW   = OFF_CKF  + (size_t)KK*EE;       // B*T*E
static const size_t OFF_Z    = OFF_XW   + (size_t)BB*TT*EE;    // B*E
static const size_t OFF_XK   = OFF_Z    + (size_t)BB*EE;       // B*T*K
static const size_t OFF_ST   = OFF_XK   + (size_t)BB*TT*KK;    // B*K*E

// ---------------- kernel 1: embedding bag-sum ----------------
__global__ __launch_bounds__(256) void k_embed_sum(
    const int* __restrict__ tok, const float* __restrict__ emb,
    const float* __restrict__ mask, float* __restrict__ out,
    int nrow, int ntok)
{
  int tid = threadIdx.x;
  int row = blockIdx.x*8 + (tid>>5);
  if (row >= nrow) return;
  int e4 = (tid&31)*4;
  float4 acc = make_float4(0.f,0.f,0.f,0.f);
  for (int s=0; s<ntok; ++s) {
    int id = tok[row*ntok + s];
    float4 ev = *(const float4*)(emb + (size_t)id*EE + e4);
    float4 mv = *(const float4*)(mask + s*EE + e4);
    acc.x += ev.x*mv.x; acc.y += ev.y*mv.y; acc.z += ev.z*mv.z; acc.w += ev.w*mv.w;
  }
  *(float4*)(out + (size_t)row*EE + e4) = acc;
}

// ---------------- kernel 2: Ckf[k][f] = bias[f] + keys[k] . V[f] ----------------
__global__ __launch_bounds__(128) void k_ckf(
    const float* __restrict__ emb, const float* __restrict__ V,
    const float* __restrict__ bias, float* __restrict__ Ckf)
{
  int k = blockIdx.x;
  int f = threadIdx.x;
  const float* key = emb + (size_t)(VOCAB-KK+k)*EE;
  const float* vr  = V + (size_t)f*EE;
  float acc = bias[f];
  for (int e=0; e<EE; e+=4) {
    float4 kv = *(const float4*)(key + e);
    float4 vv = *(const float4*)(vr + e);
    acc += kv.x*vv.x + kv.y*vv.y + kv.z*vv.z + kv.w*vv.w;
  }
  Ckf[k*EE + f] = acc;
}

// ---------------- kernel 3: xw = senc@W^T  and  xk = senc@keys^T ----------------
__global__ __launch_bounds__(256) void k_xw(
    const float* __restrict__ senc, const float* __restrict__ W,
    const float* __restrict__ emb, float* __restrict__ xw,
    float* __restrict__ xk)
{
  __shared__ float xs[64*EE];
  __shared__ float keys_s[KK*EE];
  int tid = threadIdx.x;
  int r0 = blockIdx.x*64;
  for (int i=0;i<8;++i){
    int idx = tid + i*256; int r = idx>>5; int c4 = (idx&31)*4;
    *(float4*)(xs + r*EE + c4) = *(const float4*)(senc + (size_t)(r0+r)*EE + c4);
  }
  for (int idx=tid; idx<KK*EE; idx+=256)
    keys_s[idx] = emb[(size_t)(VOCAB-KK + (idx>>7))*EE + (idx&127)];
  __syncthreads();
  int f  = tid & 127;
  int rh = tid >> 7;
  float acc[32];
  #pragma unroll
  for (int i=0;i<32;++i) acc[i]=0.f;
  const float* wr = W + (size_t)f*EE;
  for (int e4=0; e4<EE; e4+=4) {
    float4 w4 = *(const float4*)(wr + e4);
    #pragma unroll
    for (int rr=0; rr<32; ++rr) {
      float4 x4 = *(const float4*)(xs + (rh*32+rr)*EE + e4);
      acc[rr] += w4.x*x4.x + w4.y*x4.y + w4.z*x4.z + w4.w*x4.w;
    }
  }
  #pragma unroll
  for (int rr=0; rr<32; ++rr)
    xw[(size_t)(r0 + rh*32 + rr)*EE + f] = acc[rr];
  for (int i=0;i<5;++i){
    int task = tid + i*256;
    int r = task/KK, k = task - r*KK;
    float a = 0.f;
    for (int e=0; e<EE; e+=4){
      float4 x4 = *(const float4*)(xs + r*EE + e);
      float4 k4 = *(const float4*)(keys_s + k*EE + e);
      a += x4.x*k4.x + x4.y*k4.y + x4.z*k4.z + x4.w*k4.w;
    }
    xk[(size_t)(r0+r)*KK + k] = a;
  }
}

// ---------------- kernel 4: MFMA scan, tr-read state, K-split blocks ----------------
// Same structure as R6 (validated). R7: VALU diet — cvt_pk split, exp2 sigmoid,
// rcp/sqrt builtins.
struct ScanLds {
  unsigned short st[3][EE][16];   // 12288 B (planes hi,mid,lo)
  unsigned short xp[3][EE];       // 768 B
  float npart[4][16];             // 256 B
};

__global__ __launch_bounds__(256) void k_scan(
    const float* __restrict__ emb, const float* __restrict__ U,
    const float* __restrict__ senc, const float* __restrict__ xw,
    const float* __restrict__ xk, const float* __restrict__ Ckf,
    const float* __restrict__ prelu_a, float* __restrict__ zst)
{
  __shared__ ScanLds L;
  int tid = threadIdx.x;
  int bid = blockIdx.x;
  int b   = bid >> 1, kb = bid & 1;
  int l   = tid & 63, cg = tid >> 6;
  int q   = l >> 4,  c  = l & 15;
  int col[2] = { cg*32 + c, cg*32 + 16 + c };

  // ---- zero state planes (pad rows stay 0 forever) ----
  for (int idx = tid; idx < 3*EE*16; idx += 256) ((unsigned short*)L.st)[idx] = 0;
  __syncthreads();
  // ---- init real rows: keys ----
  for (int idx = tid; idx < KB_ROWS*EE; idx += 256){
    int row = idx >> 7, e = idx & 127;
    float v = emb[(size_t)(VOCAB - KK + kb*KB_ROWS + row)*EE + e];
    unsigned short hb, mb, lb; split3(v, hb, mb, lb);
    L.st[0][e][row] = hb; L.st[1][e][row] = mb; L.st[2][e][row] = lb;
  }
  // ---- B-frags: U columns, 3-plane, constant across scan ----
  s8v bh[2][4], bm[2][4], bl[2][4];
  #pragma unroll
  for (int nt=0;nt<2;++nt)
    #pragma unroll
    for (int kk=0;kk<4;++kk){
      float tmp[8];
      const float* up = U + (size_t)col[nt]*EE + kk*32 + q*8;
      *(float4*)&tmp[0] = *(const float4*)up;
      *(float4*)&tmp[4] = *(const float4*)(up+4);
      split3_8(tmp, bh[nt][kk], bm[nt][kk], bl[nt][kk]);
    }
  // ---- per-lane constants + register-carried state at own C positions ----
  float Creg[2][4], pa2[2], so[2][4];
  #pragma unroll
  for (int nt=0;nt<2;++nt){
    pa2[nt] = prelu_a[col[nt]];
    #pragma unroll
    for (int r=0;r<4;++r){
      int lr = 4*q + r;
      bool real = lr < KB_ROWS;
      Creg[nt][r] = real ? Ckf[(kb*KB_ROWS+lr)*EE + col[nt]] : 0.f;
      so[nt][r]   = real ? emb[(size_t)(VOCAB-KK+kb*KB_ROWS+lr)*EE + col[nt]] : 0.f;
    }
  }

  const float* xrow  = senc + (size_t)b*TT*EE;
  const float* xwrow = xw   + (size_t)b*TT*EE;
  const float* xkrow = xk   + (size_t)b*TT*KK;

  // t=0 staging
  if (tid < EE){
    float v = xrow[tid];
    unsigned short hb,mb,lb; split3(v,hb,mb,lb);
    L.xp[0][tid]=hb; L.xp[1][tid]=mb; L.xp[2][tid]=lb;
  }
  float xwc[2] = { xwrow[col[0]], xwrow[col[1]] };
  float xkc[4];
  #pragma unroll
  for (int r=0;r<4;++r)
    xkc[r] = (4*q+r < KB_ROWS) ? xkrow[kb*KB_ROWS + 4*q + r] : 0.f;

  unsigned va = (unsigned)(uintptr_t)&L.st[0][0][0] + q*256 + c*8;
  __syncthreads();

  for (int t=0; t<TT; ++t){
    // ---- prefetch t+1 globals ----
    float nxv = 0.f, xwn[2] = {0.f,0.f}, xkn[4] = {0.f,0.f,0.f,0.f};
    if (t+1 < TT){
      if (tid < EE) nxv = xrow[(size_t)(t+1)*EE + tid];
      xwn[0] = xwrow[(size_t)(t+1)*EE + col[0]];
      xwn[1] = xwrow[(size_t)(t+1)*EE + col[1]];
      #pragma unroll
      for (int r=0;r<4;++r)
        if (4*q+r < KB_ROWS) xkn[r] = xkrow[(size_t)(t+1)*KK + kb*KB_ROWS + 4*q + r];
    }
    // ---- A-frags via hardware transpose reads ----
    s8v A0[4] = { LDA(0,0), LDA(0,1), LDA(0,2), LDA(0,3) };  // hi
    s8v A1[4] = { LDA(1,0), LDA(1,1), LDA(1,2), LDA(1,3) };  // mid
    s8v A2[4] = { LDA(2,0), LDA(2,1), LDA(2,2), LDA(2,3) };  // lo
    asm volatile("s_waitcnt lgkmcnt(0)" ::: "memory");
    __builtin_amdgcn_sched_barrier(0);

    f4v z4 = {0.f,0.f,0.f,0.f};
    f4v acc[2][2] = {{z4,z4},{z4,z4}};
    f4v gac[2] = {z4,z4};
    #pragma unroll
    for (int kk=0; kk<4; ++kk){
      int h = kk>>1;
      s8v xh = *(const s8v*)&L.xp[0][kk*32 + q*8];
      s8v xm = *(const s8v*)&L.xp[1][kk*32 + q*8];
      s8v xl = *(const s8v*)&L.xp[2][kk*32 + q*8];
      #pragma unroll
      for (int nt=0;nt<2;++nt){
        acc[nt][h] = MFMA(A2[kk], bh[nt][kk], acc[nt][h]);
        acc[nt][h] = MFMA(A1[kk], bm[nt][kk], acc[nt][h]);
        acc[nt][h] = MFMA(A0[kk], bl[nt][kk], acc[nt][h]);
        acc[nt][h] = MFMA(A1[kk], bh[nt][kk], acc[nt][h]);
        acc[nt][h] = MFMA(A0[kk], bm[nt][kk], acc[nt][h]);
        acc[nt][h] = MFMA(A0[kk], bh[nt][kk], acc[nt][h]);
      }
      gac[h] = MFMA(A2[kk], xh, gac[h]);
      gac[h] = MFMA(A1[kk], xm, gac[h]);
      gac[h] = MFMA(A0[kk], xl, gac[h]);
      gac[h] = MFMA(A1[kk], xh, gac[h]);
      gac[h] = MFMA(A0[kk], xm, gac[h]);
      gac[h] = MFMA(A0[kk], xh, gac[h]);
    }
    f4v acc0 = acc[0][0] + acc[0][1];
    f4v acc1 = acc[1][0] + acc[1][1];
    f4v gacc = gac[0] + gac[1];

    // ---- gate + ns + norm partials (fast sigmoid: exp2 + rcp) ----
    float g4[4], ns[2][4], s2[4];
    #pragma unroll
    for (int r=0;r<4;++r){
      float graw = gacc[r] + xkc[r];
      g4[r] = __builtin_amdgcn_rcpf(1.0f + __builtin_amdgcn_exp2f(-1.442695040889f * graw));
      float s2r = 0.f;
      #pragma unroll
      for (int nt=0;nt<2;++nt){
        float cv = (nt ? acc1[r] : acc0[r]) + Creg[nt][r] + xwc[nt];
        cv = cv > 0.f ? cv : pa2[nt]*cv;
        float n = so[nt][r] + g4[r]*cv;
        ns[nt][r] = n;
        s2r += n*n;
      }
      s2r += __shfl_xor(s2r, 1);
      s2r += __shfl_xor(s2r, 2);
      s2r += __shfl_xor(s2r, 4);
      s2r += __shfl_xor(s2r, 8);
      s2[r] = s2r;
    }
    if (c == 0){
      f4v np; np[0]=s2[0]; np[1]=s2[1]; np[2]=s2[2]; np[3]=s2[3];
      *(f4v*)&L.npart[cg][4*q] = np;
    }
    __syncthreads();                              // barrier 1: npart ready

    // ---- norms + state update (cvt_pk split, uint2 stores) + stage x_{t+1} ----
    {
      f4v p0 = *(const f4v*)&L.npart[0][4*q];
      f4v p1 = *(const f4v*)&L.npart[1][4*q];
      f4v p2 = *(const f4v*)&L.npart[2][4*q];
      f4v p3 = *(const f4v*)&L.npart[3][4*q];
      f4v ss = p0 + p1 + p2 + p3;
      float inv[4];
      bool real[4];
      #pragma unroll
      for (int r=0;r<4;++r){
        real[r] = (4*q + r) < KB_ROWS;
        inv[r] = __builtin_amdgcn_rcpf(__builtin_amdgcn_sqrtf(ss[r]) + 1e-8f);
      }
      #pragma unroll
      for (int nt=0;nt<2;++nt){
        float v[4];
        #pragma unroll
        for (int r=0;r<4;++r){
          float n = ns[nt][r];
          float vv = (n > 0.f ? n : 1.0f) * inv[r];
          v[r] = real[r] ? vv : 0.f;
          so[nt][r] = v[r];
        }
        unsigned h01 = cvt_pk(v[0], v[1]);
        unsigned h23 = cvt_pk(v[2], v[3]);
        float r0 = v[0] - ubf(h01 << 16);
        float r1 = v[1] - ubf(h01 & 0xffff0000u);
        float r2 = v[2] - ubf(h23 << 16);
        float r3 = v[3] - ubf(h23 & 0xffff0000u);
        unsigned m01 = cvt_pk(r0, r1);
        unsigned m23 = cvt_pk(r2, r3);
        float s0 = r0 - ubf(m01 << 16);
        float s1 = r1 - ubf(m01 & 0xffff0000u);
        float s2_ = r2 - ubf(m23 << 16);
        float s3 = r3 - ubf(m23 & 0xffff0000u);
        unsigned l01 = cvt_pk(s0, s1);
        unsigned l23 = cvt_pk(s2_, s3);
        *(uint2*)&L.st[0][col[nt]][4*q] = make_uint2(h01, h23);
        *(uint2*)&L.st[1][col[nt]][4*q] = make_uint2(m01, m23);
        *(uint2*)&L.st[2][col[nt]][4*q] = make_uint2(l01, l23);
      }
    }
    if (t+1 < TT && tid < EE){
      unsigned short hb,mb,lb; split3(nxv,hb,mb,lb);
      L.xp[0][tid]=hb; L.xp[1][tid]=mb; L.xp[2][tid]=lb;
    }
    xwc[0]=xwn[0]; xwc[1]=xwn[1];
    #pragma unroll
    for (int r=0;r<4;++r) xkc[r]=xkn[r];
    __syncthreads();                              // barrier 2: state visible
  }

  // ---- final state writeback (exact f32 from registers) ----
  #pragma unroll
  for (int nt=0;nt<2;++nt)
    #pragma unroll
    for (int r=0;r<4;++r){
      int lr = 4*q + r;
      if (lr < KB_ROWS)
        zst[((size_t)b*KK + kb*KB_ROWS + lr)*EE + col[nt]] = so[nt][r];
    }
}

// ---------------- kernel 4b: tail (attention + u + z), needs all 20 k ----------------
__global__ __launch_bounds__(128) void k_tail(
    const float* __restrict__ zst, const float* __restrict__ qenc,
    const float* __restrict__ prelu_a, const float* __restrict__ H,
    float* __restrict__ zout)
{
  __shared__ float st[KK*EE];
  __shared__ float us[EE];
  __shared__ float red[2][KK];
  __shared__ float gs[KK];
  int b = blockIdx.x, tid = threadIdx.x;
  for (int i = tid; i < KK*EE; i += 128) st[i] = zst[(size_t)b*KK*EE + i];
  float qv = qenc[(size_t)b*EE + tid];
  __syncthreads();
  int wv = tid >> 6, ln = tid & 63;
  for (int k=0;k<KK;++k){
    float p = qv * st[k*EE + tid];
    #pragma unroll
    for (int off=32; off; off>>=1) p += __shfl_xor(p, off);
    if (ln == 0) red[wv][k] = p;
  }
  __syncthreads();
  if (tid == 0){
    float mx = -1e30f, gg[KK];
    for (int k=0;k<KK;++k){ float v = red[0][k]+red[1][k]; gg[k]=v; mx = fmaxf(mx, v); }
    float s = 0.f;
    for (int k=0;k<KK;++k){ float e_ = expf(gg[k]-mx); gg[k]=e_; s += e_; }
    for (int k=0;k<KK;++k) gs[k] = gg[k]/s;
  }
  __syncthreads();
  float u_ = 0.f;
  #pragma unroll
  for (int k=0;k<KK;++k) u_ += gs[k]*st[k*EE + tid];
  us[tid] = u_;
  __syncthreads();
  float hp = 0.f;
  const float* hr = H + (size_t)tid*EE;
  for (int e=0; e<EE; e+=4){
    float4 h4 = *(const float4*)(hr + e);
    float4 u4 = *(const float4*)(us + e);
    hp += h4.x*u4.x + h4.y*u4.y + h4.z*u4.z + h4.w*u4.w;
  }
  float zv = qv + hp;
  float pat = prelu_a[tid];
  zv = zv > 0.f ? zv : pat*zv;
  zout[(size_t)b*EE + tid] = zv;
}

// ---------------- kernel 5: y = z @ R^T ----------------
__global__ __launch_bounds__(256) void k_out(
    const float* __restrict__ z, const float* __restrict__ R,
    float* __restrict__ y)
{
  __shared__ float zs[64*EE];
  int tid = threadIdx.x;
  int rb = blockIdx.y*64;
  for (int i=0;i<8;++i){
    int idx = tid + i*256; int r = idx>>5; int c4 = (idx&31)*4;
    *(float4*)(zs + r*EE + c4) = *(const float4*)(z + (size_t)(rb+r)*EE + c4);
  }
  __syncthreads();
  int c0 = blockIdx.x*128 + (tid&31)*4;
  int r0 = (tid>>5)*8;
  float acc[8][4];
  #pragma unroll
  for (int i=0;i<8;++i)
    #pragma unroll
    for (int j=0;j<4;++j) acc[i][j]=0.f;

  const float* rp[4];
  #pragma unroll
  for (int cc=0;cc<4;++cc){ int colq = c0+cc; if (colq >= VOCAB) colq = 0; rp[cc] = R + (size_t)colq*EE; }

  for (int e4=0; e4<EE; e4+=4) {
    float4 rv[4];
    #pragma unroll
    for (int cc=0;cc<4;++cc) rv[cc] = *(const float4*)(rp[cc] + e4);
    #pragma unroll
    for (int rr=0;rr<8;++rr){
      float4 x4 = *(const float4*)(zs + (r0+rr)*EE + e4);
      #pragma unroll
      for (int cc=0;cc<4;++cc)
        acc[rr][cc] += x4.x*rv[cc].x + x4.y*rv[cc].y + x4.z*rv[cc].z + x4.w*rv[cc].w;
    }
  }
  #pragma unroll
  for (int rr=0;rr<8;++rr){
    int row = rb + r0 + rr;
    if (c0 + 3 < VOCAB) {
      *(float4*)(y + (size_t)row*VOCAB + c0) =
          make_float4(acc[rr][0], acc[rr][1], acc[rr][2], acc[rr][3]);
    } else {
      for (int cc=0;cc<4;++cc){ int colq = c0+cc; if (colq < VOCAB) y[(size_t)row*VOCAB + colq] = acc[rr][cc]; }
    }
  }
}

// ---------------- launch ----------------
extern "C" void kernel_launch(void* const* d_in, const int* in_sizes, int n_in,
                              void* d_out, int out_size, void* d_ws, size_t ws_size,
                              hipStream_t stream)
{
  const int*   story = (const int*)d_in[0];
  const int*   query = (const int*)d_in[1];
  const float* emb   = (const float*)d_in[2];
  const float* smask = (const float*)d_in[3];
  const float* qmask = (const float*)d_in[4];
  const float* pa    = (const float*)d_in[5];
  const float* U     = (const float*)d_in[6];
  const float* V     = (const float*)d_in[7];
  const float* W     = (const float*)d_in[8];
  const float* bias  = (const float*)d_in[9];
  const float* H     = (const float*)d_in[10];
  const float* R     = (const float*)d_in[11];
  float* y  = (float*)d_out;
  float* ws = (float*)d_ws;

  float* s_enc = ws + OFF_SENC;
  float* q_enc = ws + OFF_QENC;
  float* Ckf   = ws + OFF_CKF;
  float* xw    = ws + OFF_XW;
  float* z     = ws + OFF_Z;
  float* xk    = ws + OFF_XK;
  float* zst   = ws + OFF_ST;

  k_embed_sum<<<dim3(BB*TT/8), 256, 0, stream>>>(story, emb, smask, s_enc, BB*TT, SS);
  k_embed_sum<<<dim3(BB/8),    256, 0, stream>>>(query, emb, qmask, q_enc, BB, QQ);
  k_ckf<<<dim3(KK), 128, 0, stream>>>(emb, V, bias, Ckf);
  k_xw<<<dim3(BB*TT/64), 256, 0, stream>>>(s_enc, W, emb, xw, xk);

  k_scan<<<dim3(BB*2), 256, 0, stream>>>(emb, U, s_enc, xw, xk, Ckf, pa, zst);
  k_tail<<<dim3(BB), 128, 0, stream>>>(zst, q_enc, pa, H, z);

  k_out<<<dim3((VOCAB+127)/128, BB/64), 256, 0, stream>>>(z, R, y);
}

// Round 8
// 551.641 us; speedup vs baseline: 1.9998x; 1.0290x over previous
//
#include <hip/hip_runtime.h>
#include <hip/hip_bf16.h>
#include <stdint.h>

#define BB 256
#define TT 128
#define SS 16
#define QQ 16
#define EE 128
#define KK 20
#define VOCAB 50020
#define KB_ROWS 10   // k-rows per scan block (2 blocks per batch)

typedef __attribute__((ext_vector_type(8))) short s8v;            // 8 bf16
typedef __attribute__((ext_vector_type(4))) unsigned short u4h;   // 4 bf16 (b64)
typedef __attribute__((ext_vector_type(4))) float f4v;            // MFMA acc
#define MFMA(a,b,c) __builtin_amdgcn_mfma_f32_16x16x32_bf16(a,b,c,0,0,0)

static __device__ __forceinline__ unsigned short f2bf(float x){
  unsigned u = __float_as_uint(x);
  unsigned r = (u + 0x7fffu + ((u>>16)&1u)) >> 16;
  return (unsigned short)r;
}
static __device__ __forceinline__ float bf2f(unsigned short h){
  return __uint_as_float(((unsigned)h)<<16);
}
// 3-term split: v = hi + mid + lo + O(2^-24 |v|)
static __device__ __forceinline__ void split3(float v, unsigned short& hb,
                                              unsigned short& mb, unsigned short& lb){
  hb = f2bf(v);
  float r1 = v - bf2f(hb);
  mb = f2bf(r1);
  float r2 = r1 - bf2f(mb);
  lb = f2bf(r2);
}
static __device__ __forceinline__ void split3_8(const float* v, s8v& h, s8v& m_, s8v& l){
  #pragma unroll
  for (int j=0;j<8;++j){
    unsigned short hb, mb, lb;
    split3(v[j], hb, mb, lb);
    h[j]=(short)hb; m_[j]=(short)mb; l[j]=(short)lb;
  }
}
static __device__ __forceinline__ s8v cat8(u4h a, u4h b){
  union { u4h p[2]; s8v v; } u; u.p[0]=a; u.p[1]=b; return u.v;
}
// packed f32->bf16 pair: low16 = bf16(a), high16 = bf16(b)
static __device__ __forceinline__ unsigned cvt_pk(float a, float b){
  unsigned r;
  asm("v_cvt_pk_bf16_f32 %0, %1, %2" : "=v"(r) : "v"(a), "v"(b));
  return r;
}
static __device__ __forceinline__ float ubf(unsigned u){ return __uint_as_float(u); }

// hardware transpose read: quarter-wave reads 128B region, lane gets column (l&15)
template<int IMM>
static __device__ __forceinline__ u4h tr_read(unsigned va){
  u4h d;
  asm volatile("ds_read_b64_tr_b16 %0, %1 offset:%c2" : "=v"(d) : "v"(va), "i"(IMM));
  return d;
}
// A-frag (state) for plane P, k-slice K4 within current ping buffer
#define LDA(P,K4) cat8(tr_read<(P)*4096+(K4)*1024>(va), tr_read<(P)*4096+(K4)*1024+128>(va))

// ---------------- workspace layout (floats) ----------------
static const size_t OFF_SENC = 0;                              // B*T*E
static const size_t OFF_QENC = OFF_SENC + (size_t)BB*TT*EE;    // B*E
static const size_t OFF_CKF  = OFF_QENC + (size_t)BB*EE;       // K*E
static const size_t OFF_XW   = OFF_CKF  + (size_t)KK*EE;       // B*T*E
static const size_t OFF_Z    = OFF_XW   + (size_t)BB*TT*EE;    // B*E
static const size_t OFF_XK   = OFF_Z    + (size_t)BB*EE;       // B*T*K
static const size_t OFF_ST   = OFF_XK   + (size_t)BB*TT*KK;    // B*K*E

// ---------------- kernel 1: embedding bag-sum ----------------
__global__ __launch_bounds__(256) void k_embed_sum(
    const int* __restrict__ tok, const float* __restrict__ emb,
    const float* __restrict__ mask, float* __restrict__ out,
    int nrow, int ntok)
{
  int tid = threadIdx.x;
  int row = blockIdx.x*8 + (tid>>5);
  if (row >= nrow) return;
  int e4 = (tid&31)*4;
  float4 acc = make_float4(0.f,0.f,0.f,0.f);
  for (int s=0; s<ntok; ++s) {
    int id = tok[row*ntok + s];
    float4 ev = *(const float4*)(emb + (size_t)id*EE + e4);
    float4 mv = *(const float4*)(mask + s*EE + e4);
    acc.x += ev.x*mv.x; acc.y += ev.y*mv.y; acc.z += ev.z*mv.z; acc.w += ev.w*mv.w;
  }
  *(float4*)(out + (size_t)row*EE + e4) = acc;
}

// ---------------- kernel 2: Ckf[k][f] = bias[f] + keys[k] . V[f] ----------------
__global__ __launch_bounds__(128) void k_ckf(
    const float* __restrict__ emb, const float* __restrict__ V,
    const float* __restrict__ bias, float* __restrict__ Ckf)
{
  int k = blockIdx.x;
  int f = threadIdx.x;
  const float* key = emb + (size_t)(VOCAB-KK+k)*EE;
  const float* vr  = V + (size_t)f*EE;
  float acc = bias[f];
  for (int e=0; e<EE; e+=4) {
    float4 kv = *(const float4*)(key + e);
    float4 vv = *(const float4*)(vr + e);
    acc += kv.x*vv.x + kv.y*vv.y + kv.z*vv.z + kv.w*vv.w;
  }
  Ckf[k*EE + f] = acc;
}

// ---------------- kernel 3: xw = senc@W^T  and  xk = senc@keys^T ----------------
__global__ __launch_bounds__(256) void k_xw(
    const float* __restrict__ senc, const float* __restrict__ W,
    const float* __restrict__ emb, float* __restrict__ xw,
    float* __restrict__ xk)
{
  __shared__ float xs[64*EE];
  __shared__ float keys_s[KK*EE];
  int tid = threadIdx.x;
  int r0 = blockIdx.x*64;
  for (int i=0;i<8;++i){
    int idx = tid + i*256; int r = idx>>5; int c4 = (idx&31)*4;
    *(float4*)(xs + r*EE + c4) = *(const float4*)(senc + (size_t)(r0+r)*EE + c4);
  }
  for (int idx=tid; idx<KK*EE; idx+=256)
    keys_s[idx] = emb[(size_t)(VOCAB-KK + (idx>>7))*EE + (idx&127)];
  __syncthreads();
  int f  = tid & 127;
  int rh = tid >> 7;
  float acc[32];
  #pragma unroll
  for (int i=0;i<32;++i) acc[i]=0.f;
  const float* wr = W + (size_t)f*EE;
  for (int e4=0; e4<EE; e4+=4) {
    float4 w4 = *(const float4*)(wr + e4);
    #pragma unroll
    for (int rr=0; rr<32; ++rr) {
      float4 x4 = *(const float4*)(xs + (rh*32+rr)*EE + e4);
      acc[rr] += w4.x*x4.x + w4.y*x4.y + w4.z*x4.z + w4.w*x4.w;
    }
  }
  #pragma unroll
  for (int rr=0; rr<32; ++rr)
    xw[(size_t)(r0 + rh*32 + rr)*EE + f] = acc[rr];
  for (int i=0;i<5;++i){
    int task = tid + i*256;
    int r = task/KK, k = task - r*KK;
    float a = 0.f;
    for (int e=0; e<EE; e+=4){
      float4 x4 = *(const float4*)(xs + r*EE + e);
      float4 k4 = *(const float4*)(keys_s + k*EE + e);
      a += x4.x*k4.x + x4.y*k4.y + x4.z*k4.z + x4.w*k4.w;
    }
    xk[(size_t)(r0+r)*KK + k] = a;
  }
}

// ---------------- kernel 4: MFMA scan — deferred norm, ping-pong, 1 barrier/step ----
// State stored UNNORMALIZED (s_hat = n>0?n:1). Normalization deferred: next step
// reads npart, computes inv[row], scales MFMA outputs (row-scaling commutes with
// the GEMM). Ping-pong st/xp/npart buffers -> single __syncthreads per step.
struct ScanLds {
  unsigned short st[2][3][EE][16];  // 24576 B (buf, plane hi/mid/lo, e, k)
  unsigned short xp[2][3][EE];      // 1536 B
  float npart[2][4][16];            // 512 B
};

__global__ __launch_bounds__(256) void k_scan(
    const float* __restrict__ emb, const float* __restrict__ U,
    const float* __restrict__ senc, const float* __restrict__ xw,
    const float* __restrict__ xk, const float* __restrict__ Ckf,
    const float* __restrict__ prelu_a, float* __restrict__ zst)
{
  __shared__ ScanLds L;
  int tid = threadIdx.x;
  int bid = blockIdx.x;
  int b   = bid >> 1, kb = bid & 1;
  int l   = tid & 63, cg = tid >> 6;
  int q   = l >> 4,  c  = l & 15;
  int col[2] = { cg*32 + c, cg*32 + 16 + c };

  // ---- zero both state buffers (pad rows must stay 0) ----
  for (int idx = tid; idx < 2*3*EE*16; idx += 256) ((unsigned short*)L.st)[idx] = 0;
  __syncthreads();
  // ---- init s_hat_0 = keys (raw, unnormalized — matches reference state0) ----
  for (int idx = tid; idx < KB_ROWS*EE; idx += 256){
    int row = idx >> 7, e = idx & 127;
    float v = emb[(size_t)(VOCAB - KK + kb*KB_ROWS + row)*EE + e];
    unsigned short hb, mb, lb; split3(v, hb, mb, lb);
    L.st[0][0][e][row] = hb; L.st[0][1][e][row] = mb; L.st[0][2][e][row] = lb;
  }
  // ---- B-frags: U columns, 3-plane, constant across scan ----
  s8v bh[2][4], bm[2][4], bl[2][4];
  #pragma unroll
  for (int nt=0;nt<2;++nt)
    #pragma unroll
    for (int kk=0;kk<4;++kk){
      float tmp[8];
      const float* up = U + (size_t)col[nt]*EE + kk*32 + q*8;
      *(float4*)&tmp[0] = *(const float4*)up;
      *(float4*)&tmp[4] = *(const float4*)(up+4);
      split3_8(tmp, bh[nt][kk], bm[nt][kk], bl[nt][kk]);
    }
  // ---- per-lane constants; nsv = register copy of own s_hat values ----
  float Creg[2][4], pa2[2], nsv[2][4];
  bool realr[4];
  #pragma unroll
  for (int r=0;r<4;++r) realr[r] = (4*q + r) < KB_ROWS;
  #pragma unroll
  for (int nt=0;nt<2;++nt){
    pa2[nt] = prelu_a[col[nt]];
    #pragma unroll
    for (int r=0;r<4;++r){
      int lr = 4*q + r;
      Creg[nt][r] = realr[r] ? Ckf[(kb*KB_ROWS+lr)*EE + col[nt]] : 0.f;
      nsv[nt][r]  = realr[r] ? emb[(size_t)(VOCAB-KK+kb*KB_ROWS+lr)*EE + col[nt]] : 0.f;
    }
  }

  const float* xrow  = senc + (size_t)b*TT*EE;
  const float* xwrow = xw   + (size_t)b*TT*EE;
  const float* xkrow = xk   + (size_t)b*TT*KK;

  // t=0 staging into buf 0
  if (tid < EE){
    float v = xrow[tid];
    unsigned short hb,mb,lb; split3(v,hb,mb,lb);
    L.xp[0][0][tid]=hb; L.xp[0][1][tid]=mb; L.xp[0][2][tid]=lb;
  }
  float xwc[2] = { xwrow[col[0]], xwrow[col[1]] };
  float xkc[4];
  #pragma unroll
  for (int r=0;r<4;++r)
    xkc[r] = realr[r] ? xkrow[kb*KB_ROWS + 4*q + r] : 0.f;

  unsigned va0 = (unsigned)(uintptr_t)&L.st[0][0][0][0] + q*256 + c*8;
  __syncthreads();

  for (int t=0; t<TT; ++t){
    int p = t & 1, pn = p ^ 1;
    unsigned va = va0 + p*12288;
    const unsigned short (*xpp)[EE] = L.xp[p];

    // ---- inv norms of s_hat_t (from prev step's npart); t=0: state0 unnormalized ----
    float invr[4];
    if (t > 0){
      f4v p0 = *(const f4v*)&L.npart[p][0][4*q];
      f4v p1 = *(const f4v*)&L.npart[p][1][4*q];
      f4v p2 = *(const f4v*)&L.npart[p][2][4*q];
      f4v p3 = *(const f4v*)&L.npart[p][3][4*q];
      f4v ss = p0 + p1 + p2 + p3;
      #pragma unroll
      for (int r=0;r<4;++r)
        invr[r] = __builtin_amdgcn_rcpf(__builtin_amdgcn_sqrtf(ss[r]) + 1e-8f);
    } else {
      #pragma unroll
      for (int r=0;r<4;++r) invr[r] = 1.0f;
    }

    // ---- prefetch t+1 globals ----
    float nxv = 0.f, xwn[2] = {0.f,0.f}, xkn[4] = {0.f,0.f,0.f,0.f};
    if (t+1 < TT){
      if (tid < EE) nxv = xrow[(size_t)(t+1)*EE + tid];
      xwn[0] = xwrow[(size_t)(t+1)*EE + col[0]];
      xwn[1] = xwrow[(size_t)(t+1)*EE + col[1]];
      #pragma unroll
      for (int r=0;r<4;++r)
        if (realr[r]) xkn[r] = xkrow[(size_t)(t+1)*KK + kb*KB_ROWS + 4*q + r];
    }

    // ---- A-frags (s_hat_t) via hardware transpose reads ----
    s8v A0[4] = { LDA(0,0), LDA(0,1), LDA(0,2), LDA(0,3) };  // hi
    s8v A1[4] = { LDA(1,0), LDA(1,1), LDA(1,2), LDA(1,3) };  // mid
    s8v A2[4] = { LDA(2,0), LDA(2,1), LDA(2,2), LDA(2,3) };  // lo
    asm volatile("s_waitcnt lgkmcnt(0)" ::: "memory");
    __builtin_amdgcn_sched_barrier(0);

    f4v z4 = {0.f,0.f,0.f,0.f};
    f4v acc[2][2] = {{z4,z4},{z4,z4}};
    f4v gac[2] = {z4,z4};
    #pragma unroll
    for (int kk=0; kk<4; ++kk){
      int h = kk>>1;
      s8v xh = *(const s8v*)&xpp[0][kk*32 + q*8];
      s8v xm = *(const s8v*)&xpp[1][kk*32 + q*8];
      s8v xl = *(const s8v*)&xpp[2][kk*32 + q*8];
      #pragma unroll
      for (int nt=0;nt<2;++nt){
        acc[nt][h] = MFMA(A2[kk], bh[nt][kk], acc[nt][h]);
        acc[nt][h] = MFMA(A1[kk], bm[nt][kk], acc[nt][h]);
        acc[nt][h] = MFMA(A0[kk], bl[nt][kk], acc[nt][h]);
        acc[nt][h] = MFMA(A1[kk], bh[nt][kk], acc[nt][h]);
        acc[nt][h] = MFMA(A0[kk], bm[nt][kk], acc[nt][h]);
        acc[nt][h] = MFMA(A0[kk], bh[nt][kk], acc[nt][h]);
      }
      gac[h] = MFMA(A2[kk], xh, gac[h]);
      gac[h] = MFMA(A1[kk], xm, gac[h]);
      gac[h] = MFMA(A0[kk], xl, gac[h]);
      gac[h] = MFMA(A1[kk], xh, gac[h]);
      gac[h] = MFMA(A0[kk], xm, gac[h]);
      gac[h] = MFMA(A0[kk], xh, gac[h]);
    }
    f4v acc0 = acc[0][0] + acc[0][1];
    f4v acc1 = acc[1][0] + acc[1][1];
    f4v gacc = gac[0] + gac[1];

    // ---- deferred normalization: scale GEMM rows by inv; gate; new state ----
    float s2[4];
    #pragma unroll
    for (int r=0;r<4;++r){
      float graw = gacc[r]*invr[r] + xkc[r];
      float g = __builtin_amdgcn_rcpf(1.0f + __builtin_amdgcn_exp2f(-1.442695040889f * graw));
      float s2r = 0.f;
      #pragma unroll
      for (int nt=0;nt<2;++nt){
        float so = nsv[nt][r] * invr[r];                       // normalized old state
        float cv = (nt ? acc1[r] : acc0[r])*invr[r] + Creg[nt][r] + xwc[nt];
        cv = cv > 0.f ? cv : pa2[nt]*cv;
        float n = so + g*cv;
        nsv[nt][r] = realr[r] ? (n > 0.f ? n : 1.0f) : 0.f;    // s_hat_{t+1}
        s2r += n*n;
      }
      s2r += __shfl_xor(s2r, 1);
      s2r += __shfl_xor(s2r, 2);
      s2r += __shfl_xor(s2r, 4);
      s2r += __shfl_xor(s2r, 8);
      s2[r] = s2r;
    }
    if (c == 0){
      f4v np; np[0]=s2[0]; np[1]=s2[1]; np[2]=s2[2]; np[3]=s2[3];
      *(f4v*)&L.npart[pn][cg][4*q] = np;
    }

    // ---- store s_hat_{t+1} (cvt_pk split, uint2 stores) + stage x_{t+1} ----
    #pragma unroll
    for (int nt=0;nt<2;++nt){
      float v0=nsv[nt][0], v1=nsv[nt][1], v2=nsv[nt][2], v3=nsv[nt][3];
      unsigned h01 = cvt_pk(v0, v1);
      unsigned h23 = cvt_pk(v2, v3);
      float r0 = v0 - ubf(h01 << 16);
      float r1 = v1 - ubf(h01 & 0xffff0000u);
      float r2 = v2 - ubf(h23 << 16);
      float r3 = v3 - ubf(h23 & 0xffff0000u);
      unsigned m01 = cvt_pk(r0, r1);
      unsigned m23 = cvt_pk(r2, r3);
      float s0 = r0 - ubf(m01 << 16);
      float s1 = r1 - ubf(m01 & 0xffff0000u);
      float s2_ = r2 - ubf(m23 << 16);
      float s3 = r3 - ubf(m23 & 0xffff0000u);
      unsigned l01 = cvt_pk(s0, s1);
      unsigned l23 = cvt_pk(s2_, s3);
      *(uint2*)&L.st[pn][0][col[nt]][4*q] = make_uint2(h01, h23);
      *(uint2*)&L.st[pn][1][col[nt]][4*q] = make_uint2(m01, m23);
      *(uint2*)&L.st[pn][2][col[nt]][4*q] = make_uint2(l01, l23);
    }
    if (t+1 < TT && tid < EE){
      unsigned short hb,mb,lb; split3(nxv,hb,mb,lb);
      L.xp[pn][0][tid]=hb; L.xp[pn][1][tid]=mb; L.xp[pn][2][tid]=lb;
    }
    xwc[0]=xwn[0]; xwc[1]=xwn[1];
    #pragma unroll
    for (int r=0;r<4;++r) xkc[r]=xkn[r];
    __syncthreads();                              // ONE barrier per step
  }

  // ---- finalize: normalize last s_hat from registers + final npart ----
  {
    int pf = TT & 1;   // buffer holding final npart (written at t=TT-1 to pn=TT&1)
    f4v p0 = *(const f4v*)&L.npart[pf][0][4*q];
    f4v p1 = *(const f4v*)&L.npart[pf][1][4*q];
    f4v p2 = *(const f4v*)&L.npart[pf][2][4*q];
    f4v p3 = *(const f4v*)&L.npart[pf][3][4*q];
    f4v ss = p0 + p1 + p2 + p3;
    #pragma unroll
    for (int r=0;r<4;++r){
      if (realr[r]){
        float inv = __builtin_amdgcn_rcpf(__builtin_amdgcn_sqrtf(ss[r]) + 1e-8f);
        #pragma unroll
        for (int nt=0;nt<2;++nt)
          zst[((size_t)b*KK + kb*KB_ROWS + 4*q + r)*EE + col[nt]] = nsv[nt][r]*inv;
      }
    }
  }
}

// ---------------- kernel 4b: tail (attention + u + z), needs all 20 k ----------------
__global__ __launch_bounds__(128) void k_tail(
    const float* __restrict__ zst, const float* __restrict__ qenc,
    const float* __restrict__ prelu_a, const float* __restrict__ H,
    float* __restrict__ zout)
{
  __shared__ float st[KK*EE];
  __shared__ float us[EE];
  __shared__ float red[2][KK];
  __shared__ float gs[KK];
  int b = blockIdx.x, tid = threadIdx.x;
  for (int i = tid; i < KK*EE; i += 128) st[i] = zst[(size_t)b*KK*EE + i];
  float qv = qenc[(size_t)b*EE + tid];
  __syncthreads();
  int wv = tid >> 6, ln = tid & 63;
  for (int k=0;k<KK;++k){
    float p = qv * st[k*EE + tid];
    #pragma unroll
    for (int off=32; off; off>>=1) p += __shfl_xor(p, off);
    if (ln == 0) red[wv][k] = p;
  }
  __syncthreads();
  if (tid == 0){
    float mx = -1e30f, gg[KK];
    for (int k=0;k<KK;++k){ float v = red[0][k]+red[1][k]; gg[k]=v; mx = fmaxf(mx, v); }
    float s = 0.f;
    for (int k=0;k<KK;++k){ float e_ = expf(gg[k]-mx); gg[k]=e_; s += e_; }
    for (int k=0;k<KK;++k) gs[k] = gg[k]/s;
  }
  __syncthreads();
  float u_ = 0.f;
  #pragma unroll
  for (int k=0;k<KK;++k) u_ += gs[k]*st[k*EE + tid];
  us[tid] = u_;
  __syncthreads();
  float hp = 0.f;
  const float* hr = H + (size_t)tid*EE;
  for (int e=0; e<EE; e+=4){
    float4 h4 = *(const float4*)(hr + e);
    float4 u4 = *(const float4*)(us + e);
    hp += h4.x*u4.x + h4.y*u4.y + h4.z*u4.z + h4.w*u4.w;
  }
  float zv = qv + hp;
  float pat = prelu_a[tid];
  zv = zv > 0.f ? zv : pat*zv;
  zout[(size_t)b*EE + tid] = zv;
}

// ---------------- kernel 5: y = z @ R^T ----------------
__global__ __launch_bounds__(256) void k_out(
    const float* __restrict__ z, const float* __restrict__ R,
    float* __restrict__ y)
{
  __shared__ float zs[64*EE];
  int tid = threadIdx.x;
  int rb = blockIdx.y*64;
  for (int i=0;i<8;++i){
    int idx = tid + i*256; int r = idx>>5; int c4 = (idx&31)*4;
    *(float4*)(zs + r*EE + c4) = *(const float4*)(z + (size_t)(rb+r)*EE + c4);
  }
  __syncthreads();
  int c0 = blockIdx.x*128 + (tid&31)*4;
  int r0 = (tid>>5)*8;
  float acc[8][4];
  #pragma unroll
  for (int i=0;i<8;++i)
    #pragma unroll
    for (int j=0;j<4;++j) acc[i][j]=0.f;

  const float* rp[4];
  #pragma unroll
  for (int cc=0;cc<4;++cc){ int colq = c0+cc; if (colq >= VOCAB) colq = 0; rp[cc] = R + (size_t)colq*EE; }

  for (int e4=0; e4<EE; e4+=4) {
    float4 rv[4];
    #pragma unroll
    for (int cc=0;cc<4;++cc) rv[cc] = *(const float4*)(rp[cc] + e4);
    #pragma unroll
    for (int rr=0;rr<8;++rr){
      float4 x4 = *(const float4*)(zs + (r0+rr)*EE + e4);
      #pragma unroll
      for (int cc=0;cc<4;++cc)
        acc[rr][cc] += x4.x*rv[cc].x + x4.y*rv[cc].y + x4.z*rv[cc].z + x4.w*rv[cc].w;
    }
  }
  #pragma unroll
  for (int rr=0;rr<8;++rr){
    int row = rb + r0 + rr;
    if (c0 + 3 < VOCAB) {
      *(float4*)(y + (size_t)row*VOCAB + c0) =
          make_float4(acc[rr][0], acc[rr][1], acc[rr][2], acc[rr][3]);
    } else {
      for (int cc=0;cc<4;++cc){ int colq = c0+cc; if (colq < VOCAB) y[(size_t)row*VOCAB + colq] = acc[rr][cc]; }
    }
  }
}

// ---------------- launch ----------------
extern "C" void kernel_launch(void* const* d_in, const int* in_sizes, int n_in,
                              void* d_out, int out_size, void* d_ws, size_t ws_size,
                              hipStream_t stream)
{
  const int*   story = (const int*)d_in[0];
  const int*   query = (const int*)d_in[1];
  const float* emb   = (const float*)d_in[2];
  const float* smask = (const float*)d_in[3];
  const float* qmask = (const float*)d_in[4];
  const float* pa    = (const float*)d_in[5];
  const float* U     = (const float*)d_in[6];
  const float* V     = (const float*)d_in[7];
  const float* W     = (const float*)d_in[8];
  const float* bias  = (const float*)d_in[9];
  const float* H     = (const float*)d_in[10];
  const float* R     = (const float*)d_in[11];
  float* y  = (float*)d_out;
  float* ws = (float*)d_ws;

  float* s_enc = ws + OFF_SENC;
  float* q_enc = ws + OFF_QENC;
  float* Ckf   = ws + OFF_CKF;
  float* xw    = ws + OFF_XW;
  float* z     = ws + OFF_Z;
  float* xk    = ws + OFF_XK;
  float* zst   = ws + OFF_ST;

  k_embed_sum<<<dim3(BB*TT/8), 256, 0, stream>>>(story, emb, smask, s_enc, BB*TT, SS);
  k_embed_sum<<<dim3(BB/8),    256, 0, stream>>>(query, emb, qmask, q_enc, BB, QQ);
  k_ckf<<<dim3(KK), 128, 0, stream>>>(emb, V, bias, Ckf);
  k_xw<<<dim3(BB*TT/64), 256, 0, stream>>>(s_enc, W, emb, xw, xk);

  k_scan<<<dim3(BB*2), 256, 0, stream>>>(emb, U, s_enc, xw, xk, Ckf, pa, zst);
  k_tail<<<dim3(BB), 128, 0, stream>>>(zst, q_enc, pa, H, z);

  k_out<<<dim3((VOCAB+127)/128, BB/64), 256, 0, stream>>>(z, R, y);
}

// Round 10
// 492.058 us; speedup vs baseline: 2.2419x; 1.1211x over previous
//
#include <hip/hip_runtime.h>
#include <hip/hip_bf16.h>
#include <stdint.h>

#define BB 256
#define TT 128
#define SS 16
#define QQ 16
#define EE 128
#define KK 20
#define VOCAB 50020
#define KB_ROWS 10   // k-rows per scan block (2 blocks per batch)

typedef __attribute__((ext_vector_type(8))) _Float16 h8v;         // 8 fp16 (4 VGPR)
typedef __attribute__((ext_vector_type(2))) __fp16 fp2v;          // builtin's return type
typedef __attribute__((ext_vector_type(4))) unsigned short u4h;   // 4 x u16 (b64)
typedef __attribute__((ext_vector_type(4))) float f4v;            // MFMA acc
#define MFMA16(a,b,c) __builtin_amdgcn_mfma_f32_16x16x32_f16(a,b,c,0,0,0)

static __device__ __forceinline__ unsigned pk2u(fp2v h){
  union { fp2v h; unsigned u; } c; c.h = h; return c.u;
}
static __device__ __forceinline__ float pk_lo(fp2v h){ return (float)h[0]; }
static __device__ __forceinline__ float pk_hi(fp2v h){ return (float)h[1]; }
static __device__ __forceinline__ unsigned short h1u(_Float16 h){
  union { _Float16 h; unsigned short u; } c; c.h = h; return c.u;
}
// fp16 2-term split of 8 f32 (RN, used outside the hot loop)
static __device__ __forceinline__ void split2_8(const float* v, h8v& h, h8v& l){
  #pragma unroll
  for (int j=0;j<8;++j){
    _Float16 hb = (_Float16)v[j];
    float hf = (float)hb;
    h[j] = hb;
    l[j] = (_Float16)(v[j]-hf);
  }
}
// hardware transpose read: quarter-wave reads 128B region, lane gets column (l&15)
template<int IMM>
static __device__ __forceinline__ u4h tr_read(unsigned va){
  u4h d;
  asm volatile("ds_read_b64_tr_b16 %0, %1 offset:%c2" : "=v"(d) : "v"(va), "i"(IMM));
  return d;
}
static __device__ __forceinline__ h8v cat8h(u4h a, u4h b){
  union { u4h p[2]; h8v v; } u; u.p[0]=a; u.p[1]=b; return u.v;
}
// A-frag (state) for plane P (0=hi,1=lo), k-slice K4 within current ping buffer
#define LDA(P,K4) cat8h(tr_read<(P)*4096+(K4)*1024>(va), tr_read<(P)*4096+(K4)*1024+128>(va))

// ---------------- workspace layout (floats) ----------------
static const size_t OFF_SENC = 0;                              // B*T*E
static const size_t OFF_QENC = OFF_SENC + (size_t)BB*TT*EE;    // B*E
static const size_t OFF_CKF  = OFF_QENC + (size_t)BB*EE;       // K*E
static const size_t OFF_XW   = OFF_CKF  + (size_t)KK*EE;       // B*T*E
static const size_t OFF_Z    = OFF_XW   + (size_t)BB*TT*EE;    // B*E
static const size_t OFF_XK   = OFF_Z    + (size_t)BB*EE;       // B*T*K
static const size_t OFF_ST   = OFF_XK   + (size_t)BB*TT*KK;    // B*K*E

// ---------------- kernel 1: embedding bag-sum ----------------
__global__ __launch_bounds__(256) void k_embed_sum(
    const int* __restrict__ tok, const float* __restrict__ emb,
    const float* __restrict__ mask, float* __restrict__ out,
    int nrow, int ntok)
{
  int tid = threadIdx.x;
  int row = blockIdx.x*8 + (tid>>5);
  if (row >= nrow) return;
  int e4 = (tid&31)*4;
  float4 acc = make_float4(0.f,0.f,0.f,0.f);
  for (int s=0; s<ntok; ++s) {
    int id = tok[row*ntok + s];
    float4 ev = *(const float4*)(emb + (size_t)id*EE + e4);
    float4 mv = *(const float4*)(mask + s*EE + e4);
    acc.x += ev.x*mv.x; acc.y += ev.y*mv.y; acc.z += ev.z*mv.z; acc.w += ev.w*mv.w;
  }
  *(float4*)(out + (size_t)row*EE + e4) = acc;
}

// ---------------- kernel 2: Ckf[k][f] = bias[f] + keys[k] . V[f] ----------------
__global__ __launch_bounds__(128) void k_ckf(
    const float* __restrict__ emb, const float* __restrict__ V,
    const float* __restrict__ bias, float* __restrict__ Ckf)
{
  int k = blockIdx.x;
  int f = threadIdx.x;
  const float* key = emb + (size_t)(VOCAB-KK+k)*EE;
  const float* vr  = V + (size_t)f*EE;
  float acc = bias[f];
  for (int e=0; e<EE; e+=4) {
    float4 kv = *(const float4*)(key + e);
    float4 vv = *(const float4*)(vr + e);
    acc += kv.x*vv.x + kv.y*vv.y + kv.z*vv.z + kv.w*vv.w;
  }
  Ckf[k*EE + f] = acc;
}

// ---------------- kernel 3: xw = senc@W^T  and  xk = senc@keys^T ----------------
__global__ __launch_bounds__(256) void k_xw(
    const float* __restrict__ senc, const float* __restrict__ W,
    const float* __restrict__ emb, float* __restrict__ xw,
    float* __restrict__ xk)
{
  __shared__ float xs[64*EE];
  __shared__ float keys_s[KK*EE];
  int tid = threadIdx.x;
  int r0 = blockIdx.x*64;
  for (int i=0;i<8;++i){
    int idx = tid + i*256; int r = idx>>5; int c4 = (idx&31)*4;
    *(float4*)(xs + r*EE + c4) = *(const float4*)(senc + (size_t)(r0+r)*EE + c4);
  }
  for (int idx=tid; idx<KK*EE; idx+=256)
    keys_s[idx] = emb[(size_t)(VOCAB-KK + (idx>>7))*EE + (idx&127)];
  __syncthreads();
  int f  = tid & 127;
  int rh = tid >> 7;
  float acc[32];
  #pragma unroll
  for (int i=0;i<32;++i) acc[i]=0.f;
  const float* wr = W + (size_t)f*EE;
  for (int e4=0; e4<EE; e4+=4) {
    float4 w4 = *(const float4*)(wr + e4);
    #pragma unroll
    for (int rr=0; rr<32; ++rr) {
      float4 x4 = *(const float4*)(xs + (rh*32+rr)*EE + e4);
      acc[rr] += w4.x*x4.x + w4.y*x4.y + w4.z*x4.z + w4.w*x4.w;
    }
  }
  #pragma unroll
  for (int rr=0; rr<32; ++rr)
    xw[(size_t)(r0 + rh*32 + rr)*EE + f] = acc[rr];
  for (int i=0;i<5;++i){
    int task = tid + i*256;
    int r = task/KK, k = task - r*KK;
    float a = 0.f;
    for (int e=0; e<EE; e+=4){
      float4 x4 = *(const float4*)(xs + r*EE + e);
      float4 k4 = *(const float4*)(keys_s + k*EE + e);
      a += x4.x*k4.x + x4.y*k4.y + x4.z*k4.z + x4.w*k4.w;
    }
    xk[(size_t)(r0+r)*KK + k] = a;
  }
}

// ---------------- kernel 4: MFMA scan — fp16 2-term, deferred norm, ping-pong ----
// State stored UNNORMALIZED as fp16 hi/lo planes. Normalization deferred to the
// consumer step (row-scaling commutes with the GEMM). One barrier per step.
struct ScanLds {
  unsigned short st[2][2][EE][16];  // 16384 B (buf, plane hi/lo, e, k-row)
  unsigned short xp[2][2][EE];      // 1024 B
  float npart[2][4][16];            // 512 B
};

__global__ __launch_bounds__(256) void k_scan(
    const float* __restrict__ emb, const float* __restrict__ U,
    const float* __restrict__ senc, const float* __restrict__ xw,
    const float* __restrict__ xk, const float* __restrict__ Ckf,
    const float* __restrict__ prelu_a, float* __restrict__ zst)
{
  __shared__ ScanLds L;
  int tid = threadIdx.x;
  int bid = blockIdx.x;
  int b   = bid >> 1, kb = bid & 1;
  int l   = tid & 63, cg = tid >> 6;
  int q   = l >> 4,  c  = l & 15;
  int col[2] = { cg*32 + c, cg*32 + 16 + c };

  // ---- zero both state buffers (pad rows must stay 0) ----
  for (int idx = tid; idx < 2*2*EE*16; idx += 256) ((unsigned short*)L.st)[idx] = 0;
  __syncthreads();
  // ---- init s_hat_0 = keys (raw, unnormalized — matches reference state0) ----
  for (int idx = tid; idx < KB_ROWS*EE; idx += 256){
    int row = idx >> 7, e = idx & 127;
    float v = emb[(size_t)(VOCAB - KK + kb*KB_ROWS + row)*EE + e];
    _Float16 hb = (_Float16)v;
    _Float16 lb = (_Float16)(v - (float)hb);
    L.st[0][0][e][row] = h1u(hb);
    L.st[0][1][e][row] = h1u(lb);
  }
  // ---- B-frags: U columns, fp16 hi/lo, constant across scan ----
  h8v bh[2][4], bl[2][4];
  #pragma unroll
  for (int nt=0;nt<2;++nt)
    #pragma unroll
    for (int kk=0;kk<4;++kk){
      float tmp[8];
      const float* up = U + (size_t)col[nt]*EE + kk*32 + q*8;
      *(float4*)&tmp[0] = *(const float4*)up;
      *(float4*)&tmp[4] = *(const float4*)(up+4);
      split2_8(tmp, bh[nt][kk], bl[nt][kk]);
    }
  // ---- per-lane constants; nsv = register copy of own s_hat values ----
  float Creg[2][4], pa2[2], nsv[2][4];
  bool realr[4];
  #pragma unroll
  for (int r=0;r<4;++r) realr[r] = (4*q + r) < KB_ROWS;
  #pragma unroll
  for (int nt=0;nt<2;++nt){
    pa2[nt] = prelu_a[col[nt]];
    #pragma unroll
    for (int r=0;r<4;++r){
      int lr = 4*q + r;
      Creg[nt][r] = realr[r] ? Ckf[(kb*KB_ROWS+lr)*EE + col[nt]] : 0.f;
      nsv[nt][r]  = realr[r] ? emb[(size_t)(VOCAB-KK+kb*KB_ROWS+lr)*EE + col[nt]] : 0.f;
    }
  }

  const float* xrow  = senc + (size_t)b*TT*EE;
  const float* xwrow = xw   + (size_t)b*TT*EE;
  const float* xkrow = xk   + (size_t)b*TT*KK;

  // t=0 staging into buf 0
  if (tid < EE){
    float v = xrow[tid];
    _Float16 hb = (_Float16)v;
    _Float16 lb = (_Float16)(v - (float)hb);
    L.xp[0][0][tid] = h1u(hb); L.xp[0][1][tid] = h1u(lb);
  }
  float xwc[2] = { xwrow[col[0]], xwrow[col[1]] };
  float xkc[4];
  #pragma unroll
  for (int r=0;r<4;++r)
    xkc[r] = realr[r] ? xkrow[kb*KB_ROWS + 4*q + r] : 0.f;

  unsigned va0 = (unsigned)(uintptr_t)&L.st[0][0][0][0] + q*256 + c*8;
  __syncthreads();

  for (int t=0; t<TT; ++t){
    int p = t & 1, pn = p ^ 1;
    unsigned va = va0 + p*8192;
    const unsigned short (*xpp)[EE] = L.xp[p];

    // ---- inv norms of s_hat_t (from prev step's npart); t=0: state0 unnormalized ----
    float invr[4];
    if (t > 0){
      f4v p0 = *(const f4v*)&L.npart[p][0][4*q];
      f4v p1 = *(const f4v*)&L.npart[p][1][4*q];
      f4v p2 = *(const f4v*)&L.npart[p][2][4*q];
      f4v p3 = *(const f4v*)&L.npart[p][3][4*q];
      f4v ss = p0 + p1 + p2 + p3;
      #pragma unroll
      for (int r=0;r<4;++r)
        invr[r] = __builtin_amdgcn_rcpf(__builtin_amdgcn_sqrtf(ss[r]) + 1e-8f);
    } else {
      #pragma unroll
      for (int r=0;r<4;++r) invr[r] = 1.0f;
    }

    // ---- prefetch t+1 globals ----
    float nxv = 0.f, xwn[2] = {0.f,0.f}, xkn[4] = {0.f,0.f,0.f,0.f};
    if (t+1 < TT){
      if (tid < EE) nxv = xrow[(size_t)(t+1)*EE + tid];
      xwn[0] = xwrow[(size_t)(t+1)*EE + col[0]];
      xwn[1] = xwrow[(size_t)(t+1)*EE + col[1]];
      #pragma unroll
      for (int r=0;r<4;++r)
        if (realr[r]) xkn[r] = xkrow[(size_t)(t+1)*KK + kb*KB_ROWS + 4*q + r];
    }

    // ---- A-frags (s_hat_t) via hardware transpose reads: hi + lo planes ----
    h8v Ah[4] = { LDA(0,0), LDA(0,1), LDA(0,2), LDA(0,3) };
    h8v Al[4] = { LDA(1,0), LDA(1,1), LDA(1,2), LDA(1,3) };
    asm volatile("s_waitcnt lgkmcnt(0)" ::: "memory");
    __builtin_amdgcn_sched_barrier(0);

    f4v z4 = {0.f,0.f,0.f,0.f};
    f4v acc[2][2] = {{z4,z4},{z4,z4}};
    f4v gac[2] = {z4,z4};
    #pragma unroll
    for (int kk=0; kk<4; ++kk){
      int h = kk>>1;
      h8v xh = *(const h8v*)&xpp[0][kk*32 + q*8];
      h8v xl = *(const h8v*)&xpp[1][kk*32 + q*8];
      #pragma unroll
      for (int nt=0;nt<2;++nt){
        acc[nt][h] = MFMA16(Al[kk], bh[nt][kk], acc[nt][h]);
        acc[nt][h] = MFMA16(Ah[kk], bl[nt][kk], acc[nt][h]);
        acc[nt][h] = MFMA16(Ah[kk], bh[nt][kk], acc[nt][h]);
      }
      gac[h] = MFMA16(Al[kk], xh, gac[h]);
      gac[h] = MFMA16(Ah[kk], xl, gac[h]);
      gac[h] = MFMA16(Ah[kk], xh, gac[h]);
    }
    f4v acc0 = acc[0][0] + acc[0][1];
    f4v acc1 = acc[1][0] + acc[1][1];
    f4v gacc = gac[0] + gac[1];

    // ---- deferred normalization: scale GEMM rows by inv; gate; new state ----
    float s2[4];
    #pragma unroll
    for (int r=0;r<4;++r){
      float graw = gacc[r]*invr[r] + xkc[r];
      float g = __builtin_amdgcn_rcpf(1.0f + __builtin_amdgcn_exp2f(-1.442695040889f * graw));
      float s2r = 0.f;
      #pragma unroll
      for (int nt=0;nt<2;++nt){
        float so = nsv[nt][r] * invr[r];                       // normalized old state
        float cv = (nt ? acc1[r] : acc0[r])*invr[r] + Creg[nt][r] + xwc[nt];
        cv = cv > 0.f ? cv : pa2[nt]*cv;
        float n = so + g*cv;
        nsv[nt][r] = realr[r] ? (n > 0.f ? n : 1.0f) : 0.f;    // s_hat_{t+1}
        s2r += n*n;
      }
      s2r += __shfl_xor(s2r, 1);
      s2r += __shfl_xor(s2r, 2);
      s2r += __shfl_xor(s2r, 4);
      s2r += __shfl_xor(s2r, 8);
      s2[r] = s2r;
    }
    if (c == 0){
      f4v np; np[0]=s2[0]; np[1]=s2[1]; np[2]=s2[2]; np[3]=s2[3];
      *(f4v*)&L.npart[pn][cg][4*q] = np;
    }

    // ---- store s_hat_{t+1} (pkrtz split, uint2 stores) + stage x_{t+1} ----
    #pragma unroll
    for (int nt=0;nt<2;++nt){
      float v0=nsv[nt][0], v1=nsv[nt][1], v2=nsv[nt][2], v3=nsv[nt][3];
      fp2v pa = __builtin_amdgcn_cvt_pkrtz(v0, v1);
      fp2v pb = __builtin_amdgcn_cvt_pkrtz(v2, v3);
      float r0 = v0 - pk_lo(pa);
      float r1 = v1 - pk_hi(pa);
      float r2 = v2 - pk_lo(pb);
      float r3 = v3 - pk_hi(pb);
      fp2v pc = __builtin_amdgcn_cvt_pkrtz(r0, r1);
      fp2v pd = __builtin_amdgcn_cvt_pkrtz(r2, r3);
      *(uint2*)&L.st[pn][0][col[nt]][4*q] = make_uint2(pk2u(pa), pk2u(pb));
      *(uint2*)&L.st[pn][1][col[nt]][4*q] = make_uint2(pk2u(pc), pk2u(pd));
    }
    if (t+1 < TT && tid < EE){
      _Float16 hb = (_Float16)nxv;
      _Float16 lb = (_Float16)(nxv - (float)hb);
      L.xp[pn][0][tid] = h1u(hb); L.xp[pn][1][tid] = h1u(lb);
    }
    xwc[0]=xwn[0]; xwc[1]=xwn[1];
    #pragma unroll
    for (int r=0;r<4;++r) xkc[r]=xkn[r];
    __syncthreads();                              // ONE barrier per step
  }

  // ---- finalize: normalize last s_hat from registers + final npart ----
  {
    int pf = TT & 1;   // buffer holding final npart
    f4v p0 = *(const f4v*)&L.npart[pf][0][4*q];
    f4v p1 = *(const f4v*)&L.npart[pf][1][4*q];
    f4v p2 = *(const f4v*)&L.npart[pf][2][4*q];
    f4v p3 = *(const f4v*)&L.npart[pf][3][4*q];
    f4v ss = p0 + p1 + p2 + p3;
    #pragma unroll
    for (int r=0;r<4;++r){
      if (realr[r]){
        float inv = __builtin_amdgcn_rcpf(__builtin_amdgcn_sqrtf(ss[r]) + 1e-8f);
        #pragma unroll
        for (int nt=0;nt<2;++nt)
          zst[((size_t)b*KK + kb*KB_ROWS + 4*q + r)*EE + col[nt]] = nsv[nt][r]*inv;
      }
    }
  }
}

// ---------------- kernel 4b: tail (attention + u + z), needs all 20 k ----------------
__global__ __launch_bounds__(128) void k_tail(
    const float* __restrict__ zst, const float* __restrict__ qenc,
    const float* __restrict__ prelu_a, const float* __restrict__ H,
    float* __restrict__ zout)
{
  __shared__ float st[KK*EE];
  __shared__ float us[EE];
  __shared__ float red[2][KK];
  __shared__ float gs[KK];
  int b = blockIdx.x, tid = threadIdx.x;
  for (int i = tid; i < KK*EE; i += 128) st[i] = zst[(size_t)b*KK*EE + i];
  float qv = qenc[(size_t)b*EE + tid];
  __syncthreads();
  int wv = tid >> 6, ln = tid & 63;
  for (int k=0;k<KK;++k){
    float p = qv * st[k*EE + tid];
    #pragma unroll
    for (int off=32; off; off>>=1) p += __shfl_xor(p, off);
    if (ln == 0) red[wv][k] = p;
  }
  __syncthreads();
  if (tid == 0){
    float mx = -1e30f, gg[KK];
    for (int k=0;k<KK;++k){ float v = red[0][k]+red[1][k]; gg[k]=v; mx = fmaxf(mx, v); }
    float s = 0.f;
    for (int k=0;k<KK;++k){ float e_ = expf(gg[k]-mx); gg[k]=e_; s += e_; }
    for (int k=0;k<KK;++k) gs[k] = gg[k]/s;
  }
  __syncthreads();
  float u_ = 0.f;
  #pragma unroll
  for (int k=0;k<KK;++k) u_ += gs[k]*st[k*EE + tid];
  us[tid] = u_;
  __syncthreads();
  float hp = 0.f;
  const float* hr = H + (size_t)tid*EE;
  for (int e=0; e<EE; e+=4){
    float4 h4 = *(const float4*)(hr + e);
    float4 u4 = *(const float4*)(us + e);
    hp += h4.x*u4.x + h4.y*u4.y + h4.z*u4.z + h4.w*u4.w;
  }
  float zv = qv + hp;
  float pat = prelu_a[tid];
  zv = zv > 0.f ? zv : pat*zv;
  zout[(size_t)b*EE + tid] = zv;
}

// ---------------- kernel 5: y = z @ R^T ----------------
__global__ __launch_bounds__(256) void k_out(
    const float* __restrict__ z, const float* __restrict__ R,
    float* __restrict__ y)
{
  __shared__ float zs[64*EE];
  int tid = threadIdx.x;
  int rb = blockIdx.y*64;
  for (int i=0;i<8;++i){
    int idx = tid + i*256; int r = idx>>5; int c4 = (idx&31)*4;
    *(float4*)(zs + r*EE + c4) = *(const float4*)(z + (size_t)(rb+r)*EE + c4);
  }
  __syncthreads();
  int c0 = blockIdx.x*128 + (tid&31)*4;
  int r0 = (tid>>5)*8;
  float acc[8][4];
  #pragma unroll
  for (int i=0;i<8;++i)
    #pragma unroll
    for (int j=0;j<4;++j) acc[i][j]=0.f;

  const float* rp[4];
  #pragma unroll
  for (int cc=0;cc<4;++cc){ int colq = c0+cc; if (colq >= VOCAB) colq = 0; rp[cc] = R + (size_t)colq*EE; }

  for (int e4=0; e4<EE; e4+=4) {
    float4 rv[4];
    #pragma unroll
    for (int cc=0;cc<4;++cc) rv[cc] = *(const float4*)(rp[cc] + e4);
    #pragma unroll
    for (int rr=0;rr<8;++rr){
      float4 x4 = *(const float4*)(zs + (r0+rr)*EE + e4);
      #pragma unroll
      for (int cc=0;cc<4;++cc)
        acc[rr][cc] += x4.x*rv[cc].x + x4.y*rv[cc].y + x4.z*rv[cc].z + x4.w*rv[cc].w;
    }
  }
  #pragma unroll
  for (int rr=0;rr<8;++rr){
    int row = rb + r0 + rr;
    if (c0 + 3 < VOCAB) {
      *(float4*)(y + (size_t)row*VOCAB + c0) =
          make_float4(acc[rr][0], acc[rr][1], acc[rr][2], acc[rr][3]);
    } else {
      for (int cc=0;cc<4;++cc){ int colq = c0+cc; if (colq < VOCAB) y[(size_t)row*VOCAB + colq] = acc[rr][cc]; }
    }
  }
}

// ---------------- launch ----------------
extern "C" void kernel_launch(void* const* d_in, const int* in_sizes, int n_in,
                              void* d_out, int out_size, void* d_ws, size_t ws_size,
                              hipStream_t stream)
{
  const int*   story = (const int*)d_in[0];
  const int*   query = (const int*)d_in[1];
  const float* emb   = (const float*)d_in[2];
  const float* smask = (const float*)d_in[3];
  const float* qmask = (const float*)d_in[4];
  const float* pa    = (const float*)d_in[5];
  const float* U     = (const float*)d_in[6];
  const float* V     = (const float*)d_in[7];
  const float* W     = (const float*)d_in[8];
  const float* bias  = (const float*)d_in[9];
  const float* H     = (const float*)d_in[10];
  const float* R     = (const float*)d_in[11];
  float* y  = (float*)d_out;
  float* ws = (float*)d_ws;

  float* s_enc = ws + OFF_SENC;
  float* q_enc = ws + OFF_QENC;
  float* Ckf   = ws + OFF_CKF;
  float* xw    = ws + OFF_XW;
  float* z     = ws + OFF_Z;
  float* xk    = ws + OFF_XK;
  float* zst   = ws + OFF_ST;

  k_embed_sum<<<dim3(BB*TT/8), 256, 0, stream>>>(story, emb, smask, s_enc, BB*TT, SS);
  k_embed_sum<<<dim3(BB/8),    256, 0, stream>>>(query, emb, qmask, q_enc, BB, QQ);
  k_ckf<<<dim3(KK), 128, 0, stream>>>(emb, V, bias, Ckf);
  k_xw<<<dim3(BB*TT/64), 256, 0, stream>>>(s_enc, W, emb, xw, xk);

  k_scan<<<dim3(BB*2), 256, 0, stream>>>(emb, U, s_enc, xw, xk, Ckf, pa, zst);
  k_tail<<<dim3(BB), 128, 0, stream>>>(zst, q_enc, pa, H, z);

  k_out<<<dim3((VOCAB+127)/128, BB/64), 256, 0, stream>>>(z, R, y);
}

// Round 11
// 477.415 us; speedup vs baseline: 2.3107x; 1.0307x over previous
//
#include <hip/hip_runtime.h>
#include <hip/hip_bf16.h>
#include <stdint.h>

#define BB 256
#define TT 128
#define SS 16
#define QQ 16
#define EE 128
#define KK 20
#define VOCAB 50020
#define KB_ROWS 10   // k-rows per scan block (2 blocks per batch)

typedef __attribute__((ext_vector_type(8))) _Float16 h8v;         // 8 fp16 (4 VGPR)
typedef __attribute__((ext_vector_type(2))) __fp16 fp2v;          // builtin's return type
typedef __attribute__((ext_vector_type(4))) unsigned short u4h;   // 4 x u16 (b64)
typedef __attribute__((ext_vector_type(4))) float f4v;            // MFMA acc
#define MFMA16(a,b,c) __builtin_amdgcn_mfma_f32_16x16x32_f16(a,b,c,0,0,0)

static __device__ __forceinline__ unsigned pk2u(fp2v h){
  union { fp2v h; unsigned u; } c; c.h = h; return c.u;
}
static __device__ __forceinline__ float pk_lo(fp2v h){ return (float)h[0]; }
static __device__ __forceinline__ float pk_hi(fp2v h){ return (float)h[1]; }
static __device__ __forceinline__ unsigned short h1u(_Float16 h){
  union { _Float16 h; unsigned short u; } c; c.h = h; return c.u;
}
// fp16 2-term split of 8 f32 (RN, used outside the hot loop)
static __device__ __forceinline__ void split2_8(const float* v, h8v& h, h8v& l){
  #pragma unroll
  for (int j=0;j<8;++j){
    _Float16 hb = (_Float16)v[j];
    float hf = (float)hb;
    h[j] = hb;
    l[j] = (_Float16)(v[j]-hf);
  }
}
// hardware transpose read: quarter-wave reads 128B region, lane gets column (l&15)
template<int IMM>
static __device__ __forceinline__ u4h tr_read(unsigned va){
  u4h d;
  asm volatile("ds_read_b64_tr_b16 %0, %1 offset:%c2" : "=v"(d) : "v"(va), "i"(IMM));
  return d;
}
static __device__ __forceinline__ h8v cat8h(u4h a, u4h b){
  union { u4h p[2]; h8v v; } u; u.p[0]=a; u.p[1]=b; return u.v;
}
// A-frag (state) for plane P (0=hi,1=lo), k-slice K4 within current ping buffer
#define LDA(P,K4) cat8h(tr_read<(P)*4096+(K4)*1024>(va), tr_read<(P)*4096+(K4)*1024+128>(va))

// ---------------- workspace layout (floats) ----------------
static const size_t OFF_SENC = 0;                              // B*T*E
static const size_t OFF_QENC = OFF_SENC + (size_t)BB*TT*EE;    // B*E
static const size_t OFF_CKF  = OFF_QENC + (size_t)BB*EE;       // K*E
static const size_t OFF_XW   = OFF_CKF  + (size_t)KK*EE;       // B*T*E
static const size_t OFF_Z    = OFF_XW   + (size_t)BB*TT*EE;    // B*E
static const size_t OFF_XK   = OFF_Z    + (size_t)BB*EE;       // B*T*K
static const size_t OFF_ST   = OFF_XK   + (size_t)BB*TT*KK;    // B*K*E

// ---------------- kernel 1: embedding bag-sum ----------------
__global__ __launch_bounds__(256) void k_embed_sum(
    const int* __restrict__ tok, const float* __restrict__ emb,
    const float* __restrict__ mask, float* __restrict__ out,
    int nrow, int ntok)
{
  int tid = threadIdx.x;
  int row = blockIdx.x*8 + (tid>>5);
  if (row >= nrow) return;
  int e4 = (tid&31)*4;
  float4 acc = make_float4(0.f,0.f,0.f,0.f);
  for (int s=0; s<ntok; ++s) {
    int id = tok[row*ntok + s];
    float4 ev = *(const float4*)(emb + (size_t)id*EE + e4);
    float4 mv = *(const float4*)(mask + s*EE + e4);
    acc.x += ev.x*mv.x; acc.y += ev.y*mv.y; acc.z += ev.z*mv.z; acc.w += ev.w*mv.w;
  }
  *(float4*)(out + (size_t)row*EE + e4) = acc;
}

// ---------------- kernel 2: Ckf[k][f] = bias[f] + keys[k] . V[f] ----------------
__global__ __launch_bounds__(128) void k_ckf(
    const float* __restrict__ emb, const float* __restrict__ V,
    const float* __restrict__ bias, float* __restrict__ Ckf)
{
  int k = blockIdx.x;
  int f = threadIdx.x;
  const float* key = emb + (size_t)(VOCAB-KK+k)*EE;
  const float* vr  = V + (size_t)f*EE;
  float acc = bias[f];
  for (int e=0; e<EE; e+=4) {
    float4 kv = *(const float4*)(key + e);
    float4 vv = *(const float4*)(vr + e);
    acc += kv.x*vv.x + kv.y*vv.y + kv.z*vv.z + kv.w*vv.w;
  }
  Ckf[k*EE + f] = acc;
}

// ---------------- kernel 3: xw = senc@W^T  and  xk = senc@keys^T ----------------
__global__ __launch_bounds__(256) void k_xw(
    const float* __restrict__ senc, const float* __restrict__ W,
    const float* __restrict__ emb, float* __restrict__ xw,
    float* __restrict__ xk)
{
  __shared__ float xs[64*EE];
  __shared__ float keys_s[KK*EE];
  int tid = threadIdx.x;
  int r0 = blockIdx.x*64;
  for (int i=0;i<8;++i){
    int idx = tid + i*256; int r = idx>>5; int c4 = (idx&31)*4;
    *(float4*)(xs + r*EE + c4) = *(const float4*)(senc + (size_t)(r0+r)*EE + c4);
  }
  for (int idx=tid; idx<KK*EE; idx+=256)
    keys_s[idx] = emb[(size_t)(VOCAB-KK + (idx>>7))*EE + (idx&127)];
  __syncthreads();
  int f  = tid & 127;
  int rh = tid >> 7;
  float acc[32];
  #pragma unroll
  for (int i=0;i<32;++i) acc[i]=0.f;
  const float* wr = W + (size_t)f*EE;
  for (int e4=0; e4<EE; e4+=4) {
    float4 w4 = *(const float4*)(wr + e4);
    #pragma unroll
    for (int rr=0; rr<32; ++rr) {
      float4 x4 = *(const float4*)(xs + (rh*32+rr)*EE + e4);
      acc[rr] += w4.x*x4.x + w4.y*x4.y + w4.z*x4.z + w4.w*x4.w;
    }
  }
  #pragma unroll
  for (int rr=0; rr<32; ++rr)
    xw[(size_t)(r0 + rh*32 + rr)*EE + f] = acc[rr];
  for (int i=0;i<5;++i){
    int task = tid + i*256;
    int r = task/KK, k = task - r*KK;
    float a = 0.f;
    for (int e=0; e<EE; e+=4){
      float4 x4 = *(const float4*)(xs + r*EE + e);
      float4 k4 = *(const float4*)(keys_s + k*EE + e);
      a += x4.x*k4.x + x4.y*k4.y + x4.z*k4.z + x4.w*k4.w;
    }
    xk[(size_t)(r0+r)*KK + k] = a;
  }
}

// ---------------- kernel 4: MFMA scan — fp16 2-term, deferred norm+gate ----------
// State UNNORMALIZED fp16 hi/lo planes; gate computed at step t as f32 partial
// dot x_{t+1}.s_hat_{t+1} (register values), reduced like the norm; both scaled
// by inv next step. No gate MFMAs, no x staging. One barrier per step.
struct ScanLds {
  unsigned short st[2][2][EE][16];  // 16384 B (buf, plane hi/lo, e, k-row)
  float npart[2][4][16];            // 512 B
  float gpart[2][4][16];            // 512 B
};

__global__ __launch_bounds__(256) void k_scan(
    const float* __restrict__ emb, const float* __restrict__ U,
    const float* __restrict__ senc, const float* __restrict__ xw,
    const float* __restrict__ xk, const float* __restrict__ Ckf,
    const float* __restrict__ prelu_a, float* __restrict__ zst)
{
  __shared__ ScanLds L;
  int tid = threadIdx.x;
  int bid = blockIdx.x;
  int b   = bid >> 1, kb = bid & 1;
  int l   = tid & 63, cg = tid >> 6;
  int q   = l >> 4,  c  = l & 15;
  int col[2] = { cg*32 + c, cg*32 + 16 + c };

  // ---- zero both state buffers (pad rows must stay 0) ----
  for (int idx = tid; idx < 2*2*EE*16; idx += 256) ((unsigned short*)L.st)[idx] = 0;
  __syncthreads();
  // ---- init s_hat_0 = keys (raw, unnormalized — matches reference state0) ----
  for (int idx = tid; idx < KB_ROWS*EE; idx += 256){
    int row = idx >> 7, e = idx & 127;
    float v = emb[(size_t)(VOCAB - KK + kb*KB_ROWS + row)*EE + e];
    _Float16 hb = (_Float16)v;
    _Float16 lb = (_Float16)(v - (float)hb);
    L.st[0][0][e][row] = h1u(hb);
    L.st[0][1][e][row] = h1u(lb);
  }
  // ---- B-frags: U columns, fp16 hi/lo, constant across scan ----
  h8v bh[2][4], bl[2][4];
  #pragma unroll
  for (int nt=0;nt<2;++nt)
    #pragma unroll
    for (int kk=0;kk<4;++kk){
      float tmp[8];
      const float* up = U + (size_t)col[nt]*EE + kk*32 + q*8;
      *(float4*)&tmp[0] = *(const float4*)up;
      *(float4*)&tmp[4] = *(const float4*)(up+4);
      split2_8(tmp, bh[nt][kk], bl[nt][kk]);
    }
  // ---- per-lane constants; nsv = register copy of own s_hat values ----
  float Creg[2][4], pa2[2], nsv[2][4];
  bool realr[4];
  #pragma unroll
  for (int r=0;r<4;++r) realr[r] = (4*q + r) < KB_ROWS;
  #pragma unroll
  for (int nt=0;nt<2;++nt){
    pa2[nt] = prelu_a[col[nt]];
    #pragma unroll
    for (int r=0;r<4;++r){
      int lr = 4*q + r;
      Creg[nt][r] = realr[r] ? Ckf[(kb*KB_ROWS+lr)*EE + col[nt]] : 0.f;
      nsv[nt][r]  = realr[r] ? emb[(size_t)(VOCAB-KK+kb*KB_ROWS+lr)*EE + col[nt]] : 0.f;
    }
  }

  const float* xrow  = senc + (size_t)b*TT*EE;
  const float* xwrow = xw   + (size_t)b*TT*EE;
  const float* xkrow = xk   + (size_t)b*TT*KK;

  float xwc[2] = { xwrow[col[0]], xwrow[col[1]] };
  float xkc[4];
  #pragma unroll
  for (int r=0;r<4;++r)
    xkc[r] = realr[r] ? xkrow[kb*KB_ROWS + 4*q + r] : 0.f;

  unsigned va0 = (unsigned)(uintptr_t)&L.st[0][0][0][0] + q*256 + c*8;
  __syncthreads();

  for (int t=0; t<TT; ++t){
    int p = t & 1, pn = p ^ 1;
    unsigned va = va0 + p*8192;

    // ---- inv norms + gate raw (deferred from prev step); t=0: state0=keys ----
    float invr[4], graw[4];
    if (t > 0){
      f4v n0 = *(const f4v*)&L.npart[p][0][4*q];
      f4v n1 = *(const f4v*)&L.npart[p][1][4*q];
      f4v n2 = *(const f4v*)&L.npart[p][2][4*q];
      f4v n3 = *(const f4v*)&L.npart[p][3][4*q];
      f4v g0 = *(const f4v*)&L.gpart[p][0][4*q];
      f4v g1 = *(const f4v*)&L.gpart[p][1][4*q];
      f4v g2 = *(const f4v*)&L.gpart[p][2][4*q];
      f4v g3 = *(const f4v*)&L.gpart[p][3][4*q];
      f4v ss = n0 + n1 + n2 + n3;
      f4v gg = g0 + g1 + g2 + g3;
      #pragma unroll
      for (int r=0;r<4;++r){
        invr[r] = __builtin_amdgcn_rcpf(__builtin_amdgcn_sqrtf(ss[r]) + 1e-8f);
        graw[r] = gg[r]*invr[r] + xkc[r];
      }
    } else {
      #pragma unroll
      for (int r=0;r<4;++r){ invr[r] = 1.0f; graw[r] = 2.0f*xkc[r]; }  // x.state0 = x.keys = xk
    }

    // ---- prefetch t+1 globals (incl. x at own cols for the deferred gate dot) ----
    float xvn[2] = {0.f,0.f}, xwn[2] = {0.f,0.f}, xkn[4] = {0.f,0.f,0.f,0.f};
    if (t+1 < TT){
      xvn[0] = xrow[(size_t)(t+1)*EE + col[0]];
      xvn[1] = xrow[(size_t)(t+1)*EE + col[1]];
      xwn[0] = xwrow[(size_t)(t+1)*EE + col[0]];
      xwn[1] = xwrow[(size_t)(t+1)*EE + col[1]];
      #pragma unroll
      for (int r=0;r<4;++r)
        if (realr[r]) xkn[r] = xkrow[(size_t)(t+1)*KK + kb*KB_ROWS + 4*q + r];
    }

    // ---- A-frags (s_hat_t) via hardware transpose reads: hi + lo planes ----
    h8v Ah[4] = { LDA(0,0), LDA(0,1), LDA(0,2), LDA(0,3) };
    h8v Al[4] = { LDA(1,0), LDA(1,1), LDA(1,2), LDA(1,3) };
    asm volatile("s_waitcnt lgkmcnt(0)" ::: "memory");
    __builtin_amdgcn_sched_barrier(0);

    f4v z4 = {0.f,0.f,0.f,0.f};
    f4v acc[2][2] = {{z4,z4},{z4,z4}};
    #pragma unroll
    for (int kk=0; kk<4; ++kk){
      int h = kk>>1;
      #pragma unroll
      for (int nt=0;nt<2;++nt){
        acc[nt][h] = MFMA16(Al[kk], bh[nt][kk], acc[nt][h]);
        acc[nt][h] = MFMA16(Ah[kk], bl[nt][kk], acc[nt][h]);
        acc[nt][h] = MFMA16(Ah[kk], bh[nt][kk], acc[nt][h]);
      }
    }
    f4v acc0 = acc[0][0] + acc[0][1];
    f4v acc1 = acc[1][0] + acc[1][1];

    // ---- gate sigmoid; new state; norm + gate partials for t+1 ----
    float s2[4], gp[4];
    #pragma unroll
    for (int r=0;r<4;++r){
      float g = __builtin_amdgcn_rcpf(1.0f + __builtin_amdgcn_exp2f(-1.442695040889f * graw[r]));
      float s2r = 0.f, gpr = 0.f;
      #pragma unroll
      for (int nt=0;nt<2;++nt){
        float so = nsv[nt][r] * invr[r];                       // normalized old state
        float cv = (nt ? acc1[r] : acc0[r])*invr[r] + Creg[nt][r] + xwc[nt];
        cv = cv > 0.f ? cv : pa2[nt]*cv;
        float n = so + g*cv;
        float sh = realr[r] ? (n > 0.f ? n : 1.0f) : 0.f;      // s_hat_{t+1}
        nsv[nt][r] = sh;
        s2r += n*n;
        gpr += xvn[nt]*sh;                                      // x_{t+1}.s_hat_{t+1}
      }
      #pragma unroll
      for (int off=1; off<16; off<<=1){
        s2r += __shfl_xor(s2r, off);
        gpr += __shfl_xor(gpr, off);
      }
      s2[r] = s2r; gp[r] = gpr;
    }
    if (c == 0){
      f4v np; np[0]=s2[0]; np[1]=s2[1]; np[2]=s2[2]; np[3]=s2[3];
      f4v gv; gv[0]=gp[0]; gv[1]=gp[1]; gv[2]=gp[2]; gv[3]=gp[3];
      *(f4v*)&L.npart[pn][cg][4*q] = np;
      *(f4v*)&L.gpart[pn][cg][4*q] = gv;
    }

    // ---- store s_hat_{t+1} (pkrtz split, uint2 stores) ----
    #pragma unroll
    for (int nt=0;nt<2;++nt){
      float v0=nsv[nt][0], v1=nsv[nt][1], v2=nsv[nt][2], v3=nsv[nt][3];
      fp2v pa = __builtin_amdgcn_cvt_pkrtz(v0, v1);
      fp2v pb = __builtin_amdgcn_cvt_pkrtz(v2, v3);
      float r0 = v0 - pk_lo(pa);
      float r1 = v1 - pk_hi(pa);
      float r2 = v2 - pk_lo(pb);
      float r3 = v3 - pk_hi(pb);
      fp2v pc = __builtin_amdgcn_cvt_pkrtz(r0, r1);
      fp2v pd = __builtin_amdgcn_cvt_pkrtz(r2, r3);
      *(uint2*)&L.st[pn][0][col[nt]][4*q] = make_uint2(pk2u(pa), pk2u(pb));
      *(uint2*)&L.st[pn][1][col[nt]][4*q] = make_uint2(pk2u(pc), pk2u(pd));
    }
    xwc[0]=xwn[0]; xwc[1]=xwn[1];
    #pragma unroll
    for (int r=0;r<4;++r) xkc[r]=xkn[r];
    __syncthreads();                              // ONE barrier per step
  }

  // ---- finalize: normalize last s_hat from registers + final npart ----
  {
    int pf = TT & 1;   // buffer holding final npart
    f4v p0 = *(const f4v*)&L.npart[pf][0][4*q];
    f4v p1 = *(const f4v*)&L.npart[pf][1][4*q];
    f4v p2 = *(const f4v*)&L.npart[pf][2][4*q];
    f4v p3 = *(const f4v*)&L.npart[pf][3][4*q];
    f4v ss = p0 + p1 + p2 + p3;
    #pragma unroll
    for (int r=0;r<4;++r){
      if (realr[r]){
        float inv = __builtin_amdgcn_rcpf(__builtin_amdgcn_sqrtf(ss[r]) + 1e-8f);
        #pragma unroll
        for (int nt=0;nt<2;++nt)
          zst[((size_t)b*KK + kb*KB_ROWS + 4*q + r)*EE + col[nt]] = nsv[nt][r]*inv;
      }
    }
  }
}

// ---------------- kernel 4b: tail (attention + u + z), needs all 20 k ----------------
__global__ __launch_bounds__(128) void k_tail(
    const float* __restrict__ zst, const float* __restrict__ qenc,
    const float* __restrict__ prelu_a, const float* __restrict__ H,
    float* __restrict__ zout)
{
  __shared__ float st[KK*EE];
  __shared__ float us[EE];
  __shared__ float red[2][KK];
  __shared__ float gs[KK];
  int b = blockIdx.x, tid = threadIdx.x;
  for (int i = tid; i < KK*EE; i += 128) st[i] = zst[(size_t)b*KK*EE + i];
  float qv = qenc[(size_t)b*EE + tid];
  __syncthreads();
  int wv = tid >> 6, ln = tid & 63;
  for (int k=0;k<KK;++k){
    float p = qv * st[k*EE + tid];
    #pragma unroll
    for (int off=32; off; off>>=1) p += __shfl_xor(p, off);
    if (ln == 0) red[wv][k] = p;
  }
  __syncthreads();
  if (tid == 0){
    float mx = -1e30f, gg[KK];
    for (int k=0;k<KK;++k){ float v = red[0][k]+red[1][k]; gg[k]=v; mx = fmaxf(mx, v); }
    float s = 0.f;
    for (int k=0;k<KK;++k){ float e_ = expf(gg[k]-mx); gg[k]=e_; s += e_; }
    for (int k=0;k<KK;++k) gs[k] = gg[k]/s;
  }
  __syncthreads();
  float u_ = 0.f;
  #pragma unroll
  for (int k=0;k<KK;++k) u_ += gs[k]*st[k*EE + tid];
  us[tid] = u_;
  __syncthreads();
  float hp = 0.f;
  const float* hr = H + (size_t)tid*EE;
  for (int e=0; e<EE; e+=4){
    float4 h4 = *(const float4*)(hr + e);
    float4 u4 = *(const float4*)(us + e);
    hp += h4.x*u4.x + h4.y*u4.y + h4.z*u4.z + h4.w*u4.w;
  }
  float zv = qv + hp;
  float pat = prelu_a[tid];
  zv = zv > 0.f ? zv : pat*zv;
  zout[(size_t)b*EE + tid] = zv;
}

// ---------------- kernel 5: y = z @ R^T via fp16-split MFMA ----------------
// Wave: 16 b-rows x 64 v-cols (4 v-tiles). A = z rows, B = R rows (as cols).
// C layout: col = lane&15, row = (lane>>4)*4 + reg.
__global__ __launch_bounds__(256) void k_out(
    const float* __restrict__ z, const float* __restrict__ R,
    float* __restrict__ y)
{
  int tid = threadIdx.x;
  int w = tid >> 6, l = tid & 63;
  int q = l >> 4, cc = l & 15;
  int b0 = blockIdx.y * 16;
  int vbase = blockIdx.x * 256 + w * 64;

  // A-frags: z rows (row = lane&15, k = q*8+j within each 32-slice)
  h8v ah[4], al[4];
  const float* zr = z + (size_t)(b0 + cc)*EE;
  #pragma unroll
  for (int kk=0;kk<4;++kk){
    float tmp[8];
    *(float4*)&tmp[0] = *(const float4*)(zr + kk*32 + q*8);
    *(float4*)&tmp[4] = *(const float4*)(zr + kk*32 + q*8 + 4);
    split2_8(tmp, ah[kk], al[kk]);
  }
  #pragma unroll
  for (int vt=0; vt<4; ++vt){
    int v = vbase + vt*16 + cc;
    int vc = v < VOCAB ? v : VOCAB-1;
    const float* rr = R + (size_t)vc*EE;
    h8v bh[4], bl[4];
    #pragma unroll
    for (int kk=0;kk<4;++kk){
      float tmp[8];
      *(float4*)&tmp[0] = *(const float4*)(rr + kk*32 + q*8);
      *(float4*)&tmp[4] = *(const float4*)(rr + kk*32 + q*8 + 4);
      split2_8(tmp, bh[kk], bl[kk]);
    }
    f4v acc = {0.f,0.f,0.f,0.f};
    #pragma unroll
    for (int kk=0;kk<4;++kk){
      acc = MFMA16(al[kk], bh[kk], acc);
      acc = MFMA16(ah[kk], bl[kk], acc);
      acc = MFMA16(ah[kk], bh[kk], acc);
    }
    if (v < VOCAB){
      #pragma unroll
      for (int r=0;r<4;++r)
        y[(size_t)(b0 + q*4 + r)*VOCAB + v] = acc[r];
    }
  }
}

// ---------------- launch ----------------
extern "C" void kernel_launch(void* const* d_in, const int* in_sizes, int n_in,
                              void* d_out, int out_size, void* d_ws, size_t ws_size,
                              hipStream_t stream)
{
  const int*   story = (const int*)d_in[0];
  const int*   query = (const int*)d_in[1];
  const float* emb   = (const float*)d_in[2];
  const float* smask = (const float*)d_in[3];
  const float* qmask = (const float*)d_in[4];
  const float* pa    = (const float*)d_in[5];
  const float* U     = (const float*)d_in[6];
  const float* V     = (const float*)d_in[7];
  const float* W     = (const float*)d_in[8];
  const float* bias  = (const float*)d_in[9];
  const float* H     = (const float*)d_in[10];
  const float* R     = (const float*)d_in[11];
  float* y  = (float*)d_out;
  float* ws = (float*)d_ws;

  float* s_enc = ws + OFF_SENC;
  float* q_enc = ws + OFF_QENC;
  float* Ckf   = ws + OFF_CKF;
  float* xw    = ws + OFF_XW;
  float* z     = ws + OFF_Z;
  float* xk    = ws + OFF_XK;
  float* zst   = ws + OFF_ST;

  k_embed_sum<<<dim3(BB*TT/8), 256, 0, stream>>>(story, emb, smask, s_enc, BB*TT, SS);
  k_embed_sum<<<dim3(BB/8),    256, 0, stream>>>(query, emb, qmask, q_enc, BB, QQ);
  k_ckf<<<dim3(KK), 128, 0, stream>>>(emb, V, bias, Ckf);
  k_xw<<<dim3(BB*TT/64), 256, 0, stream>>>(s_enc, W, emb, xw, xk);

  k_scan<<<dim3(BB*2), 256, 0, stream>>>(emb, U, s_enc, xw, xk, Ckf, pa, zst);
  k_tail<<<dim3(BB), 128, 0, stream>>>(zst, q_enc, pa, H, z);

  k_out<<<dim3((VOCAB+255)/256, BB/16), 256, 0, stream>>>(z, R, y);
}

// Round 12
// 422.043 us; speedup vs baseline: 2.6139x; 1.1312x over previous
//
#include <hip/hip_runtime.h>
#include <hip/hip_bf16.h>
#include <stdint.h>

#define BB 256
#define TT 128
#define SS 16
#define QQ 16
#define EE 128
#define KK 20
#define VOCAB 50020
#define KB_ROWS 10   // k-rows per scan block (2 blocks per batch)

typedef __attribute__((ext_vector_type(8))) _Float16 h8v;         // 8 fp16 (4 VGPR)
typedef __attribute__((ext_vector_type(2))) __fp16 fp2v;          // builtin's return type
typedef __attribute__((ext_vector_type(4))) unsigned short u4h;   // 4 x u16 (b64)
typedef __attribute__((ext_vector_type(4))) float f4v;            // MFMA acc
#define MFMA16(a,b,c) __builtin_amdgcn_mfma_f32_16x16x32_f16(a,b,c,0,0,0)

static __device__ __forceinline__ unsigned pk2u(fp2v h){
  union { fp2v h; unsigned u; } c; c.h = h; return c.u;
}
static __device__ __forceinline__ float pk_lo(fp2v h){ return (float)h[0]; }
static __device__ __forceinline__ float pk_hi(fp2v h){ return (float)h[1]; }
static __device__ __forceinline__ unsigned short h1u(_Float16 h){
  union { _Float16 h; unsigned short u; } c; c.h = h; return c.u;
}
// fp16 2-term split of 8 f32 (RN, used outside the hot loop)
static __device__ __forceinline__ void split2_8(const float* v, h8v& h, h8v& l){
  #pragma unroll
  for (int j=0;j<8;++j){
    _Float16 hb = (_Float16)v[j];
    float hf = (float)hb;
    h[j] = hb;
    l[j] = (_Float16)(v[j]-hf);
  }
}
// hardware transpose read: quarter-wave reads 128B region, lane gets column (l&15)
template<int IMM>
static __device__ __forceinline__ u4h tr_read(unsigned va){
  u4h d;
  asm volatile("ds_read_b64_tr_b16 %0, %1 offset:%c2" : "=v"(d) : "v"(va), "i"(IMM));
  return d;
}
static __device__ __forceinline__ h8v cat8h(u4h a, u4h b){
  union { u4h p[2]; h8v v; } u; u.p[0]=a; u.p[1]=b; return u.v;
}
// A-frag (state) for plane P (0=hi,1=lo), k-slice K4 within current ping buffer
#define LDA(P,K4) cat8h(tr_read<(P)*4096+(K4)*1024>(va), tr_read<(P)*4096+(K4)*1024+128>(va))

// ---------------- workspace layout (floats) ----------------
static const size_t OFF_SENC = 0;                              // B*T*E
static const size_t OFF_QENC = OFF_SENC + (size_t)BB*TT*EE;    // B*E
static const size_t OFF_CKF  = OFF_QENC + (size_t)BB*EE;       // K*E
static const size_t OFF_XW   = OFF_CKF  + (size_t)KK*EE;       // B*T*E
static const size_t OFF_Z    = OFF_XW   + (size_t)BB*TT*EE;    // B*E
static const size_t OFF_XK   = OFF_Z    + (size_t)BB*EE;       // B*T*K
static const size_t OFF_ST   = OFF_XK   + (size_t)BB*TT*KK;    // B*K*E

// ---------------- kernel 1: embedding bag-sum ----------------
__global__ __launch_bounds__(256) void k_embed_sum(
    const int* __restrict__ tok, const float* __restrict__ emb,
    const float* __restrict__ mask, float* __restrict__ out,
    int nrow, int ntok)
{
  int tid = threadIdx.x;
  int row = blockIdx.x*8 + (tid>>5);
  if (row >= nrow) return;
  int e4 = (tid&31)*4;
  float4 acc = make_float4(0.f,0.f,0.f,0.f);
  for (int s=0; s<ntok; ++s) {
    int id = tok[row*ntok + s];
    float4 ev = *(const float4*)(emb + (size_t)id*EE + e4);
    float4 mv = *(const float4*)(mask + s*EE + e4);
    acc.x += ev.x*mv.x; acc.y += ev.y*mv.y; acc.z += ev.z*mv.z; acc.w += ev.w*mv.w;
  }
  *(float4*)(out + (size_t)row*EE + e4) = acc;
}

// ---------------- kernel 2: Ckf[k][f] = bias[f] + keys[k] . V[f] ----------------
__global__ __launch_bounds__(128) void k_ckf(
    const float* __restrict__ emb, const float* __restrict__ V,
    const float* __restrict__ bias, float* __restrict__ Ckf)
{
  int k = blockIdx.x;
  int f = threadIdx.x;
  const float* key = emb + (size_t)(VOCAB-KK+k)*EE;
  const float* vr  = V + (size_t)f*EE;
  float acc = bias[f];
  for (int e=0; e<EE; e+=4) {
    float4 kv = *(const float4*)(key + e);
    float4 vv = *(const float4*)(vr + e);
    acc += kv.x*vv.x + kv.y*vv.y + kv.z*vv.z + kv.w*vv.w;
  }
  Ckf[k*EE + f] = acc;
}

// ---------------- kernel 3: xw = senc@W^T  and  xk = senc@keys^T ----------------
__global__ __launch_bounds__(256) void k_xw(
    const float* __restrict__ senc, const float* __restrict__ W,
    const float* __restrict__ emb, float* __restrict__ xw,
    float* __restrict__ xk)
{
  __shared__ float xs[64*EE];
  __shared__ float keys_s[KK*EE];
  int tid = threadIdx.x;
  int r0 = blockIdx.x*64;
  for (int i=0;i<8;++i){
    int idx = tid + i*256; int r = idx>>5; int c4 = (idx&31)*4;
    *(float4*)(xs + r*EE + c4) = *(const float4*)(senc + (size_t)(r0+r)*EE + c4);
  }
  for (int idx=tid; idx<KK*EE; idx+=256)
    keys_s[idx] = emb[(size_t)(VOCAB-KK + (idx>>7))*EE + (idx&127)];
  __syncthreads();
  int f  = tid & 127;
  int rh = tid >> 7;
  float acc[32];
  #pragma unroll
  for (int i=0;i<32;++i) acc[i]=0.f;
  const float* wr = W + (size_t)f*EE;
  for (int e4=0; e4<EE; e4+=4) {
    float4 w4 = *(const float4*)(wr + e4);
    #pragma unroll
    for (int rr=0; rr<32; ++rr) {
      float4 x4 = *(const float4*)(xs + (rh*32+rr)*EE + e4);
      acc[rr] += w4.x*x4.x + w4.y*x4.y + w4.z*x4.z + w4.w*x4.w;
    }
  }
  #pragma unroll
  for (int rr=0; rr<32; ++rr)
    xw[(size_t)(r0 + rh*32 + rr)*EE + f] = acc[rr];
  for (int i=0;i<5;++i){
    int task = tid + i*256;
    int r = task/KK, k = task - r*KK;
    float a = 0.f;
    for (int e=0; e<EE; e+=4){
      float4 x4 = *(const float4*)(xs + r*EE + e);
      float4 k4 = *(const float4*)(keys_s + k*EE + e);
      a += x4.x*k4.x + x4.y*k4.y + x4.z*k4.z + x4.w*k4.w;
    }
    xk[(size_t)(r0+r)*KK + k] = a;
  }
}

// ---------------- kernel 4: MFMA scan — fp16 2-term, deferred norm, ping-pong ----
// (R10 structure, verbatim — gate via MFMA stays off the critical path.)
struct ScanLds {
  unsigned short st[2][2][EE][16];  // 16384 B (buf, plane hi/lo, e, k-row)
  unsigned short xp[2][2][EE];      // 1024 B
  float npart[2][4][16];            // 512 B
};

__global__ __launch_bounds__(256) void k_scan(
    const float* __restrict__ emb, const float* __restrict__ U,
    const float* __restrict__ senc, const float* __restrict__ xw,
    const float* __restrict__ xk, const float* __restrict__ Ckf,
    const float* __restrict__ prelu_a, float* __restrict__ zst)
{
  __shared__ ScanLds L;
  int tid = threadIdx.x;
  int bid = blockIdx.x;
  int b   = bid >> 1, kb = bid & 1;
  int l   = tid & 63, cg = tid >> 6;
  int q   = l >> 4,  c  = l & 15;
  int col[2] = { cg*32 + c, cg*32 + 16 + c };

  // ---- zero both state buffers (pad rows must stay 0) ----
  for (int idx = tid; idx < 2*2*EE*16; idx += 256) ((unsigned short*)L.st)[idx] = 0;
  __syncthreads();
  // ---- init s_hat_0 = keys (raw, unnormalized — matches reference state0) ----
  for (int idx = tid; idx < KB_ROWS*EE; idx += 256){
    int row = idx >> 7, e = idx & 127;
    float v = emb[(size_t)(VOCAB - KK + kb*KB_ROWS + row)*EE + e];
    _Float16 hb = (_Float16)v;
    _Float16 lb = (_Float16)(v - (float)hb);
    L.st[0][0][e][row] = h1u(hb);
    L.st[0][1][e][row] = h1u(lb);
  }
  // ---- B-frags: U columns, fp16 hi/lo, constant across scan ----
  h8v bh[2][4], bl[2][4];
  #pragma unroll
  for (int nt=0;nt<2;++nt)
    #pragma unroll
    for (int kk=0;kk<4;++kk){
      float tmp[8];
      const float* up = U + (size_t)col[nt]*EE + kk*32 + q*8;
      *(float4*)&tmp[0] = *(const float4*)up;
      *(float4*)&tmp[4] = *(const float4*)(up+4);
      split2_8(tmp, bh[nt][kk], bl[nt][kk]);
    }
  // ---- per-lane constants; nsv = register copy of own s_hat values ----
  float Creg[2][4], pa2[2], nsv[2][4];
  bool realr[4];
  #pragma unroll
  for (int r=0;r<4;++r) realr[r] = (4*q + r) < KB_ROWS;
  #pragma unroll
  for (int nt=0;nt<2;++nt){
    pa2[nt] = prelu_a[col[nt]];
    #pragma unroll
    for (int r=0;r<4;++r){
      int lr = 4*q + r;
      Creg[nt][r] = realr[r] ? Ckf[(kb*KB_ROWS+lr)*EE + col[nt]] : 0.f;
      nsv[nt][r]  = realr[r] ? emb[(size_t)(VOCAB-KK+kb*KB_ROWS+lr)*EE + col[nt]] : 0.f;
    }
  }

  const float* xrow  = senc + (size_t)b*TT*EE;
  const float* xwrow = xw   + (size_t)b*TT*EE;
  const float* xkrow = xk   + (size_t)b*TT*KK;

  // t=0 staging into buf 0
  if (tid < EE){
    float v = xrow[tid];
    _Float16 hb = (_Float16)v;
    _Float16 lb = (_Float16)(v - (float)hb);
    L.xp[0][0][tid] = h1u(hb); L.xp[0][1][tid] = h1u(lb);
  }
  float xwc[2] = { xwrow[col[0]], xwrow[col[1]] };
  float xkc[4];
  #pragma unroll
  for (int r=0;r<4;++r)
    xkc[r] = realr[r] ? xkrow[kb*KB_ROWS + 4*q + r] : 0.f;

  unsigned va0 = (unsigned)(uintptr_t)&L.st[0][0][0][0] + q*256 + c*8;
  __syncthreads();

  for (int t=0; t<TT; ++t){
    int p = t & 1, pn = p ^ 1;
    unsigned va = va0 + p*8192;
    const unsigned short (*xpp)[EE] = L.xp[p];

    // ---- inv norms of s_hat_t (from prev step's npart); t=0: state0 unnormalized ----
    float invr[4];
    if (t > 0){
      f4v p0 = *(const f4v*)&L.npart[p][0][4*q];
      f4v p1 = *(const f4v*)&L.npart[p][1][4*q];
      f4v p2 = *(const f4v*)&L.npart[p][2][4*q];
      f4v p3 = *(const f4v*)&L.npart[p][3][4*q];
      f4v ss = p0 + p1 + p2 + p3;
      #pragma unroll
      for (int r=0;r<4;++r)
        invr[r] = __builtin_amdgcn_rcpf(__builtin_amdgcn_sqrtf(ss[r]) + 1e-8f);
    } else {
      #pragma unroll
      for (int r=0;r<4;++r) invr[r] = 1.0f;
    }

    // ---- prefetch t+1 globals ----
    float nxv = 0.f, xwn[2] = {0.f,0.f}, xkn[4] = {0.f,0.f,0.f,0.f};
    if (t+1 < TT){
      if (tid < EE) nxv = xrow[(size_t)(t+1)*EE + tid];
      xwn[0] = xwrow[(size_t)(t+1)*EE + col[0]];
      xwn[1] = xwrow[(size_t)(t+1)*EE + col[1]];
      #pragma unroll
      for (int r=0;r<4;++r)
        if (realr[r]) xkn[r] = xkrow[(size_t)(t+1)*KK + kb*KB_ROWS + 4*q + r];
    }

    // ---- A-frags (s_hat_t) via hardware transpose reads: hi + lo planes ----
    h8v Ah[4] = { LDA(0,0), LDA(0,1), LDA(0,2), LDA(0,3) };
    h8v Al[4] = { LDA(1,0), LDA(1,1), LDA(1,2), LDA(1,3) };
    asm volatile("s_waitcnt lgkmcnt(0)" ::: "memory");
    __builtin_amdgcn_sched_barrier(0);

    f4v z4 = {0.f,0.f,0.f,0.f};
    f4v acc[2][2] = {{z4,z4},{z4,z4}};
    f4v gac[2] = {z4,z4};
    #pragma unroll
    for (int kk=0; kk<4; ++kk){
      int h = kk>>1;
      h8v xh = *(const h8v*)&xpp[0][kk*32 + q*8];
      h8v xl = *(const h8v*)&xpp[1][kk*32 + q*8];
      #pragma unroll
      for (int nt=0;nt<2;++nt){
        acc[nt][h] = MFMA16(Al[kk], bh[nt][kk], acc[nt][h]);
        acc[nt][h] = MFMA16(Ah[kk], bl[nt][kk], acc[nt][h]);
        acc[nt][h] = MFMA16(Ah[kk], bh[nt][kk], acc[nt][h]);
      }
      gac[h] = MFMA16(Al[kk], xh, gac[h]);
      gac[h] = MFMA16(Ah[kk], xl, gac[h]);
      gac[h] = MFMA16(Ah[kk], xh, gac[h]);
    }
    f4v acc0 = acc[0][0] + acc[0][1];
    f4v acc1 = acc[1][0] + acc[1][1];
    f4v gacc = gac[0] + gac[1];

    // ---- deferred normalization: scale GEMM rows by inv; gate; new state ----
    float s2[4];
    #pragma unroll
    for (int r=0;r<4;++r){
      float graw = gacc[r]*invr[r] + xkc[r];
      float g = __builtin_amdgcn_rcpf(1.0f + __builtin_amdgcn_exp2f(-1.442695040889f * graw));
      float s2r = 0.f;
      #pragma unroll
      for (int nt=0;nt<2;++nt){
        float so = nsv[nt][r] * invr[r];                       // normalized old state
        float cv = (nt ? acc1[r] : acc0[r])*invr[r] + Creg[nt][r] + xwc[nt];
        cv = cv > 0.f ? cv : pa2[nt]*cv;
        float n = so + g*cv;
        nsv[nt][r] = realr[r] ? (n > 0.f ? n : 1.0f) : 0.f;    // s_hat_{t+1}
        s2r += n*n;
      }
      s2r += __shfl_xor(s2r, 1);
      s2r += __shfl_xor(s2r, 2);
      s2r += __shfl_xor(s2r, 4);
      s2r += __shfl_xor(s2r, 8);
      s2[r] = s2r;
    }
    if (c == 0){
      f4v np; np[0]=s2[0]; np[1]=s2[1]; np[2]=s2[2]; np[3]=s2[3];
      *(f4v*)&L.npart[pn][cg][4*q] = np;
    }

    // ---- store s_hat_{t+1} (pkrtz split, uint2 stores) + stage x_{t+1} ----
    #pragma unroll
    for (int nt=0;nt<2;++nt){
      float v0=nsv[nt][0], v1=nsv[nt][1], v2=nsv[nt][2], v3=nsv[nt][3];
      fp2v pa = __builtin_amdgcn_cvt_pkrtz(v0, v1);
      fp2v pb = __builtin_amdgcn_cvt_pkrtz(v2, v3);
      float r0 = v0 - pk_lo(pa);
      float r1 = v1 - pk_hi(pa);
      float r2 = v2 - pk_lo(pb);
      float r3 = v3 - pk_hi(pb);
      fp2v pc = __builtin_amdgcn_cvt_pkrtz(r0, r1);
      fp2v pd = __builtin_amdgcn_cvt_pkrtz(r2, r3);
      *(uint2*)&L.st[pn][0][col[nt]][4*q] = make_uint2(pk2u(pa), pk2u(pb));
      *(uint2*)&L.st[pn][1][col[nt]][4*q] = make_uint2(pk2u(pc), pk2u(pd));
    }
    if (t+1 < TT && tid < EE){
      _Float16 hb = (_Float16)nxv;
      _Float16 lb = (_Float16)(nxv - (float)hb);
      L.xp[pn][0][tid] = h1u(hb); L.xp[pn][1][tid] = h1u(lb);
    }
    xwc[0]=xwn[0]; xwc[1]=xwn[1];
    #pragma unroll
    for (int r=0;r<4;++r) xkc[r]=xkn[r];
    __syncthreads();                              // ONE barrier per step
  }

  // ---- finalize: normalize last s_hat from registers + final npart ----
  {
    int pf = TT & 1;   // buffer holding final npart
    f4v p0 = *(const f4v*)&L.npart[pf][0][4*q];
    f4v p1 = *(const f4v*)&L.npart[pf][1][4*q];
    f4v p2 = *(const f4v*)&L.npart[pf][2][4*q];
    f4v p3 = *(const f4v*)&L.npart[pf][3][4*q];
    f4v ss = p0 + p1 + p2 + p3;
    #pragma unroll
    for (int r=0;r<4;++r){
      if (realr[r]){
        float inv = __builtin_amdgcn_rcpf(__builtin_amdgcn_sqrtf(ss[r]) + 1e-8f);
        #pragma unroll
        for (int nt=0;nt<2;++nt)
          zst[((size_t)b*KK + kb*KB_ROWS + 4*q + r)*EE + col[nt]] = nsv[nt][r]*inv;
      }
    }
  }
}

// ---------------- kernel 4b: tail (attention + u + z), needs all 20 k ----------------
__global__ __launch_bounds__(128) void k_tail(
    const float* __restrict__ zst, const float* __restrict__ qenc,
    const float* __restrict__ prelu_a, const float* __restrict__ H,
    float* __restrict__ zout)
{
  __shared__ float st[KK*EE];
  __shared__ float us[EE];
  __shared__ float red[2][KK];
  __shared__ float gs[KK];
  int b = blockIdx.x, tid = threadIdx.x;
  for (int i = tid; i < KK*EE; i += 128) st[i] = zst[(size_t)b*KK*EE + i];
  float qv = qenc[(size_t)b*EE + tid];
  __syncthreads();
  int wv = tid >> 6, ln = tid & 63;
  for (int k=0;k<KK;++k){
    float p = qv * st[k*EE + tid];
    #pragma unroll
    for (int off=32; off; off>>=1) p += __shfl_xor(p, off);
    if (ln == 0) red[wv][k] = p;
  }
  __syncthreads();
  if (tid == 0){
    float mx = -1e30f, gg[KK];
    for (int k=0;k<KK;++k){ float v = red[0][k]+red[1][k]; gg[k]=v; mx = fmaxf(mx, v); }
    float s = 0.f;
    for (int k=0;k<KK;++k){ float e_ = expf(gg[k]-mx); gg[k]=e_; s += e_; }
    for (int k=0;k<KK;++k) gs[k] = gg[k]/s;
  }
  __syncthreads();
  float u_ = 0.f;
  #pragma unroll
  for (int k=0;k<KK;++k) u_ += gs[k]*st[k*EE + tid];
  us[tid] = u_;
  __syncthreads();
  float hp = 0.f;
  const float* hr = H + (size_t)tid*EE;
  for (int e=0; e<EE; e+=4){
    float4 h4 = *(const float4*)(hr + e);
    float4 u4 = *(const float4*)(us + e);
    hp += h4.x*u4.x + h4.y*u4.y + h4.z*u4.z + h4.w*u4.w;
  }
  float zv = qv + hp;
  float pat = prelu_a[tid];
  zv = zv > 0.f ? zv : pat*zv;
  zout[(size_t)b*EE + tid] = zv;
}

// ---------------- kernel 5: y = z @ R^T via fp16-split MFMA, 2 M-tiles/block ----
// Wave: 32 b-rows x 64 v-cols. B-frags (R) loaded once, reused across both
// M-tiles -> R traffic halves vs 16-row blocks.
__global__ __launch_bounds__(256) void k_out(
    const float* __restrict__ z, const float* __restrict__ R,
    float* __restrict__ y)
{
  int tid = threadIdx.x;
  int w = tid >> 6, l = tid & 63;
  int q = l >> 4, cc = l & 15;
  int b0 = blockIdx.y * 32;
  int vbase = blockIdx.x * 256 + w * 64;

  // A-frags: z rows for 2 M-tiles (row = lane&15 within tile)
  h8v ah[2][4], al[2][4];
  #pragma unroll
  for (int mt=0;mt<2;++mt){
    const float* zr = z + (size_t)(b0 + mt*16 + cc)*EE;
    #pragma unroll
    for (int kk=0;kk<4;++kk){
      float tmp[8];
      *(float4*)&tmp[0] = *(const float4*)(zr + kk*32 + q*8);
      *(float4*)&tmp[4] = *(const float4*)(zr + kk*32 + q*8 + 4);
      split2_8(tmp, ah[mt][kk], al[mt][kk]);
    }
  }
  #pragma unroll
  for (int vt=0; vt<4; ++vt){
    int v = vbase + vt*16 + cc;
    int vc = v < VOCAB ? v : VOCAB-1;
    const float* rr = R + (size_t)vc*EE;
    h8v bh[4], bl[4];
    #pragma unroll
    for (int kk=0;kk<4;++kk){
      float tmp[8];
      *(float4*)&tmp[0] = *(const float4*)(rr + kk*32 + q*8);
      *(float4*)&tmp[4] = *(const float4*)(rr + kk*32 + q*8 + 4);
      split2_8(tmp, bh[kk], bl[kk]);
    }
    f4v acc0 = {0.f,0.f,0.f,0.f};
    f4v acc1 = {0.f,0.f,0.f,0.f};
    #pragma unroll
    for (int kk=0;kk<4;++kk){
      acc0 = MFMA16(al[0][kk], bh[kk], acc0);
      acc0 = MFMA16(ah[0][kk], bl[kk], acc0);
      acc0 = MFMA16(ah[0][kk], bh[kk], acc0);
      acc1 = MFMA16(al[1][kk], bh[kk], acc1);
      acc1 = MFMA16(ah[1][kk], bl[kk], acc1);
      acc1 = MFMA16(ah[1][kk], bh[kk], acc1);
    }
    if (v < VOCAB){
      #pragma unroll
      for (int r=0;r<4;++r){
        y[(size_t)(b0 + q*4 + r)*VOCAB + v]      = acc0[r];
        y[(size_t)(b0 + 16 + q*4 + r)*VOCAB + v] = acc1[r];
      }
    }
  }
}

// ---------------- launch ----------------
extern "C" void kernel_launch(void* const* d_in, const int* in_sizes, int n_in,
                              void* d_out, int out_size, void* d_ws, size_t ws_size,
                              hipStream_t stream)
{
  const int*   story = (const int*)d_in[0];
  const int*   query = (const int*)d_in[1];
  const float* emb   = (const float*)d_in[2];
  const float* smask = (const float*)d_in[3];
  const float* qmask = (const float*)d_in[4];
  const float* pa    = (const float*)d_in[5];
  const float* U     = (const float*)d_in[6];
  const float* V     = (const float*)d_in[7];
  const float* W     = (const float*)d_in[8];
  const float* bias  = (const float*)d_in[9];
  const float* H     = (const float*)d_in[10];
  const float* R     = (const float*)d_in[11];
  float* y  = (float*)d_out;
  float* ws = (float*)d_ws;

  float* s_enc = ws + OFF_SENC;
  float* q_enc = ws + OFF_QENC;
  float* Ckf   = ws + OFF_CKF;
  float* xw    = ws + OFF_XW;
  float* z     = ws + OFF_Z;
  float* xk    = ws + OFF_XK;
  float* zst   = ws + OFF_ST;

  k_embed_sum<<<dim3(BB*TT/8), 256, 0, stream>>>(story, emb, smask, s_enc, BB*TT, SS);
  k_embed_sum<<<dim3(BB/8),    256, 0, stream>>>(query, emb, qmask, q_enc, BB, QQ);
  k_ckf<<<dim3(KK), 128, 0, stream>>>(emb, V, bias, Ckf);
  k_xw<<<dim3(BB*TT/64), 256, 0, stream>>>(s_enc, W, emb, xw, xk);

  k_scan<<<dim3(BB*2), 256, 0, stream>>>(emb, U, s_enc, xw, xk, Ckf, pa, zst);
  k_tail<<<dim3(BB), 128, 0, stream>>>(zst, q_enc, pa, H, z);

  k_out<<<dim3((VOCAB+255)/256, BB/32), 256, 0, stream>>>(z, R, y);
}

// Round 13
// 379.105 us; speedup vs baseline: 2.9099x; 1.1133x over previous
//
#include <hip/hip_runtime.h>
#include <hip/hip_bf16.h>
#include <stdint.h>

#define BB 256
#define TT 128
#define SS 16
#define QQ 16
#define EE 128
#define KK 20
#define VOCAB 50020
#define KB_ROWS 10   // k-rows per scan block (2 blocks per batch)
#define XK_STR 24    // padded xk row stride (halves at 0 and 12, 16B-aligned)

typedef __attribute__((ext_vector_type(8))) _Float16 h8v;         // 8 fp16 (4 VGPR)
typedef __attribute__((ext_vector_type(2))) __fp16 fp2v;          // builtin's return type
typedef __attribute__((ext_vector_type(4))) unsigned short u4h;   // 4 x u16 (b64)
typedef __attribute__((ext_vector_type(4))) float f4v;            // MFMA acc
#define MFMA16(a,b,c) __builtin_amdgcn_mfma_f32_16x16x32_f16(a,b,c,0,0,0)

static __device__ __forceinline__ unsigned pk2u(fp2v h){
  union { fp2v h; unsigned u; } c; c.h = h; return c.u;
}
static __device__ __forceinline__ float pk_lo(fp2v h){ return (float)h[0]; }
static __device__ __forceinline__ float pk_hi(fp2v h){ return (float)h[1]; }
static __device__ __forceinline__ unsigned short h1u(_Float16 h){
  union { _Float16 h; unsigned short u; } c; c.h = h; return c.u;
}
// fp16 2-term split of 8 f32 (RN, used outside the hot loop)
static __device__ __forceinline__ void split2_8(const float* v, h8v& h, h8v& l){
  #pragma unroll
  for (int j=0;j<8;++j){
    _Float16 hb = (_Float16)v[j];
    float hf = (float)hb;
    h[j] = hb;
    l[j] = (_Float16)(v[j]-hf);
  }
}
// 16-lane row sum via DPP (quad_perm xor1, xor2, row_ror:4, row_ror:8)
static __device__ __forceinline__ float dpp_add16(float x){
  int v;
  v = __builtin_amdgcn_update_dpp(0, __float_as_int(x), 0xB1, 0xF, 0xF, true);
  x += __int_as_float(v);
  v = __builtin_amdgcn_update_dpp(0, __float_as_int(x), 0x4E, 0xF, 0xF, true);
  x += __int_as_float(v);
  v = __builtin_amdgcn_update_dpp(0, __float_as_int(x), 0x124, 0xF, 0xF, true);
  x += __int_as_float(v);
  v = __builtin_amdgcn_update_dpp(0, __float_as_int(x), 0x128, 0xF, 0xF, true);
  x += __int_as_float(v);
  return x;
}
// hardware transpose read: quarter-wave reads 128B region, lane gets column (l&15)
template<int IMM>
static __device__ __forceinline__ u4h tr_read(unsigned va){
  u4h d;
  asm volatile("ds_read_b64_tr_b16 %0, %1 offset:%c2" : "=v"(d) : "v"(va), "i"(IMM));
  return d;
}
static __device__ __forceinline__ h8v cat8h(u4h a, u4h b){
  union { u4h p[2]; h8v v; } u; u.p[0]=a; u.p[1]=b; return u.v;
}
// A-frag (state) for plane P (0=hi,1=lo), k-slice K4 within current ping buffer
#define LDA(P,K4) cat8h(tr_read<(P)*4096+(K4)*1024>(va), tr_read<(P)*4096+(K4)*1024+128>(va))

// ---------------- workspace layout (floats) ----------------
static const size_t OFF_SENC = 0;                              // B*T*E
static const size_t OFF_QENC = OFF_SENC + (size_t)BB*TT*EE;    // B*E
static const size_t OFF_CKF  = OFF_QENC + (size_t)BB*EE;       // K*E
static const size_t OFF_XW   = OFF_CKF  + (size_t)KK*EE;       // B*T*E
static const size_t OFF_Z    = OFF_XW   + (size_t)BB*TT*EE;    // B*E
static const size_t OFF_XK   = OFF_Z    + (size_t)BB*EE;       // B*T*XK_STR
static const size_t OFF_ST   = OFF_XK   + (size_t)BB*TT*XK_STR; // B*K*E

// ---------------- kernel 1: embedding bag-sum (ntok fixed at 16, unrolled) ----------------
__global__ __launch_bounds__(256) void k_embed_sum(
    const int* __restrict__ tok, const float* __restrict__ emb,
    const float* __restrict__ mask, float* __restrict__ out,
    int nrow)
{
  int tid = threadIdx.x;
  int row = blockIdx.x*8 + (tid>>5);
  if (row >= nrow) return;
  int e4 = (tid&31)*4;
  float4 acc = make_float4(0.f,0.f,0.f,0.f);
  #pragma unroll
  for (int s=0; s<16; ++s) {
    int id = tok[row*16 + s];
    float4 ev = *(const float4*)(emb + (size_t)id*EE + e4);
    float4 mv = *(const float4*)(mask + s*EE + e4);
    acc.x += ev.x*mv.x; acc.y += ev.y*mv.y; acc.z += ev.z*mv.z; acc.w += ev.w*mv.w;
  }
  *(float4*)(out + (size_t)row*EE + e4) = acc;
}

// ---------------- kernel 2: Ckf[k][f] = bias[f] + keys[k] . V[f] ----------------
__global__ __launch_bounds__(128) void k_ckf(
    const float* __restrict__ emb, const float* __restrict__ V,
    const float* __restrict__ bias, float* __restrict__ Ckf)
{
  int k = blockIdx.x;
  int f = threadIdx.x;
  const float* key = emb + (size_t)(VOCAB-KK+k)*EE;
  const float* vr  = V + (size_t)f*EE;
  float acc = bias[f];
  for (int e=0; e<EE; e+=4) {
    float4 kv = *(const float4*)(key + e);
    float4 vv = *(const float4*)(vr + e);
    acc += kv.x*vv.x + kv.y*vv.y + kv.z*vv.z + kv.w*vv.w;
  }
  Ckf[k*EE + f] = acc;
}

// ---------------- kernel 3: xw = senc@W^T  and  xk = senc@keys^T (padded) --------
__global__ __launch_bounds__(256) void k_xw(
    const float* __restrict__ senc, const float* __restrict__ W,
    const float* __restrict__ emb, float* __restrict__ xw,
    float* __restrict__ xk)
{
  __shared__ float xs[64*EE];
  __shared__ float keys_s[KK*EE];
  int tid = threadIdx.x;
  int r0 = blockIdx.x*64;
  for (int i=0;i<8;++i){
    int idx = tid + i*256; int r = idx>>5; int c4 = (idx&31)*4;
    *(float4*)(xs + r*EE + c4) = *(const float4*)(senc + (size_t)(r0+r)*EE + c4);
  }
  for (int idx=tid; idx<KK*EE; idx+=256)
    keys_s[idx] = emb[(size_t)(VOCAB-KK + (idx>>7))*EE + (idx&127)];
  __syncthreads();
  int f  = tid & 127;
  int rh = tid >> 7;
  float acc[32];
  #pragma unroll
  for (int i=0;i<32;++i) acc[i]=0.f;
  const float* wr = W + (size_t)f*EE;
  for (int e4=0; e4<EE; e4+=4) {
    float4 w4 = *(const float4*)(wr + e4);
    #pragma unroll
    for (int rr=0; rr<32; ++rr) {
      float4 x4 = *(const float4*)(xs + (rh*32+rr)*EE + e4);
      acc[rr] += w4.x*x4.x + w4.y*x4.y + w4.z*x4.z + w4.w*x4.w;
    }
  }
  #pragma unroll
  for (int rr=0; rr<32; ++rr)
    xw[(size_t)(r0 + rh*32 + rr)*EE + f] = acc[rr];
  for (int i=0;i<5;++i){
    int task = tid + i*256;
    int r = task/KK, k = task - r*KK;
    float a = 0.f;
    for (int e=0; e<EE; e+=4){
      float4 x4 = *(const float4*)(xs + r*EE + e);
      float4 k4 = *(const float4*)(keys_s + k*EE + e);
      a += x4.x*k4.x + x4.y*k4.y + x4.z*k4.z + x4.w*k4.w;
    }
    int ki = k < 10 ? k : k + 2;   // halves at 0 and 12
    xk[(size_t)(r0+r)*XK_STR + ki] = a;
  }
}

// ---------------- kernel 4: MFMA scan — fp16 2-term, deferred norm, ping-pong ----
// R12 structure + DPP reduce + float4 xk loads.
struct ScanLds {
  unsigned short st[2][2][EE][16];  // 16384 B (buf, plane hi/lo, e, k-row)
  unsigned short xp[2][2][EE];      // 1024 B
  float npart[2][4][16];            // 512 B
};

__global__ __launch_bounds__(256) void k_scan(
    const float* __restrict__ emb, const float* __restrict__ U,
    const float* __restrict__ senc, const float* __restrict__ xw,
    const float* __restrict__ xk, const float* __restrict__ Ckf,
    const float* __restrict__ prelu_a, float* __restrict__ zst)
{
  __shared__ ScanLds L;
  int tid = threadIdx.x;
  int bid = blockIdx.x;
  int b   = bid >> 1, kb = bid & 1;
  int l   = tid & 63, cg = tid >> 6;
  int q   = l >> 4,  c  = l & 15;
  int col[2] = { cg*32 + c, cg*32 + 16 + c };

  // ---- zero both state buffers (pad rows must stay 0) ----
  for (int idx = tid; idx < 2*2*EE*16; idx += 256) ((unsigned short*)L.st)[idx] = 0;
  __syncthreads();
  // ---- init s_hat_0 = keys (raw, unnormalized — matches reference state0) ----
  for (int idx = tid; idx < KB_ROWS*EE; idx += 256){
    int row = idx >> 7, e = idx & 127;
    float v = emb[(size_t)(VOCAB - KK + kb*KB_ROWS + row)*EE + e];
    _Float16 hb = (_Float16)v;
    _Float16 lb = (_Float16)(v - (float)hb);
    L.st[0][0][e][row] = h1u(hb);
    L.st[0][1][e][row] = h1u(lb);
  }
  // ---- B-frags: U columns, fp16 hi/lo, constant across scan ----
  h8v bh[2][4], bl[2][4];
  #pragma unroll
  for (int nt=0;nt<2;++nt)
    #pragma unroll
    for (int kk=0;kk<4;++kk){
      float tmp[8];
      const float* up = U + (size_t)col[nt]*EE + kk*32 + q*8;
      *(float4*)&tmp[0] = *(const float4*)up;
      *(float4*)&tmp[4] = *(const float4*)(up+4);
      split2_8(tmp, bh[nt][kk], bl[nt][kk]);
    }
  // ---- per-lane constants; nsv = register copy of own s_hat values ----
  float Creg[2][4], pa2[2], nsv[2][4];
  bool realr[4];
  #pragma unroll
  for (int r=0;r<4;++r) realr[r] = (4*q + r) < KB_ROWS;
  #pragma unroll
  for (int nt=0;nt<2;++nt){
    pa2[nt] = prelu_a[col[nt]];
    #pragma unroll
    for (int r=0;r<4;++r){
      int lr = 4*q + r;
      Creg[nt][r] = realr[r] ? Ckf[(kb*KB_ROWS+lr)*EE + col[nt]] : 0.f;
      nsv[nt][r]  = realr[r] ? emb[(size_t)(VOCAB-KK+kb*KB_ROWS+lr)*EE + col[nt]] : 0.f;
    }
  }

  const float* xrow  = senc + (size_t)b*TT*EE;
  const float* xwrow = xw   + (size_t)b*TT*EE;
  const float* xkrow = xk   + (size_t)b*TT*XK_STR + kb*12;   // 16B-aligned half

  // t=0 staging into buf 0
  if (tid < EE){
    float v = xrow[tid];
    _Float16 hb = (_Float16)v;
    _Float16 lb = (_Float16)(v - (float)hb);
    L.xp[0][0][tid] = h1u(hb); L.xp[0][1][tid] = h1u(lb);
  }
  float xwc[2] = { xwrow[col[0]], xwrow[col[1]] };
  float xkc[4];
  {
    f4v xk4 = {0.f,0.f,0.f,0.f};
    if (q < 3) xk4 = *(const f4v*)(xkrow + 4*q);
    #pragma unroll
    for (int r=0;r<4;++r) xkc[r] = realr[r] ? xk4[r] : 0.f;
  }

  unsigned va0 = (unsigned)(uintptr_t)&L.st[0][0][0][0] + q*256 + c*8;
  __syncthreads();

  for (int t=0; t<TT; ++t){
    int p = t & 1, pn = p ^ 1;
    unsigned va = va0 + p*8192;
    const unsigned short (*xpp)[EE] = L.xp[p];

    // ---- inv norms of s_hat_t (from prev step's npart); t=0: state0 unnormalized ----
    float invr[4];
    if (t > 0){
      f4v p0 = *(const f4v*)&L.npart[p][0][4*q];
      f4v p1 = *(const f4v*)&L.npart[p][1][4*q];
      f4v p2 = *(const f4v*)&L.npart[p][2][4*q];
      f4v p3 = *(const f4v*)&L.npart[p][3][4*q];
      f4v ss = p0 + p1 + p2 + p3;
      #pragma unroll
      for (int r=0;r<4;++r)
        invr[r] = __builtin_amdgcn_rcpf(__builtin_amdgcn_sqrtf(ss[r]) + 1e-8f);
    } else {
      #pragma unroll
      for (int r=0;r<4;++r) invr[r] = 1.0f;
    }

    // ---- prefetch t+1 globals ----
    float nxv = 0.f, xwn[2] = {0.f,0.f};
    f4v xk4n = {0.f,0.f,0.f,0.f};
    if (t+1 < TT){
      if (tid < EE) nxv = xrow[(size_t)(t+1)*EE + tid];
      xwn[0] = xwrow[(size_t)(t+1)*EE + col[0]];
      xwn[1] = xwrow[(size_t)(t+1)*EE + col[1]];
      if (q < 3) xk4n = *(const f4v*)(xkrow + (size_t)(t+1)*XK_STR + 4*q);
    }

    // ---- A-frags (s_hat_t) via hardware transpose reads: hi + lo planes ----
    h8v Ah[4] = { LDA(0,0), LDA(0,1), LDA(0,2), LDA(0,3) };
    h8v Al[4] = { LDA(1,0), LDA(1,1), LDA(1,2), LDA(1,3) };
    asm volatile("s_waitcnt lgkmcnt(0)" ::: "memory");
    __builtin_amdgcn_sched_barrier(0);

    f4v z4 = {0.f,0.f,0.f,0.f};
    f4v acc[2][2] = {{z4,z4},{z4,z4}};
    f4v gac[2] = {z4,z4};
    #pragma unroll
    for (int kk=0; kk<4; ++kk){
      int h = kk>>1;
      h8v xh = *(const h8v*)&xpp[0][kk*32 + q*8];
      h8v xl = *(const h8v*)&xpp[1][kk*32 + q*8];
      #pragma unroll
      for (int nt=0;nt<2;++nt){
        acc[nt][h] = MFMA16(Al[kk], bh[nt][kk], acc[nt][h]);
        acc[nt][h] = MFMA16(Ah[kk], bl[nt][kk], acc[nt][h]);
        acc[nt][h] = MFMA16(Ah[kk], bh[nt][kk], acc[nt][h]);
      }
      gac[h] = MFMA16(Al[kk], xh, gac[h]);
      gac[h] = MFMA16(Ah[kk], xl, gac[h]);
      gac[h] = MFMA16(Ah[kk], xh, gac[h]);
    }
    f4v acc0 = acc[0][0] + acc[0][1];
    f4v acc1 = acc[1][0] + acc[1][1];
    f4v gacc = gac[0] + gac[1];

    // ---- deferred normalization: scale GEMM rows by inv; gate; new state ----
    float s2[4];
    #pragma unroll
    for (int r=0;r<4;++r){
      float graw = gacc[r]*invr[r] + xkc[r];
      float g = __builtin_amdgcn_rcpf(1.0f + __builtin_amdgcn_exp2f(-1.442695040889f * graw));
      float s2r = 0.f;
      #pragma unroll
      for (int nt=0;nt<2;++nt){
        float so = nsv[nt][r] * invr[r];                       // normalized old state
        float cv = (nt ? acc1[r] : acc0[r])*invr[r] + Creg[nt][r] + xwc[nt];
        cv = cv > 0.f ? cv : pa2[nt]*cv;
        float n = so + g*cv;
        nsv[nt][r] = realr[r] ? (n > 0.f ? n : 1.0f) : 0.f;    // s_hat_{t+1}
        s2r += n*n;
      }
      s2[r] = dpp_add16(s2r);                                  // 16-lane DPP reduce
    }
    if (c == 0){
      f4v np; np[0]=s2[0]; np[1]=s2[1]; np[2]=s2[2]; np[3]=s2[3];
      *(f4v*)&L.npart[pn][cg][4*q] = np;
    }

    // ---- store s_hat_{t+1} (pkrtz split, uint2 stores) + stage x_{t+1} ----
    #pragma unroll
    for (int nt=0;nt<2;++nt){
      float v0=nsv[nt][0], v1=nsv[nt][1], v2=nsv[nt][2], v3=nsv[nt][3];
      fp2v pa = __builtin_amdgcn_cvt_pkrtz(v0, v1);
      fp2v pb = __builtin_amdgcn_cvt_pkrtz(v2, v3);
      float r0 = v0 - pk_lo(pa);
      float r1 = v1 - pk_hi(pa);
      float r2 = v2 - pk_lo(pb);
      float r3 = v3 - pk_hi(pb);
      fp2v pc = __builtin_amdgcn_cvt_pkrtz(r0, r1);
      fp2v pd = __builtin_amdgcn_cvt_pkrtz(r2, r3);
      *(uint2*)&L.st[pn][0][col[nt]][4*q] = make_uint2(pk2u(pa), pk2u(pb));
      *(uint2*)&L.st[pn][1][col[nt]][4*q] = make_uint2(pk2u(pc), pk2u(pd));
    }
    if (t+1 < TT && tid < EE){
      _Float16 hb = (_Float16)nxv;
      _Float16 lb = (_Float16)(nxv - (float)hb);
      L.xp[pn][0][tid] = h1u(hb); L.xp[pn][1][tid] = h1u(lb);
    }
    xwc[0]=xwn[0]; xwc[1]=xwn[1];
    #pragma unroll
    for (int r=0;r<4;++r) xkc[r] = realr[r] ? xk4n[r] : 0.f;
    __syncthreads();                              // ONE barrier per step
  }

  // ---- finalize: normalize last s_hat from registers + final npart ----
  {
    int pf = TT & 1;   // buffer holding final npart
    f4v p0 = *(const f4v*)&L.npart[pf][0][4*q];
    f4v p1 = *(const f4v*)&L.npart[pf][1][4*q];
    f4v p2 = *(const f4v*)&L.npart[pf][2][4*q];
    f4v p3 = *(const f4v*)&L.npart[pf][3][4*q];
    f4v ss = p0 + p1 + p2 + p3;
    #pragma unroll
    for (int r=0;r<4;++r){
      if (realr[r]){
        float inv = __builtin_amdgcn_rcpf(__builtin_amdgcn_sqrtf(ss[r]) + 1e-8f);
        #pragma unroll
        for (int nt=0;nt<2;++nt)
          zst[((size_t)b*KK + kb*KB_ROWS + 4*q + r)*EE + col[nt]] = nsv[nt][r]*inv;
      }
    }
  }
}

// ---------------- kernel 4b: tail (attention + u + z), needs all 20 k ----------------
__global__ __launch_bounds__(128) void k_tail(
    const float* __restrict__ zst, const float* __restrict__ qenc,
    const float* __restrict__ prelu_a, const float* __restrict__ H,
    float* __restrict__ zout)
{
  __shared__ float st[KK*EE];
  __shared__ float us[EE];
  __shared__ float red[2][KK];
  __shared__ float gs[KK];
  int b = blockIdx.x, tid = threadIdx.x;
  for (int i = tid; i < KK*EE; i += 128) st[i] = zst[(size_t)b*KK*EE + i];
  float qv = qenc[(size_t)b*EE + tid];
  __syncthreads();
  int wv = tid >> 6, ln = tid & 63;
  for (int k=0;k<KK;++k){
    float p = qv * st[k*EE + tid];
    #pragma unroll
    for (int off=32; off; off>>=1) p += __shfl_xor(p, off);
    if (ln == 0) red[wv][k] = p;
  }
  __syncthreads();
  if (tid == 0){
    float mx = -1e30f, gg[KK];
    for (int k=0;k<KK;++k){ float v = red[0][k]+red[1][k]; gg[k]=v; mx = fmaxf(mx, v); }
    float s = 0.f;
    for (int k=0;k<KK;++k){ float e_ = expf(gg[k]-mx); gg[k]=e_; s += e_; }
    for (int k=0;k<KK;++k) gs[k] = gg[k]/s;
  }
  __syncthreads();
  float u_ = 0.f;
  #pragma unroll
  for (int k=0;k<KK;++k) u_ += gs[k]*st[k*EE + tid];
  us[tid] = u_;
  __syncthreads();
  float hp = 0.f;
  const float* hr = H + (size_t)tid*EE;
  for (int e=0; e<EE; e+=4){
    float4 h4 = *(const float4*)(hr + e);
    float4 u4 = *(const float4*)(us + e);
    hp += h4.x*u4.x + h4.y*u4.y + h4.z*u4.z + h4.w*u4.w;
  }
  float zv = qv + hp;
  float pat = prelu_a[tid];
  zv = zv > 0.f ? zv : pat*zv;
  zout[(size_t)b*EE + tid] = zv;
}

// ---------------- kernel 5: y = z @ R^T via fp16-split MFMA, 2 M-tiles/block ----
__global__ __launch_bounds__(256) void k_out(
    const float* __restrict__ z, const float* __restrict__ R,
    float* __restrict__ y)
{
  int tid = threadIdx.x;
  int w = tid >> 6, l = tid & 63;
  int q = l >> 4, cc = l & 15;
  int b0 = blockIdx.y * 32;
  int vbase = blockIdx.x * 256 + w * 64;

  // A-frags: z rows for 2 M-tiles (row = lane&15 within tile)
  h8v ah[2][4], al[2][4];
  #pragma unroll
  for (int mt=0;mt<2;++mt){
    const float* zr = z + (size_t)(b0 + mt*16 + cc)*EE;
    #pragma unroll
    for (int kk=0;kk<4;++kk){
      float tmp[8];
      *(float4*)&tmp[0] = *(const float4*)(zr + kk*32 + q*8);
      *(float4*)&tmp[4] = *(const float4*)(zr + kk*32 + q*8 + 4);
      split2_8(tmp, ah[mt][kk], al[mt][kk]);
    }
  }
  #pragma unroll
  for (int vt=0; vt<4; ++vt){
    int v = vbase + vt*16 + cc;
    int vc = v < VOCAB ? v : VOCAB-1;
    const float* rr = R + (size_t)vc*EE;
    h8v bh[4], bl[4];
    #pragma unroll
    for (int kk=0;kk<4;++kk){
      float tmp[8];
      *(float4*)&tmp[0] = *(const float4*)(rr + kk*32 + q*8);
      *(float4*)&tmp[4] = *(const float4*)(rr + kk*32 + q*8 + 4);
      split2_8(tmp, bh[kk], bl[kk]);
    }
    f4v acc0 = {0.f,0.f,0.f,0.f};
    f4v acc1 = {0.f,0.f,0.f,0.f};
    #pragma unroll
    for (int kk=0;kk<4;++kk){
      acc0 = MFMA16(al[0][kk], bh[kk], acc0);
      acc0 = MFMA16(ah[0][kk], bl[kk], acc0);
      acc0 = MFMA16(ah[0][kk], bh[kk], acc0);
      acc1 = MFMA16(al[1][kk], bh[kk], acc1);
      acc1 = MFMA16(ah[1][kk], bl[kk], acc1);
      acc1 = MFMA16(ah[1][kk], bh[kk], acc1);
    }
    if (v < VOCAB){
      #pragma unroll
      for (int r=0;r<4;++r){
        y[(size_t)(b0 + q*4 + r)*VOCAB + v]      = acc0[r];
        y[(size_t)(b0 + 16 + q*4 + r)*VOCAB + v] = acc1[r];
      }
    }
  }
}

// ---------------- launch ----------------
extern "C" void kernel_launch(void* const* d_in, const int* in_sizes, int n_in,
                              void* d_out, int out_size, void* d_ws, size_t ws_size,
                              hipStream_t stream)
{
  const int*   story = (const int*)d_in[0];
  const int*   query = (const int*)d_in[1];
  const float* emb   = (const float*)d_in[2];
  const float* smask = (const float*)d_in[3];
  const float* qmask = (const float*)d_in[4];
  const float* pa    = (const float*)d_in[5];
  const float* U     = (const float*)d_in[6];
  const float* V     = (const float*)d_in[7];
  const float* W     = (const float*)d_in[8];
  const float* bias  = (const float*)d_in[9];
  const float* H     = (const float*)d_in[10];
  const float* R     = (const float*)d_in[11];
  float* y  = (float*)d_out;
  float* ws = (float*)d_ws;

  float* s_enc = ws + OFF_SENC;
  float* q_enc = ws + OFF_QENC;
  float* Ckf   = ws + OFF_CKF;
  float* xw    = ws + OFF_XW;
  float* z     = ws + OFF_Z;
  float* xk    = ws + OFF_XK;
  float* zst   = ws + OFF_ST;

  k_embed_sum<<<dim3(BB*TT/8), 256, 0, stream>>>(story, emb, smask, s_enc, BB*TT);
  k_embed_sum<<<dim3(BB/8),    256, 0, stream>>>(query, emb, qmask, q_enc, BB);
  k_ckf<<<dim3(KK), 128, 0, stream>>>(emb, V, bias, Ckf);
  k_xw<<<dim3(BB*TT/64), 256, 0, stream>>>(s_enc, W, emb, xw, xk);

  k_scan<<<dim3(BB*2), 256, 0, stream>>>(emb, U, s_enc, xw, xk, Ckf, pa, zst);
  k_tail<<<dim3(BB), 128, 0, stream>>>(zst, q_enc, pa, H, z);

  k_out<<<dim3((VOCAB+255)/256, BB/32), 256, 0, stream>>>(z, R, y);
}